// Round 4
// baseline (651.561 us; speedup 1.0000x reference)
//
#include <hip/hip_runtime.h>

#define NN 20000
#define EE 320000
#define WSTRIDE 27648

typedef unsigned short u16;
typedef unsigned int u32;
typedef __attribute__((ext_vector_type(8))) short bf16x8;
typedef __attribute__((ext_vector_type(4))) float f32x4;

__device__ __forceinline__ float bf2f(u16 u){
  union { u32 i; float f; } v; v.i = ((u32)u) << 16; return v.f;
}
__device__ __forceinline__ u16 f2bf(float f){
  union { float f; u32 i; } v; v.f = f;
  u32 i = v.i;
  return (u16)((i + 0x7FFFu + ((i >> 16) & 1u)) >> 16);
}
__device__ __forceinline__ u32 pack2(float a, float b){
  return ((u32)f2bf(b) << 16) | (u32)f2bf(a);
}
// cheap split: hi = truncated top-16, lo = rne(residual). total rel err ~2^-17
__device__ __forceinline__ void split2(float a, float b, u32& hi, u32& lo){
  union { float f; u32 u; } ua, ub; ua.f = a; ub.f = b;
  u32 ha = ua.u & 0xFFFF0000u, hb = ub.u & 0xFFFF0000u;
  union { u32 u; float f; } fa, fb; fa.u = ha; fb.u = hb;
  u16 la = f2bf(a - fa.f), lb = f2bf(b - fb.f);
  hi = hb | (ha >> 16);
  lo = ((u32)lb << 16) | la;
}

// ---------------- weight pre-transpose (to bf16, [n][k] layout) -------------
__global__ __launch_bounds__(256) void k_prep(
    const float* __restrict__ plw, const float* __restrict__ lew,
    const float* __restrict__ lw,
    u16* __restrict__ Bt1, u16* __restrict__ Bt2, u16* __restrict__ Bt3)
{
  int i = blockIdx.x * 256 + threadIdx.x;
  if (i < 128*320) {                       // Bt1[n][k] = pre_lin_w[k][n]
    int n = i / 320, k = i % 320;
    Bt1[i] = f2bf(plw[k*128 + n]);
  }
  int j = i - 128*320;
  if (j >= 0 && j < 256*128) {             // Bt2[h*64+c][k] = lin_edge_w[h*128+k][c]
    int n = j / 128, k = j % 128;
    int h = n >> 6, c = n & 63;
    Bt2[j] = f2bf(lew[(h*128 + k)*64 + c]);
  }
  int l = i - 128*320 - 256*128;
  if (l >= 0 && l < 128*512) {             // Bt3[n][k] = lin_w[k][n]
    int n = l / 512, k = l % 512;
    Bt3[l] = f2bf(lw[k*128 + n]);
  }
}

// MLP weights, transposed to [out][in], stored as hi (at i) + lo (at i+WSTRIDE).
// Layout: Wa1[4096] Wa2[4096] Wa3[1024(pad16x64)] Wr1[4096] Wr2[4096]
//         Ws1[4096] Ws2[4096] Ws3[2048]
__global__ __launch_bounds__(256) void k_prep2(
    const float* __restrict__ aw1, const float* __restrict__ aw2, const float* __restrict__ aw3,
    const float* __restrict__ rw1, const float* __restrict__ rw2,
    const float* __restrict__ sw1, const float* __restrict__ sw2, const float* __restrict__ sw3,
    u16* __restrict__ W)
{
  int i = blockIdx.x * 256 + threadIdx.x;
  if (i >= WSTRIDE) return;
  float v = 0.f;
  int j = i;
  if (j < 4096)      { int n = j >> 6, k = j & 63; v = aw1[k*64 + n]; }
  else if ((j -= 4096) < 4096) { int n = j >> 6, k = j & 63; v = aw2[k*64 + n]; }
  else if ((j -= 4096) < 1024) { int n = j >> 6, k = j & 63; v = (n < 4) ? aw3[k*4 + n] : 0.f; }
  else if ((j -= 1024) < 4096) { int n = j >> 6, k = j & 63; v = rw1[k*64 + n]; }
  else if ((j -= 4096) < 4096) { int n = j >> 6, k = j & 63; v = rw2[k*64 + n]; }
  else if ((j -= 4096) < 4096) { int n = j >> 6, k = j & 63; v = sw1[k*64 + n]; }
  else if ((j -= 4096) < 4096) { int n = j >> 6, k = j & 63; v = sw2[k*64 + n]; }
  else               { j -= 4096; int n = j >> 6, k = j & 63; v = sw3[k*32 + n]; }
  u16 hi = f2bf(v);
  W[i] = hi;
  W[i + WSTRIDE] = f2bf(v - bf2f(hi));
}

// ---------------- CSR build -------------------------------------------------
__global__ __launch_bounds__(256) void k_zero(int* __restrict__ counts){
  int i = blockIdx.x * 256 + threadIdx.x;
  if (i < NN) counts[i] = 0;
}
__global__ __launch_bounds__(256) void k_count(const int* __restrict__ edst, int* __restrict__ counts){
  int e = blockIdx.x * 256 + threadIdx.x;
  if (e < EE) atomicAdd(&counts[edst[e]], 1);
}
__global__ __launch_bounds__(1024) void k_scan(const int* __restrict__ counts,
                                               int* __restrict__ offs, int* __restrict__ cursor){
  __shared__ int part[1024];
  int t = threadIdx.x;
  int c0 = t * 20, c1 = c0 + 20; if (c1 > NN) c1 = NN; if (c0 > NN) c0 = NN;
  int s = 0;
  for (int i = c0; i < c1; ++i) s += counts[i];
  part[t] = s;
  __syncthreads();
  if (t == 0) {
    int run = 0;
    for (int i = 0; i < 1024; ++i) { int v = part[i]; part[i] = run; run += v; }
    offs[NN] = run;
  }
  __syncthreads();
  int run = part[t];
  for (int i = c0; i < c1; ++i) { offs[i] = run; cursor[i] = run; run += counts[i]; }
}
__global__ __launch_bounds__(256) void k_fill(const int* __restrict__ edst,
                                              int* __restrict__ cursor, int* __restrict__ eids){
  int e = blockIdx.x * 256 + threadIdx.x;
  if (e < EE) { int p = atomicAdd(&cursor[edst[e]], 1); eids[p] = e; }
}
__global__ __launch_bounds__(256) void k_sort(const int* __restrict__ offs, int* __restrict__ eids){
  int n = blockIdx.x * 256 + threadIdx.x;
  if (n >= NN) return;
  int b = offs[n], e = offs[n+1];
  for (int i = b + 1; i < e; ++i) {
    int v = eids[i]; int j = i - 1;
    while (j >= b && eids[j] > v) { eids[j+1] = eids[j]; --j; }
    eids[j+1] = v;
  }
}

// ---------------- MFMA MLP building blocks (64-row tile, wave-private) ------
// X: LDS tiles [64][72] bf16 hi + lo; B: [out][64] bf16 hi + lo in global.
// Wave w owns rows [w*16, w*16+16): staging, reads and writes are all
// wave-private -> NO __syncthreads anywhere, in-place layer chaining safe.
// acc += Xhi*Bhi + Xhi*Blo + Xlo*Bhi  (effective ~16-bit mantissa)
template<int NI>
__device__ __forceinline__ void gemm_frag1(const u16 (*Xh)[72], const u16 (*Xl)[72],
                                           int wrow, int lane,
                                           const u16* __restrict__ Bh, const u16* __restrict__ Bl,
                                           f32x4* acc)
{
  const int fr = lane & 15, fc = lane >> 4;
  #pragma unroll
  for (int ni = 0; ni < NI; ++ni) acc[ni] = (f32x4){0.f, 0.f, 0.f, 0.f};
  #pragma unroll
  for (int kk = 0; kk < 2; ++kk) {
    bf16x8 ah = *(const bf16x8*)&Xh[wrow + fr][kk*32 + fc*8];
    bf16x8 al = *(const bf16x8*)&Xl[wrow + fr][kk*32 + fc*8];
    #pragma unroll
    for (int ni = 0; ni < NI; ++ni) {
      bf16x8 bh = *(const bf16x8*)(Bh + (size_t)(ni*16 + fr)*64 + kk*32 + fc*8);
      bf16x8 bl = *(const bf16x8*)(Bl + (size_t)(ni*16 + fr)*64 + kk*32 + fc*8);
      acc[ni] = __builtin_amdgcn_mfma_f32_16x16x32_bf16(ah, bh, acc[ni], 0, 0, 0);
      acc[ni] = __builtin_amdgcn_mfma_f32_16x16x32_bf16(ah, bl, acc[ni], 0, 0, 0);
      acc[ni] = __builtin_amdgcn_mfma_f32_16x16x32_bf16(al, bh, acc[ni], 0, 0, 0);
    }
  }
}

// bias (+ optional LN) + SiLU on C fragments, store bf16 hi/lo to H (may == X)
template<bool LN>
__device__ __forceinline__ void act_store1(f32x4* acc,
    const float* __restrict__ b, const float* __restrict__ g, const float* __restrict__ be,
    u16 (*Hh)[72], u16 (*Hl)[72], int wrow, int lane)
{
  const int fr = lane & 15, fc = lane >> 4;
  float bv[4], gv[4], bev[4];
  #pragma unroll
  for (int ni = 0; ni < 4; ++ni) {
    bv[ni] = b[ni*16 + fr];
    if (LN) { gv[ni] = g[ni*16 + fr]; bev[ni] = be[ni*16 + fr]; }
  }
  #pragma unroll
  for (int j = 0; j < 4; ++j) {
    int r = wrow + fc*4 + j;
    float x[4];
    #pragma unroll
    for (int ni = 0; ni < 4; ++ni) x[ni] = acc[ni][j] + bv[ni];
    if (LN) {
      float s  = x[0] + x[1] + x[2] + x[3];
      float s2 = x[0]*x[0] + x[1]*x[1] + x[2]*x[2] + x[3]*x[3];
      #pragma unroll
      for (int off = 1; off < 16; off <<= 1) {
        s  += __shfl_xor(s,  off);
        s2 += __shfl_xor(s2, off);
      }
      float mu  = s * (1.f/64.f);
      float var = s2 * (1.f/64.f) - mu*mu;
      float rs  = rsqrtf(var + 1e-6f);
      #pragma unroll
      for (int ni = 0; ni < 4; ++ni) x[ni] = (x[ni] - mu)*rs*gv[ni] + bev[ni];
    }
    #pragma unroll
    for (int ni = 0; ni < 4; ++ni) {
      float y = x[ni];
      y = y / (1.f + __expf(-y));
      union { float f; u32 u; } c; c.f = y;
      union { u32 u; float f; } hf; hf.u = c.u & 0xFFFF0000u;
      Hh[r][ni*16 + fr] = (u16)(c.u >> 16);
      Hl[r][ni*16 + fr] = f2bf(y - hf.f);
    }
  }
}

// stage 64x64 fp32 rows -> Xh/Xl (wave-private rows)
__device__ __forceinline__ void stage_f32(const float* __restrict__ src, size_t row_stride,
                                          int e0, int tid, u16 (*Xh)[72], u16 (*Xl)[72])
{
  int r = tid >> 2, cb = (tid & 3) * 16;
  const float* p = src + (size_t)(e0 + r)*row_stride + cb;
  u32* dh = (u32*)&Xh[r][cb];
  u32* dl = (u32*)&Xl[r][cb];
  #pragma unroll
  for (int q = 0; q < 4; ++q) {
    float4 v = *(const float4*)(p + q*4);
    u32 h0, l0, h1, l1;
    split2(v.x, v.y, h0, l0);
    split2(v.z, v.w, h1, l1);
    dh[q*2] = h0; dh[q*2+1] = h1;
    dl[q*2] = l0; dl[q*2+1] = l1;
  }
}

// ---------------- alpha MLP (elen -> alpha[E,4]) ----------------------------
__global__ __launch_bounds__(256) void k_alpha_m(
  const float* __restrict__ elen, const u16* __restrict__ Wm,
  const float* __restrict__ b1, const float* __restrict__ g1, const float* __restrict__ be1,
  const float* __restrict__ b2, const float* __restrict__ g2, const float* __restrict__ be2,
  const float* __restrict__ b3,
  float* __restrict__ alpha_g)
{
  __shared__ u16 Xh[64][72], Xl[64][72];
  const u16* Wa1 = Wm;
  const u16* Wa2 = Wm + 4096;
  const u16* Wa3 = Wm + 8192;
  const int tid = threadIdx.x;
  const int wave = tid >> 6, lane = tid & 63;
  const int fr = lane & 15, fc = lane >> 4;
  const int wrow = wave * 16;
  const int e0 = blockIdx.x * 64;
  stage_f32(elen, 64, e0, tid, Xh, Xl);
  f32x4 acc[4];
  gemm_frag1<4>(Xh, Xl, wrow, lane, Wa1, Wa1 + WSTRIDE, acc);
  act_store1<true>(acc, b1, g1, be1, Xh, Xl, wrow, lane);
  gemm_frag1<4>(Xh, Xl, wrow, lane, Wa2, Wa2 + WSTRIDE, acc);
  act_store1<true>(acc, b2, g2, be2, Xh, Xl, wrow, lane);
  gemm_frag1<1>(Xh, Xl, wrow, lane, Wa3, Wa3 + WSTRIDE, acc);
  {
    float bv = (fr < 4) ? b3[fr] : 0.f;
    #pragma unroll
    for (int j = 0; j < 4; ++j) {
      int r = wrow + fc*4 + j;
      float v = acc[0][j] + bv;
      if (fr < 4) alpha_g[(size_t)(e0 + r)*4 + fr] = v;
    }
  }
}

// ---------------- radial MLP + sh contraction -------------------------------
__global__ __launch_bounds__(256) void k_radial_m(
  const float* __restrict__ elen, const float* __restrict__ esh,
  const u16* __restrict__ Wm,
  const float* __restrict__ tb1, const float* __restrict__ tb2,
  const float* __restrict__ alpha_g,
  float* __restrict__ scal_g, float* __restrict__ cbuf_g)
{
  __shared__ u16 Xh[64][72], Xl[64][72];
  const u16* Wr1 = Wm + 9216;
  const u16* Wr2 = Wm + 13312;
  const int tid = threadIdx.x;
  const int wave = tid >> 6, lane = tid & 63;
  const int fr = lane & 15, fc = lane >> 4;
  const int wrow = wave * 16;
  const int e0 = blockIdx.x * 64;
  stage_f32(elen, 64, e0, tid, Xh, Xl);
  f32x4 acc[4];
  gemm_frag1<4>(Xh, Xl, wrow, lane, Wr1, Wr1 + WSTRIDE, acc);
  act_store1<false>(acc, tb1, nullptr, nullptr, Xh, Xl, wrow, lane);
  gemm_frag1<4>(Xh, Xl, wrow, lane, Wr2, Wr2 + WSTRIDE, acc);
  {
    float bv[4];
    #pragma unroll
    for (int ni = 0; ni < 4; ++ni) bv[ni] = tb2[ni*16 + fr];
    #pragma unroll
    for (int j = 0; j < 4; ++j) {
      int r = wrow + fc*4 + j;
      float shv = esh[(size_t)(e0 + r)*16 + fr];
      float sc[4];
      #pragma unroll
      for (int ni = 0; ni < 4; ++ni) {
        float t = (acc[ni][j] + bv[ni]) * shv;
        #pragma unroll
        for (int off = 1; off < 16; off <<= 1) t += __shfl_xor(t, off);
        sc[ni] = t;
      }
      if (fr == 0) {
        float4 av = *(const float4*)(alpha_g + (size_t)(e0 + r)*4);
        float4 sv; sv.x = sc[0]; sv.y = sc[1]; sv.z = sc[2]; sv.w = sc[3];
        *(float4*)(scal_g + (size_t)(e0 + r)*4) = sv;
        float4 cv;
        cv.x = sc[0]*av.x; cv.y = sc[1]*av.y; cv.z = sc[2]*av.z; cv.w = sc[3]*av.w;
        *(float4*)(cbuf_g + (size_t)(e0 + r)*4) = cv;
      }
    }
  }
}

// ---------------- MFMA s-MLP (y0 -> edge_scalar[E,32]) ----------------------
__global__ __launch_bounds__(256) void k_smlp2(
  const u16* __restrict__ y0b, const u16* __restrict__ Wm,
  const float* __restrict__ b1, const float* __restrict__ g1, const float* __restrict__ be1,
  const float* __restrict__ b2, const float* __restrict__ g2, const float* __restrict__ be2,
  const float* __restrict__ b3,
  float* __restrict__ oute)
{
  __shared__ u16 Xh[64][72], Xl[64][72];
  const u16* Ws1 = Wm + 17408;
  const u16* Ws2 = Wm + 21504;
  const u16* Ws3 = Wm + 25600;
  const int tid = threadIdx.x;
  const int wave = tid >> 6, lane = tid & 63;
  const int fr = lane & 15, fc = lane >> 4;
  const int wrow = wave * 16;
  const int e0 = blockIdx.x * 64;
  {
    int r = tid >> 2, cb = (tid & 3) * 16;
    const uint4* p = (const uint4*)(y0b + (size_t)(e0 + r)*64 + cb);
    uint4* dh = (uint4*)&Xh[r][cb];
    uint4* dl = (uint4*)&Xl[r][cb];
    uint4 z; z.x = 0; z.y = 0; z.z = 0; z.w = 0;
    dh[0] = p[0]; dh[1] = p[1];
    dl[0] = z; dl[1] = z;
  }
  f32x4 acc[4];
  gemm_frag1<4>(Xh, Xl, wrow, lane, Ws1, Ws1 + WSTRIDE, acc);
  act_store1<true>(acc, b1, g1, be1, Xh, Xl, wrow, lane);
  gemm_frag1<4>(Xh, Xl, wrow, lane, Ws2, Ws2 + WSTRIDE, acc);
  act_store1<true>(acc, b2, g2, be2, Xh, Xl, wrow, lane);
  gemm_frag1<2>(Xh, Xl, wrow, lane, Ws3, Ws3 + WSTRIDE, acc);
  {
    float bv[2];
    bv[0] = b3[fr]; bv[1] = b3[16 + fr];
    #pragma unroll
    for (int j = 0; j < 4; ++j) {
      int r = wrow + fc*4 + j;
      #pragma unroll
      for (int ni = 0; ni < 2; ++ni)
        oute[(size_t)(e0 + r)*32 + ni*16 + fr] = acc[ni][j] + bv[ni];
    }
  }
}

// ---------------- G1: msg = [x_src|x_dst|elen] @ pre_lin_w  (bf16 out) ------
__global__ __launch_bounds__(256) void g1_msg(
    const float* __restrict__ node_in, const float* __restrict__ elen,
    const int* __restrict__ esrc, const int* __restrict__ edst,
    const u16* __restrict__ Bt1, u16* __restrict__ msgb)
{
  __shared__ u16 As[128][40];
  __shared__ u16 Bs[128][40];
  const int tid = threadIdx.x;
  const int e0 = blockIdx.x * 128;
  const int wave = tid >> 6, lane = tid & 63;
  const int wr = (wave >> 1) * 64, wc = (wave & 1) * 64;
  const int fr = lane & 15, fc = lane >> 4;
  f32x4 acc[4][4] = {};
  const int r = tid >> 1, half = tid & 1;
  const int e = e0 + r;
  const int s_idx = esrc[e], d_idx = edst[e];
  for (int k0 = 0; k0 < 320; k0 += 32) {
    const int kk = k0 + half * 16;
    const float* ap;
    if (kk < 128)      ap = node_in + (size_t)s_idx*128 + kk;
    else if (kk < 256) ap = node_in + (size_t)d_idx*128 + (kk - 128);
    else               ap = elen + (size_t)e*64 + (kk - 256);
    u32* asp = (u32*)&As[r][half*16];
    #pragma unroll
    for (int q = 0; q < 4; ++q) {
      float4 v = *(const float4*)(ap + q*4);
      asp[q*2]   = pack2(v.x, v.y);
      asp[q*2+1] = pack2(v.z, v.w);
    }
    const uint4* bp = (const uint4*)(Bt1 + (size_t)r*320 + kk);
    *(uint4*)&Bs[r][half*16]     = bp[0];
    *(uint4*)&Bs[r][half*16 + 8] = bp[1];
    __syncthreads();
    bf16x8 a[4], b[4];
    #pragma unroll
    for (int mi = 0; mi < 4; ++mi) a[mi] = *(const bf16x8*)&As[wr + mi*16 + fr][fc*8];
    #pragma unroll
    for (int ni = 0; ni < 4; ++ni) b[ni] = *(const bf16x8*)&Bs[wc + ni*16 + fr][fc*8];
    #pragma unroll
    for (int mi = 0; mi < 4; ++mi)
      #pragma unroll
      for (int ni = 0; ni < 4; ++ni)
        acc[mi][ni] = __builtin_amdgcn_mfma_f32_16x16x32_bf16(a[mi], b[ni], acc[mi][ni], 0, 0, 0);
    __syncthreads();
  }
  #pragma unroll
  for (int mi = 0; mi < 4; ++mi)
    #pragma unroll
    for (int j = 0; j < 4; ++j) {
      int row = wr + mi*16 + fc*4 + j;
      size_t base = (size_t)(e0 + row)*128 + wc + fr;
      #pragma unroll
      for (int ni = 0; ni < 4; ++ni)
        msgb[base + ni*16] = f2bf(acc[mi][ni][j]);
    }
}

// ---------------- G2: t = msg @ Wcat ; y0 = sum_h c[h]*t[:,h*64+j] ----------
union G2Smem {
  struct { u16 As[64][40]; u16 Bs[256][40]; } s;
  float R[2][64][66];
};
__global__ __launch_bounds__(256) void g2_y0(
    const u16* __restrict__ msgb, const u16* __restrict__ Bt2,
    const float* __restrict__ cbuf, u16* __restrict__ y0b)
{
  __shared__ G2Smem u;
  __shared__ float cS[64][4];
  const int tid = threadIdx.x, wave = tid >> 6, lane = tid & 63;
  const int e0 = blockIdx.x * 64;
  const int fr = lane & 15, fc = lane >> 4;
  cS[tid >> 2][tid & 3] = cbuf[(size_t)e0*4 + tid];
  f32x4 acc[4][4] = {};
  for (int k0 = 0; k0 < 128; k0 += 32) {
    { // stage A (64 x 32)
      int r = tid >> 2, q = tid & 3;
      *(uint4*)&u.s.As[r][q*8] = *(const uint4*)(msgb + (size_t)(e0 + r)*128 + k0 + q*8);
    }
    { // stage B (256 x 32)
      const uint4* bp = (const uint4*)(Bt2 + (size_t)tid*128 + k0);
      *(uint4*)&u.s.Bs[tid][0]  = bp[0];
      *(uint4*)&u.s.Bs[tid][8]  = bp[1];
      *(uint4*)&u.s.Bs[tid][16] = bp[2];
      *(uint4*)&u.s.Bs[tid][24] = bp[3];
    }
    __syncthreads();
    bf16x8 a[4], b[4];
    #pragma unroll
    for (int mi = 0; mi < 4; ++mi) a[mi] = *(const bf16x8*)&u.s.As[mi*16 + fr][fc*8];
    #pragma unroll
    for (int ni = 0; ni < 4; ++ni) b[ni] = *(const bf16x8*)&u.s.Bs[wave*64 + ni*16 + fr][fc*8];
    #pragma unroll
    for (int mi = 0; mi < 4; ++mi)
      #pragma unroll
      for (int ni = 0; ni < 4; ++ni)
        acc[mi][ni] = __builtin_amdgcn_mfma_f32_16x16x32_bf16(a[mi], b[ni], acc[mi][ni], 0, 0, 0);
    __syncthreads();
  }
  const int h = wave;
  if ((wave & 1) == 0) {
    float (*Rb)[66] = u.R[wave >> 1];
    #pragma unroll
    for (int mi = 0; mi < 4; ++mi)
      #pragma unroll
      for (int j = 0; j < 4; ++j) {
        int row = mi*16 + fc*4 + j;
        float cv = cS[row][h];
        #pragma unroll
        for (int ni = 0; ni < 4; ++ni)
          Rb[row][ni*16 + fr] = acc[mi][ni][j] * cv;
      }
  }
  __syncthreads();
  if (wave & 1) {
    float (*Rb)[66] = u.R[wave >> 1];
    #pragma unroll
    for (int mi = 0; mi < 4; ++mi)
      #pragma unroll
      for (int j = 0; j < 4; ++j) {
        int row = mi*16 + fc*4 + j;
        float cv = cS[row][h];
        #pragma unroll
        for (int ni = 0; ni < 4; ++ni)
          Rb[row][ni*16 + fr] += acc[mi][ni][j] * cv;
      }
  }
  __syncthreads();
  {
    int rr = tid >> 2, j0 = (tid & 3) * 16;
    u16 tmp[16];
    #pragma unroll
    for (int i = 0; i < 16; ++i)
      tmp[i] = f2bf(u.R[0][rr][j0 + i] + u.R[1][rr][j0 + i]);
    uint4* dst = (uint4*)(y0b + (size_t)(e0 + rr)*64 + j0);
    dst[0] = *(const uint4*)&tmp[0];
    dst[1] = *(const uint4*)&tmp[8];
  }
}

// ---------------- K9: per-node softmax + aggregation ------------------------
__global__ __launch_bounds__(256) void k_node(
  const int* __restrict__ offs, const int* __restrict__ eids,
  const float* __restrict__ alpha, const float* __restrict__ scal,
  const u16* __restrict__ msgb, u16* __restrict__ nfb)
{
  const int w = threadIdx.x >> 6, lane = threadIdx.x & 63;
  const int n = blockIdx.x * 4 + w;
  const int beg = offs[n], end = offs[n+1];
  float m0=-3e38f, m1=-3e38f, m2=-3e38f, m3=-3e38f;
  for (int i = beg + lane; i < end; i += 64) {
    int eid = eids[i];
    float4 a = *(const float4*)(alpha + (size_t)eid*4);
    m0 = fmaxf(m0, a.x); m1 = fmaxf(m1, a.y);
    m2 = fmaxf(m2, a.z); m3 = fmaxf(m3, a.w);
  }
  #pragma unroll
  for (int off = 1; off < 64; off <<= 1) {
    m0 = fmaxf(m0, __shfl_xor(m0, off));
    m1 = fmaxf(m1, __shfl_xor(m1, off));
    m2 = fmaxf(m2, __shfl_xor(m2, off));
    m3 = fmaxf(m3, __shfl_xor(m3, off));
  }
  float se0=0.f, se1=0.f, se2=0.f, se3=0.f;
  float f00=0.f, f01=0.f, f10=0.f, f11=0.f, f20=0.f, f21=0.f, f30=0.f, f31=0.f;
  for (int i = beg; i < end; ++i) {
    int eid = eids[i];
    float4 a = *(const float4*)(alpha + (size_t)eid*4);
    float4 s = *(const float4*)(scal + (size_t)eid*4);
    float e0 = __expf(a.x - m0), e1 = __expf(a.y - m1);
    float e2 = __expf(a.z - m2), e3 = __expf(a.w - m3);
    se0 += e0; se1 += e1; se2 += e2; se3 += e3;
    float w0 = e0*s.x, w1 = e1*s.y, w2 = e2*s.z, w3 = e3*s.w;
    float v0 = bf2f(msgb[(size_t)eid*128 + lane]);
    float v1 = bf2f(msgb[(size_t)eid*128 + 64 + lane]);
    f00 = fmaf(w0, v0, f00); f01 = fmaf(w0, v1, f01);
    f10 = fmaf(w1, v0, f10); f11 = fmaf(w1, v1, f11);
    f20 = fmaf(w2, v0, f20); f21 = fmaf(w2, v1, f21);
    f30 = fmaf(w3, v0, f30); f31 = fmaf(w3, v1, f31);
  }
  float i0 = 1.f/(se0 + 1e-16f), i1 = 1.f/(se1 + 1e-16f);
  float i2 = 1.f/(se2 + 1e-16f), i3 = 1.f/(se3 + 1e-16f);
  size_t b = (size_t)n * 512;
  nfb[b + 0*128 + lane]      = f2bf(f00*i0);
  nfb[b + 0*128 + 64 + lane] = f2bf(f01*i0);
  nfb[b + 1*128 + lane]      = f2bf(f10*i1);
  nfb[b + 1*128 + 64 + lane] = f2bf(f11*i1);
  nfb[b + 2*128 + lane]      = f2bf(f20*i2);
  nfb[b + 2*128 + 64 + lane] = f2bf(f21*i2);
  nfb[b + 3*128 + lane]      = f2bf(f30*i3);
  nfb[b + 3*128 + 64 + lane] = f2bf(f31*i3);
}

// ---------------- G10: node_out = node_fea @ lin_w --------------------------
__global__ __launch_bounds__(256) void g10_out(
    const u16* __restrict__ nfb, const u16* __restrict__ Bt3,
    float* __restrict__ out)
{
  __shared__ u16 As[128][40];
  __shared__ u16 Bs[128][40];
  const int tid = threadIdx.x;
  const int n0 = blockIdx.x * 128;
  const int wave = tid >> 6, lane = tid & 63;
  const int wr = (wave >> 1) * 64, wc = (wave & 1) * 64;
  const int fr = lane & 15, fc = lane >> 4;
  f32x4 acc[4][4] = {};
  const int r = tid >> 1, half = tid & 1;
  const int n = n0 + r;
  for (int k0 = 0; k0 < 512; k0 += 32) {
    uint4 z; z.x=0; z.y=0; z.z=0; z.w=0;
    uint4 v0 = z, v1 = z;
    if (n < NN) {
      const uint4* apv = (const uint4*)(nfb + (size_t)n*512 + k0 + half*16);
      v0 = apv[0]; v1 = apv[1];
    }
    *(uint4*)&As[r][half*16]     = v0;
    *(uint4*)&As[r][half*16 + 8] = v1;
    const uint4* bp = (const uint4*)(Bt3 + (size_t)r*512 + k0 + half*16);
    *(uint4*)&Bs[r][half*16]     = bp[0];
    *(uint4*)&Bs[r][half*16 + 8] = bp[1];
    __syncthreads();
    bf16x8 a[4], b[4];
    #pragma unroll
    for (int mi = 0; mi < 4; ++mi) a[mi] = *(const bf16x8*)&As[wr + mi*16 + fr][fc*8];
    #pragma unroll
    for (int ni = 0; ni < 4; ++ni) b[ni] = *(const bf16x8*)&Bs[wc + ni*16 + fr][fc*8];
    #pragma unroll
    for (int mi = 0; mi < 4; ++mi)
      #pragma unroll
      for (int ni = 0; ni < 4; ++ni)
        acc[mi][ni] = __builtin_amdgcn_mfma_f32_16x16x32_bf16(a[mi], b[ni], acc[mi][ni], 0, 0, 0);
    __syncthreads();
  }
  #pragma unroll
  for (int mi = 0; mi < 4; ++mi)
    #pragma unroll
    for (int j = 0; j < 4; ++j) {
      int rowg = n0 + wr + mi*16 + fc*4 + j;
      if (rowg < NN) {
        size_t base = (size_t)rowg*128 + wc + fr;
        #pragma unroll
        for (int ni = 0; ni < 4; ++ni)
          out[base + ni*16] = acc[mi][ni][j];
      }
    }
}

// ---------------- launch ----------------------------------------------------
extern "C" void kernel_launch(void* const* d_in, const int* in_sizes, int n_in,
                              void* d_out, int out_size, void* d_ws, size_t ws_size,
                              hipStream_t stream)
{
  const float* node_in    = (const float*)d_in[0];
  const float* edge_sh    = (const float*)d_in[2];
  const float* elen       = (const float*)d_in[3];
  const int*   esrc       = (const int*)d_in[4];
  const int*   edst       = (const int*)d_in[5];
  const float* pre_lin_w  = (const float*)d_in[7];
  const float* tp2_w1     = (const float*)d_in[8];
  const float* tp2_b1     = (const float*)d_in[9];
  const float* tp2_w2     = (const float*)d_in[10];
  const float* tp2_b2     = (const float*)d_in[11];
  const float* a_w1  = (const float*)d_in[12];
  const float* a_b1  = (const float*)d_in[13];
  const float* a_g1  = (const float*)d_in[14];
  const float* a_be1 = (const float*)d_in[15];
  const float* a_w2  = (const float*)d_in[16];
  const float* a_b2  = (const float*)d_in[17];
  const float* a_g2  = (const float*)d_in[18];
  const float* a_be2 = (const float*)d_in[19];
  const float* a_w3  = (const float*)d_in[20];
  const float* a_b3  = (const float*)d_in[21];
  const float* lin_w      = (const float*)d_in[22];
  const float* lin_edge_w = (const float*)d_in[23];
  const float* s_w1  = (const float*)d_in[24];
  const float* s_b1  = (const float*)d_in[25];
  const float* s_g1  = (const float*)d_in[26];
  const float* s_be1 = (const float*)d_in[27];
  const float* s_w2  = (const float*)d_in[28];
  const float* s_b2  = (const float*)d_in[29];
  const float* s_g2  = (const float*)d_in[30];
  const float* s_be2 = (const float*)d_in[31];
  const float* s_w3  = (const float*)d_in[32];
  const float* s_b3  = (const float*)d_in[33];

  float* out_node = (float*)d_out;
  float* out_edge = out_node + (size_t)NN * 128;

  char* ws = (char*)d_ws;
  size_t off = 0;
  auto take = [&](size_t bytes) -> char* {
    char* p = ws + off;
    off = (off + bytes + 255) & ~(size_t)255;
    return p;
  };
  u16*   msgb   = (u16*)take((size_t)EE * 128 * 2);
  u16*   y0b    = (u16*)take((size_t)EE * 64 * 2);
  u16*   nfb    = (u16*)take((size_t)NN * 512 * 2);
  float* alpha  = (float*)take((size_t)EE * 4 * 4);
  float* scal   = (float*)take((size_t)EE * 4 * 4);
  float* cbuf   = (float*)take((size_t)EE * 4 * 4);
  int*   counts = (int*)take((size_t)NN * 4);
  int*   offs   = (int*)take((size_t)(NN + 1) * 4);
  int*   cursor = (int*)take((size_t)NN * 4);
  int*   eids   = (int*)take((size_t)EE * 4);
  u16*   Bt1    = (u16*)take((size_t)128 * 320 * 2);
  u16*   Bt2    = (u16*)take((size_t)256 * 128 * 2);
  u16*   Bt3    = (u16*)take((size_t)128 * 512 * 2);
  u16*   Wmlp   = (u16*)take((size_t)WSTRIDE * 2 * 2);

  k_prep<<<544, 256, 0, stream>>>(pre_lin_w, lin_edge_w, lin_w, Bt1, Bt2, Bt3);
  k_prep2<<<(WSTRIDE + 255)/256, 256, 0, stream>>>(a_w1, a_w2, a_w3, tp2_w1, tp2_w2,
                                                   s_w1, s_w2, s_w3, Wmlp);
  k_zero<<<(NN + 255)/256, 256, 0, stream>>>(counts);
  k_count<<<EE/256, 256, 0, stream>>>(edst, counts);
  k_scan<<<1, 1024, 0, stream>>>(counts, offs, cursor);
  k_fill<<<EE/256, 256, 0, stream>>>(edst, cursor, eids);
  k_sort<<<(NN + 255)/256, 256, 0, stream>>>(offs, eids);
  k_alpha_m<<<EE/64, 256, 0, stream>>>(elen, Wmlp, a_b1, a_g1, a_be1,
                                       a_b2, a_g2, a_be2, a_b3, alpha);
  k_radial_m<<<EE/64, 256, 0, stream>>>(elen, edge_sh, Wmlp, tp2_b1, tp2_b2,
                                        alpha, scal, cbuf);
  g1_msg<<<EE/128, 256, 0, stream>>>(node_in, elen, esrc, edst, Bt1, msgb);
  g2_y0<<<EE/64, 256, 0, stream>>>(msgb, Bt2, cbuf, y0b);
  k_smlp2<<<EE/64, 256, 0, stream>>>(y0b, Wmlp, s_b1, s_g1, s_be1,
                                     s_b2, s_g2, s_be2, s_b3, out_edge);
  k_node<<<NN/4, 256, 0, stream>>>(offs, eids, alpha, scal, msgb, nfb);
  g10_out<<<(NN + 127)/128, 256, 0, stream>>>(nfb, Bt3, out_node);
}

// Round 5
// 599.731 us; speedup vs baseline: 1.0864x; 1.0864x over previous
//
#include <hip/hip_runtime.h>

#define NN 20000
#define EE 320000
#define WSTRIDE 27648

typedef unsigned short u16;
typedef unsigned int u32;
typedef __attribute__((ext_vector_type(8))) short bf16x8;
typedef __attribute__((ext_vector_type(4))) float f32x4;

__device__ __forceinline__ float bf2f(u16 u){
  union { u32 i; float f; } v; v.i = ((u32)u) << 16; return v.f;
}
__device__ __forceinline__ u16 f2bf(float f){
  union { float f; u32 i; } v; v.f = f;
  u32 i = v.i;
  return (u16)((i + 0x7FFFu + ((i >> 16) & 1u)) >> 16);
}
__device__ __forceinline__ u32 pack2(float a, float b){
  return ((u32)f2bf(b) << 16) | (u32)f2bf(a);
}
// cheap split: hi = truncated top-16, lo = rne(residual). total rel err ~2^-17
__device__ __forceinline__ void split2(float a, float b, u32& hi, u32& lo){
  union { float f; u32 u; } ua, ub; ua.f = a; ub.f = b;
  u32 ha = ua.u & 0xFFFF0000u, hb = ub.u & 0xFFFF0000u;
  union { u32 u; float f; } fa, fb; fa.u = ha; fb.u = hb;
  u16 la = f2bf(a - fa.f), lb = f2bf(b - fb.f);
  hi = hb | (ha >> 16);
  lo = ((u32)lb << 16) | la;
}

// ---------------- weight pre-transpose (to bf16, [n][k] layout) -------------
__global__ __launch_bounds__(256) void k_prep(
    const float* __restrict__ plw, const float* __restrict__ lew,
    const float* __restrict__ lw,
    u16* __restrict__ Bt1, u16* __restrict__ Bt2, u16* __restrict__ Bt3)
{
  int i = blockIdx.x * 256 + threadIdx.x;
  if (i < 128*320) {                       // Bt1[n][k] = pre_lin_w[k][n]
    int n = i / 320, k = i % 320;
    Bt1[i] = f2bf(plw[k*128 + n]);
  }
  int j = i - 128*320;
  if (j >= 0 && j < 256*128) {             // Bt2[h*64+c][k] = lin_edge_w[h*128+k][c]
    int n = j / 128, k = j % 128;
    int h = n >> 6, c = n & 63;
    Bt2[j] = f2bf(lew[(h*128 + k)*64 + c]);
  }
  int l = i - 128*320 - 256*128;
  if (l >= 0 && l < 128*512) {             // Bt3[n][k] = lin_w[k][n]
    int n = l / 512, k = l % 512;
    Bt3[l] = f2bf(lw[k*128 + n]);
  }
}

// MLP weights, transposed to [out][in], stored as hi (at i) + lo (at i+WSTRIDE).
// Layout: Wa1[4096] Wa2[4096] Wa3[1024(pad16x64)] Wr1[4096] Wr2[4096]
//         Ws1[4096] Ws2[4096] Ws3[2048]
__global__ __launch_bounds__(256) void k_prep2(
    const float* __restrict__ aw1, const float* __restrict__ aw2, const float* __restrict__ aw3,
    const float* __restrict__ rw1, const float* __restrict__ rw2,
    const float* __restrict__ sw1, const float* __restrict__ sw2, const float* __restrict__ sw3,
    u16* __restrict__ W)
{
  int i = blockIdx.x * 256 + threadIdx.x;
  if (i >= WSTRIDE) return;
  float v = 0.f;
  int j = i;
  if (j < 4096)      { int n = j >> 6, k = j & 63; v = aw1[k*64 + n]; }
  else if ((j -= 4096) < 4096) { int n = j >> 6, k = j & 63; v = aw2[k*64 + n]; }
  else if ((j -= 4096) < 1024) { int n = j >> 6, k = j & 63; v = (n < 4) ? aw3[k*4 + n] : 0.f; }
  else if ((j -= 1024) < 4096) { int n = j >> 6, k = j & 63; v = rw1[k*64 + n]; }
  else if ((j -= 4096) < 4096) { int n = j >> 6, k = j & 63; v = rw2[k*64 + n]; }
  else if ((j -= 4096) < 4096) { int n = j >> 6, k = j & 63; v = sw1[k*64 + n]; }
  else if ((j -= 4096) < 4096) { int n = j >> 6, k = j & 63; v = sw2[k*64 + n]; }
  else               { j -= 4096; int n = j >> 6, k = j & 63; v = sw3[k*32 + n]; }
  u16 hi = f2bf(v);
  W[i] = hi;
  W[i + WSTRIDE] = f2bf(v - bf2f(hi));
}

// ---------------- CSR build -------------------------------------------------
__global__ __launch_bounds__(256) void k_zero(int* __restrict__ counts){
  int i = blockIdx.x * 256 + threadIdx.x;
  if (i < NN) counts[i] = 0;
}
__global__ __launch_bounds__(256) void k_count(const int* __restrict__ edst, int* __restrict__ counts){
  int e = blockIdx.x * 256 + threadIdx.x;
  if (e < EE) atomicAdd(&counts[edst[e]], 1);
}
__global__ __launch_bounds__(1024) void k_scan(const int* __restrict__ counts,
                                               int* __restrict__ offs, int* __restrict__ cursor){
  __shared__ int part[1024];
  int t = threadIdx.x;
  int c0 = t * 20, c1 = c0 + 20; if (c1 > NN) c1 = NN; if (c0 > NN) c0 = NN;
  int s = 0;
  for (int i = c0; i < c1; ++i) s += counts[i];
  part[t] = s;
  __syncthreads();
  if (t == 0) {
    int run = 0;
    for (int i = 0; i < 1024; ++i) { int v = part[i]; part[i] = run; run += v; }
    offs[NN] = run;
  }
  __syncthreads();
  int run = part[t];
  for (int i = c0; i < c1; ++i) { offs[i] = run; cursor[i] = run; run += counts[i]; }
}
__global__ __launch_bounds__(256) void k_fill(const int* __restrict__ edst,
                                              int* __restrict__ cursor, int* __restrict__ eids){
  int e = blockIdx.x * 256 + threadIdx.x;
  if (e < EE) { int p = atomicAdd(&cursor[edst[e]], 1); eids[p] = e; }
}
__global__ __launch_bounds__(256) void k_sort(const int* __restrict__ offs, int* __restrict__ eids){
  int n = blockIdx.x * 256 + threadIdx.x;
  if (n >= NN) return;
  int b = offs[n], e = offs[n+1];
  for (int i = b + 1; i < e; ++i) {
    int v = eids[i]; int j = i - 1;
    while (j >= b && eids[j] > v) { eids[j+1] = eids[j]; --j; }
    eids[j+1] = v;
  }
}

// ---------------- MFMA MLP building blocks (128-row tile, 32 rows/wave) -----
// X: LDS tiles [128][72] bf16 hi + lo; B: [out][64] bf16 hi + lo in global.
// Wave w owns rows [w*32, w*32+32): staging, reads and writes all wave-private
// -> NO __syncthreads, in-place layer chaining safe.
// Split accumulators: accA = Xh*Bh ; accB = Xh*Bl + Xl*Bh  (summed in epilogue)
// -> 16 independent MFMA chains per wave (vs 1 in the R4 version).
template<int NI>
__device__ __forceinline__ void gemm_frag2(const u16 (*Xh)[72], const u16 (*Xl)[72],
                                           int wrow, int lane,
                                           const u16* __restrict__ Bh, const u16* __restrict__ Bl,
                                           f32x4 accA[2][4], f32x4 accB[2][4])
{
  const int fr = lane & 15, fc = lane >> 4;
  #pragma unroll
  for (int mi = 0; mi < 2; ++mi)
    #pragma unroll
    for (int ni = 0; ni < NI; ++ni) {
      accA[mi][ni] = (f32x4){0.f, 0.f, 0.f, 0.f};
      accB[mi][ni] = (f32x4){0.f, 0.f, 0.f, 0.f};
    }
  #pragma unroll
  for (int kk = 0; kk < 2; ++kk) {
    bf16x8 ah0 = *(const bf16x8*)&Xh[wrow + fr][kk*32 + fc*8];
    bf16x8 ah1 = *(const bf16x8*)&Xh[wrow + 16 + fr][kk*32 + fc*8];
    bf16x8 al0 = *(const bf16x8*)&Xl[wrow + fr][kk*32 + fc*8];
    bf16x8 al1 = *(const bf16x8*)&Xl[wrow + 16 + fr][kk*32 + fc*8];
    #pragma unroll
    for (int ni = 0; ni < NI; ++ni) {
      bf16x8 bh = *(const bf16x8*)(Bh + (size_t)(ni*16 + fr)*64 + kk*32 + fc*8);
      bf16x8 bl = *(const bf16x8*)(Bl + (size_t)(ni*16 + fr)*64 + kk*32 + fc*8);
      accA[0][ni] = __builtin_amdgcn_mfma_f32_16x16x32_bf16(ah0, bh, accA[0][ni], 0, 0, 0);
      accB[0][ni] = __builtin_amdgcn_mfma_f32_16x16x32_bf16(ah0, bl, accB[0][ni], 0, 0, 0);
      accB[0][ni] = __builtin_amdgcn_mfma_f32_16x16x32_bf16(al0, bh, accB[0][ni], 0, 0, 0);
      accA[1][ni] = __builtin_amdgcn_mfma_f32_16x16x32_bf16(ah1, bh, accA[1][ni], 0, 0, 0);
      accB[1][ni] = __builtin_amdgcn_mfma_f32_16x16x32_bf16(ah1, bl, accB[1][ni], 0, 0, 0);
      accB[1][ni] = __builtin_amdgcn_mfma_f32_16x16x32_bf16(al1, bh, accB[1][ni], 0, 0, 0);
    }
  }
}

// bias (+ optional LN) + SiLU on C fragments, store bf16 hi/lo to H (may == X)
template<bool LN>
__device__ __forceinline__ void act_store2(f32x4 accA[2][4], f32x4 accB[2][4],
    const float* __restrict__ b, const float* __restrict__ g, const float* __restrict__ be,
    u16 (*Hh)[72], u16 (*Hl)[72], int wrow, int lane)
{
  const int fr = lane & 15, fc = lane >> 4;
  float bv[4], gv[4], bev[4];
  #pragma unroll
  for (int ni = 0; ni < 4; ++ni) {
    bv[ni] = b[ni*16 + fr];
    if (LN) { gv[ni] = g[ni*16 + fr]; bev[ni] = be[ni*16 + fr]; }
  }
  #pragma unroll
  for (int mi = 0; mi < 2; ++mi)
    #pragma unroll
    for (int j = 0; j < 4; ++j) {
      int r = wrow + mi*16 + fc*4 + j;
      float x[4];
      #pragma unroll
      for (int ni = 0; ni < 4; ++ni) x[ni] = accA[mi][ni][j] + accB[mi][ni][j] + bv[ni];
      if (LN) {
        float s  = x[0] + x[1] + x[2] + x[3];
        float s2 = x[0]*x[0] + x[1]*x[1] + x[2]*x[2] + x[3]*x[3];
        #pragma unroll
        for (int off = 1; off < 16; off <<= 1) {
          s  += __shfl_xor(s,  off);
          s2 += __shfl_xor(s2, off);
        }
        float mu  = s * (1.f/64.f);
        float var = s2 * (1.f/64.f) - mu*mu;
        float rs  = rsqrtf(var + 1e-6f);
        #pragma unroll
        for (int ni = 0; ni < 4; ++ni) x[ni] = (x[ni] - mu)*rs*gv[ni] + bev[ni];
      }
      #pragma unroll
      for (int ni = 0; ni < 4; ++ni) {
        float y = x[ni];
        y = y / (1.f + __expf(-y));
        union { float f; u32 u; } c; c.f = y;
        union { u32 u; float f; } hf; hf.u = c.u & 0xFFFF0000u;
        Hh[r][ni*16 + fr] = (u16)(c.u >> 16);
        Hl[r][ni*16 + fr] = f2bf(y - hf.f);
      }
    }
}

// stage 128x64 fp32 rows -> Xh/Xl (wave-private rows: tid>>1 in [w*32,w*32+32))
__device__ __forceinline__ void stage_f32(const float* __restrict__ src, size_t row_stride,
                                          int e0, int tid, u16 (*Xh)[72], u16 (*Xl)[72])
{
  int r = tid >> 1, cb = (tid & 1) * 32;
  const float* p = src + (size_t)(e0 + r)*row_stride + cb;
  u32* dh = (u32*)&Xh[r][cb];
  u32* dl = (u32*)&Xl[r][cb];
  #pragma unroll
  for (int q = 0; q < 8; ++q) {
    float4 v = *(const float4*)(p + q*4);
    u32 h0, l0, h1, l1;
    split2(v.x, v.y, h0, l0);
    split2(v.z, v.w, h1, l1);
    dh[q*2] = h0; dh[q*2+1] = h1;
    dl[q*2] = l0; dl[q*2+1] = l1;
  }
}

// ---------------- alpha MLP (elen -> alpha[E,4]) ----------------------------
__global__ __launch_bounds__(256) void k_alpha_m(
  const float* __restrict__ elen, const u16* __restrict__ Wm,
  const float* __restrict__ b1, const float* __restrict__ g1, const float* __restrict__ be1,
  const float* __restrict__ b2, const float* __restrict__ g2, const float* __restrict__ be2,
  const float* __restrict__ b3,
  float* __restrict__ alpha_g)
{
  __shared__ u16 Xh[128][72], Xl[128][72];
  const u16* Wa1 = Wm;
  const u16* Wa2 = Wm + 4096;
  const u16* Wa3 = Wm + 8192;
  const int tid = threadIdx.x;
  const int wave = tid >> 6, lane = tid & 63;
  const int fr = lane & 15, fc = lane >> 4;
  const int wrow = wave * 32;
  const int e0 = blockIdx.x * 128;
  stage_f32(elen, 64, e0, tid, Xh, Xl);
  f32x4 accA[2][4], accB[2][4];
  gemm_frag2<4>(Xh, Xl, wrow, lane, Wa1, Wa1 + WSTRIDE, accA, accB);
  act_store2<true>(accA, accB, b1, g1, be1, Xh, Xl, wrow, lane);
  gemm_frag2<4>(Xh, Xl, wrow, lane, Wa2, Wa2 + WSTRIDE, accA, accB);
  act_store2<true>(accA, accB, b2, g2, be2, Xh, Xl, wrow, lane);
  gemm_frag2<1>(Xh, Xl, wrow, lane, Wa3, Wa3 + WSTRIDE, accA, accB);
  {
    float bv = (fr < 4) ? b3[fr] : 0.f;
    #pragma unroll
    for (int mi = 0; mi < 2; ++mi)
      #pragma unroll
      for (int j = 0; j < 4; ++j) {
        int r = wrow + mi*16 + fc*4 + j;
        float v = accA[mi][0][j] + accB[mi][0][j] + bv;
        if (fr < 4) alpha_g[(size_t)(e0 + r)*4 + fr] = v;
      }
  }
}

// ---------------- radial MLP + sh contraction -------------------------------
__global__ __launch_bounds__(256) void k_radial_m(
  const float* __restrict__ elen, const float* __restrict__ esh,
  const u16* __restrict__ Wm,
  const float* __restrict__ tb1, const float* __restrict__ tb2,
  const float* __restrict__ alpha_g,
  float* __restrict__ scal_g, float* __restrict__ cbuf_g)
{
  __shared__ u16 Xh[128][72], Xl[128][72];
  const u16* Wr1 = Wm + 9216;
  const u16* Wr2 = Wm + 13312;
  const int tid = threadIdx.x;
  const int wave = tid >> 6, lane = tid & 63;
  const int fr = lane & 15, fc = lane >> 4;
  const int wrow = wave * 32;
  const int e0 = blockIdx.x * 128;
  stage_f32(elen, 64, e0, tid, Xh, Xl);
  f32x4 accA[2][4], accB[2][4];
  gemm_frag2<4>(Xh, Xl, wrow, lane, Wr1, Wr1 + WSTRIDE, accA, accB);
  act_store2<false>(accA, accB, tb1, nullptr, nullptr, Xh, Xl, wrow, lane);
  gemm_frag2<4>(Xh, Xl, wrow, lane, Wr2, Wr2 + WSTRIDE, accA, accB);
  {
    float bv[4];
    #pragma unroll
    for (int ni = 0; ni < 4; ++ni) bv[ni] = tb2[ni*16 + fr];
    #pragma unroll
    for (int mi = 0; mi < 2; ++mi)
      #pragma unroll
      for (int j = 0; j < 4; ++j) {
        int r = wrow + mi*16 + fc*4 + j;
        float shv = esh[(size_t)(e0 + r)*16 + fr];
        float sc[4];
        #pragma unroll
        for (int ni = 0; ni < 4; ++ni) {
          float t = (accA[mi][ni][j] + accB[mi][ni][j] + bv[ni]) * shv;
          #pragma unroll
          for (int off = 1; off < 16; off <<= 1) t += __shfl_xor(t, off);
          sc[ni] = t;
        }
        if (fr == 0) {
          float4 av = *(const float4*)(alpha_g + (size_t)(e0 + r)*4);
          float4 sv; sv.x = sc[0]; sv.y = sc[1]; sv.z = sc[2]; sv.w = sc[3];
          *(float4*)(scal_g + (size_t)(e0 + r)*4) = sv;
          float4 cv;
          cv.x = sc[0]*av.x; cv.y = sc[1]*av.y; cv.z = sc[2]*av.z; cv.w = sc[3]*av.w;
          *(float4*)(cbuf_g + (size_t)(e0 + r)*4) = cv;
        }
      }
  }
}

// ---------------- MFMA s-MLP (y0 -> edge_scalar[E,32]) ----------------------
__global__ __launch_bounds__(256) void k_smlp2(
  const u16* __restrict__ y0b, const u16* __restrict__ Wm,
  const float* __restrict__ b1, const float* __restrict__ g1, const float* __restrict__ be1,
  const float* __restrict__ b2, const float* __restrict__ g2, const float* __restrict__ be2,
  const float* __restrict__ b3,
  float* __restrict__ oute)
{
  __shared__ u16 Xh[128][72], Xl[128][72];
  const u16* Ws1 = Wm + 17408;
  const u16* Ws2 = Wm + 21504;
  const u16* Ws3 = Wm + 25600;
  const int tid = threadIdx.x;
  const int wave = tid >> 6, lane = tid & 63;
  const int fr = lane & 15, fc = lane >> 4;
  const int wrow = wave * 32;
  const int e0 = blockIdx.x * 128;
  {
    int r = tid >> 1, cb = (tid & 1) * 32;
    const uint4* p = (const uint4*)(y0b + (size_t)(e0 + r)*64 + cb);
    uint4* dh = (uint4*)&Xh[r][cb];
    uint4* dl = (uint4*)&Xl[r][cb];
    uint4 z; z.x = 0; z.y = 0; z.z = 0; z.w = 0;
    dh[0] = p[0]; dh[1] = p[1]; dh[2] = p[2]; dh[3] = p[3];
    dl[0] = z; dl[1] = z; dl[2] = z; dl[3] = z;
  }
  f32x4 accA[2][4], accB[2][4];
  gemm_frag2<4>(Xh, Xl, wrow, lane, Ws1, Ws1 + WSTRIDE, accA, accB);
  act_store2<true>(accA, accB, b1, g1, be1, Xh, Xl, wrow, lane);
  gemm_frag2<4>(Xh, Xl, wrow, lane, Ws2, Ws2 + WSTRIDE, accA, accB);
  act_store2<true>(accA, accB, b2, g2, be2, Xh, Xl, wrow, lane);
  gemm_frag2<2>(Xh, Xl, wrow, lane, Ws3, Ws3 + WSTRIDE, accA, accB);
  {
    float bv[2];
    bv[0] = b3[fr]; bv[1] = b3[16 + fr];
    #pragma unroll
    for (int mi = 0; mi < 2; ++mi)
      #pragma unroll
      for (int j = 0; j < 4; ++j) {
        int r = wrow + mi*16 + fc*4 + j;
        #pragma unroll
        for (int ni = 0; ni < 2; ++ni)
          oute[(size_t)(e0 + r)*32 + ni*16 + fr] = accA[mi][ni][j] + accB[mi][ni][j] + bv[ni];
      }
  }
}

// ---------------- G1: msg = [x_src|x_dst|elen] @ pre_lin_w  (bf16 out) ------
__global__ __launch_bounds__(256) void g1_msg(
    const float* __restrict__ node_in, const float* __restrict__ elen,
    const int* __restrict__ esrc, const int* __restrict__ edst,
    const u16* __restrict__ Bt1, u16* __restrict__ msgb)
{
  __shared__ u16 As[128][40];
  __shared__ u16 Bs[128][40];
  const int tid = threadIdx.x;
  const int e0 = blockIdx.x * 128;
  const int wave = tid >> 6, lane = tid & 63;
  const int wr = (wave >> 1) * 64, wc = (wave & 1) * 64;
  const int fr = lane & 15, fc = lane >> 4;
  f32x4 acc[4][4] = {};
  const int r = tid >> 1, half = tid & 1;
  const int e = e0 + r;
  const int s_idx = esrc[e], d_idx = edst[e];
  for (int k0 = 0; k0 < 320; k0 += 32) {
    const int kk = k0 + half * 16;
    const float* ap;
    if (kk < 128)      ap = node_in + (size_t)s_idx*128 + kk;
    else if (kk < 256) ap = node_in + (size_t)d_idx*128 + (kk - 128);
    else               ap = elen + (size_t)e*64 + (kk - 256);
    u32* asp = (u32*)&As[r][half*16];
    #pragma unroll
    for (int q = 0; q < 4; ++q) {
      float4 v = *(const float4*)(ap + q*4);
      asp[q*2]   = pack2(v.x, v.y);
      asp[q*2+1] = pack2(v.z, v.w);
    }
    const uint4* bp = (const uint4*)(Bt1 + (size_t)r*320 + kk);
    *(uint4*)&Bs[r][half*16]     = bp[0];
    *(uint4*)&Bs[r][half*16 + 8] = bp[1];
    __syncthreads();
    bf16x8 a[4], b[4];
    #pragma unroll
    for (int mi = 0; mi < 4; ++mi) a[mi] = *(const bf16x8*)&As[wr + mi*16 + fr][fc*8];
    #pragma unroll
    for (int ni = 0; ni < 4; ++ni) b[ni] = *(const bf16x8*)&Bs[wc + ni*16 + fr][fc*8];
    #pragma unroll
    for (int mi = 0; mi < 4; ++mi)
      #pragma unroll
      for (int ni = 0; ni < 4; ++ni)
        acc[mi][ni] = __builtin_amdgcn_mfma_f32_16x16x32_bf16(a[mi], b[ni], acc[mi][ni], 0, 0, 0);
    __syncthreads();
  }
  #pragma unroll
  for (int mi = 0; mi < 4; ++mi)
    #pragma unroll
    for (int j = 0; j < 4; ++j) {
      int row = wr + mi*16 + fc*4 + j;
      size_t base = (size_t)(e0 + row)*128 + wc + fr;
      #pragma unroll
      for (int ni = 0; ni < 4; ++ni)
        msgb[base + ni*16] = f2bf(acc[mi][ni][j]);
    }
}

// ---------------- G2: t = msg @ Wcat ; y0 = sum_h c[h]*t[:,h*64+j] ----------
union G2Smem {
  struct { u16 As[64][40]; u16 Bs[256][40]; } s;
  float R[2][64][66];
};
__global__ __launch_bounds__(256) void g2_y0(
    const u16* __restrict__ msgb, const u16* __restrict__ Bt2,
    const float* __restrict__ cbuf, u16* __restrict__ y0b)
{
  __shared__ G2Smem u;
  __shared__ float cS[64][4];
  const int tid = threadIdx.x, wave = tid >> 6, lane = tid & 63;
  const int e0 = blockIdx.x * 64;
  const int fr = lane & 15, fc = lane >> 4;
  cS[tid >> 2][tid & 3] = cbuf[(size_t)e0*4 + tid];
  f32x4 acc[4][4] = {};
  for (int k0 = 0; k0 < 128; k0 += 32) {
    { // stage A (64 x 32)
      int r = tid >> 2, q = tid & 3;
      *(uint4*)&u.s.As[r][q*8] = *(const uint4*)(msgb + (size_t)(e0 + r)*128 + k0 + q*8);
    }
    { // stage B (256 x 32)
      const uint4* bp = (const uint4*)(Bt2 + (size_t)tid*128 + k0);
      *(uint4*)&u.s.Bs[tid][0]  = bp[0];
      *(uint4*)&u.s.Bs[tid][8]  = bp[1];
      *(uint4*)&u.s.Bs[tid][16] = bp[2];
      *(uint4*)&u.s.Bs[tid][24] = bp[3];
    }
    __syncthreads();
    bf16x8 a[4], b[4];
    #pragma unroll
    for (int mi = 0; mi < 4; ++mi) a[mi] = *(const bf16x8*)&u.s.As[mi*16 + fr][fc*8];
    #pragma unroll
    for (int ni = 0; ni < 4; ++ni) b[ni] = *(const bf16x8*)&u.s.Bs[wave*64 + ni*16 + fr][fc*8];
    #pragma unroll
    for (int mi = 0; mi < 4; ++mi)
      #pragma unroll
      for (int ni = 0; ni < 4; ++ni)
        acc[mi][ni] = __builtin_amdgcn_mfma_f32_16x16x32_bf16(a[mi], b[ni], acc[mi][ni], 0, 0, 0);
    __syncthreads();
  }
  const int h = wave;
  if ((wave & 1) == 0) {
    float (*Rb)[66] = u.R[wave >> 1];
    #pragma unroll
    for (int mi = 0; mi < 4; ++mi)
      #pragma unroll
      for (int j = 0; j < 4; ++j) {
        int row = mi*16 + fc*4 + j;
        float cv = cS[row][h];
        #pragma unroll
        for (int ni = 0; ni < 4; ++ni)
          Rb[row][ni*16 + fr] = acc[mi][ni][j] * cv;
      }
  }
  __syncthreads();
  if (wave & 1) {
    float (*Rb)[66] = u.R[wave >> 1];
    #pragma unroll
    for (int mi = 0; mi < 4; ++mi)
      #pragma unroll
      for (int j = 0; j < 4; ++j) {
        int row = mi*16 + fc*4 + j;
        float cv = cS[row][h];
        #pragma unroll
        for (int ni = 0; ni < 4; ++ni)
          Rb[row][ni*16 + fr] += acc[mi][ni][j] * cv;
      }
  }
  __syncthreads();
  {
    int rr = tid >> 2, j0 = (tid & 3) * 16;
    u16 tmp[16];
    #pragma unroll
    for (int i = 0; i < 16; ++i)
      tmp[i] = f2bf(u.R[0][rr][j0 + i] + u.R[1][rr][j0 + i]);
    uint4* dst = (uint4*)(y0b + (size_t)(e0 + rr)*64 + j0);
    dst[0] = *(const uint4*)&tmp[0];
    dst[1] = *(const uint4*)&tmp[8];
  }
}

// ---------------- K9: per-node softmax + aggregation ------------------------
__global__ __launch_bounds__(256) void k_node(
  const int* __restrict__ offs, const int* __restrict__ eids,
  const float* __restrict__ alpha, const float* __restrict__ scal,
  const u16* __restrict__ msgb, u16* __restrict__ nfb)
{
  const int w = threadIdx.x >> 6, lane = threadIdx.x & 63;
  const int n = blockIdx.x * 4 + w;
  const int beg = offs[n], end = offs[n+1];
  float m0=-3e38f, m1=-3e38f, m2=-3e38f, m3=-3e38f;
  for (int i = beg + lane; i < end; i += 64) {
    int eid = eids[i];
    float4 a = *(const float4*)(alpha + (size_t)eid*4);
    m0 = fmaxf(m0, a.x); m1 = fmaxf(m1, a.y);
    m2 = fmaxf(m2, a.z); m3 = fmaxf(m3, a.w);
  }
  #pragma unroll
  for (int off = 1; off < 64; off <<= 1) {
    m0 = fmaxf(m0, __shfl_xor(m0, off));
    m1 = fmaxf(m1, __shfl_xor(m1, off));
    m2 = fmaxf(m2, __shfl_xor(m2, off));
    m3 = fmaxf(m3, __shfl_xor(m3, off));
  }
  float se0=0.f, se1=0.f, se2=0.f, se3=0.f;
  float f00=0.f, f01=0.f, f10=0.f, f11=0.f, f20=0.f, f21=0.f, f30=0.f, f31=0.f;
  for (int i = beg; i < end; ++i) {
    int eid = eids[i];
    float4 a = *(const float4*)(alpha + (size_t)eid*4);
    float4 s = *(const float4*)(scal + (size_t)eid*4);
    float e0 = __expf(a.x - m0), e1 = __expf(a.y - m1);
    float e2 = __expf(a.z - m2), e3 = __expf(a.w - m3);
    se0 += e0; se1 += e1; se2 += e2; se3 += e3;
    float w0 = e0*s.x, w1 = e1*s.y, w2 = e2*s.z, w3 = e3*s.w;
    float v0 = bf2f(msgb[(size_t)eid*128 + lane]);
    float v1 = bf2f(msgb[(size_t)eid*128 + 64 + lane]);
    f00 = fmaf(w0, v0, f00); f01 = fmaf(w0, v1, f01);
    f10 = fmaf(w1, v0, f10); f11 = fmaf(w1, v1, f11);
    f20 = fmaf(w2, v0, f20); f21 = fmaf(w2, v1, f21);
    f30 = fmaf(w3, v0, f30); f31 = fmaf(w3, v1, f31);
  }
  float i0 = 1.f/(se0 + 1e-16f), i1 = 1.f/(se1 + 1e-16f);
  float i2 = 1.f/(se2 + 1e-16f), i3 = 1.f/(se3 + 1e-16f);
  size_t b = (size_t)n * 512;
  nfb[b + 0*128 + lane]      = f2bf(f00*i0);
  nfb[b + 0*128 + 64 + lane] = f2bf(f01*i0);
  nfb[b + 1*128 + lane]      = f2bf(f10*i1);
  nfb[b + 1*128 + 64 + lane] = f2bf(f11*i1);
  nfb[b + 2*128 + lane]      = f2bf(f20*i2);
  nfb[b + 2*128 + 64 + lane] = f2bf(f21*i2);
  nfb[b + 3*128 + lane]      = f2bf(f30*i3);
  nfb[b + 3*128 + 64 + lane] = f2bf(f31*i3);
}

// ---------------- G10: node_out = node_fea @ lin_w --------------------------
__global__ __launch_bounds__(256) void g10_out(
    const u16* __restrict__ nfb, const u16* __restrict__ Bt3,
    float* __restrict__ out)
{
  __shared__ u16 As[128][40];
  __shared__ u16 Bs[128][40];
  const int tid = threadIdx.x;
  const int n0 = blockIdx.x * 128;
  const int wave = tid >> 6, lane = tid & 63;
  const int wr = (wave >> 1) * 64, wc = (wave & 1) * 64;
  const int fr = lane & 15, fc = lane >> 4;
  f32x4 acc[4][4] = {};
  const int r = tid >> 1, half = tid & 1;
  const int n = n0 + r;
  for (int k0 = 0; k0 < 512; k0 += 32) {
    uint4 z; z.x=0; z.y=0; z.z=0; z.w=0;
    uint4 v0 = z, v1 = z;
    if (n < NN) {
      const uint4* apv = (const uint4*)(nfb + (size_t)n*512 + k0 + half*16);
      v0 = apv[0]; v1 = apv[1];
    }
    *(uint4*)&As[r][half*16]     = v0;
    *(uint4*)&As[r][half*16 + 8] = v1;
    const uint4* bp = (const uint4*)(Bt3 + (size_t)r*512 + k0 + half*16);
    *(uint4*)&Bs[r][half*16]     = bp[0];
    *(uint4*)&Bs[r][half*16 + 8] = bp[1];
    __syncthreads();
    bf16x8 a[4], b[4];
    #pragma unroll
    for (int mi = 0; mi < 4; ++mi) a[mi] = *(const bf16x8*)&As[wr + mi*16 + fr][fc*8];
    #pragma unroll
    for (int ni = 0; ni < 4; ++ni) b[ni] = *(const bf16x8*)&Bs[wc + ni*16 + fr][fc*8];
    #pragma unroll
    for (int mi = 0; mi < 4; ++mi)
      #pragma unroll
      for (int ni = 0; ni < 4; ++ni)
        acc[mi][ni] = __builtin_amdgcn_mfma_f32_16x16x32_bf16(a[mi], b[ni], acc[mi][ni], 0, 0, 0);
    __syncthreads();
  }
  #pragma unroll
  for (int mi = 0; mi < 4; ++mi)
    #pragma unroll
    for (int j = 0; j < 4; ++j) {
      int rowg = n0 + wr + mi*16 + fc*4 + j;
      if (rowg < NN) {
        size_t base = (size_t)rowg*128 + wc + fr;
        #pragma unroll
        for (int ni = 0; ni < 4; ++ni)
          out[base + ni*16] = acc[mi][ni][j];
      }
    }
}

// ---------------- launch ----------------------------------------------------
extern "C" void kernel_launch(void* const* d_in, const int* in_sizes, int n_in,
                              void* d_out, int out_size, void* d_ws, size_t ws_size,
                              hipStream_t stream)
{
  const float* node_in    = (const float*)d_in[0];
  const float* edge_sh    = (const float*)d_in[2];
  const float* elen       = (const float*)d_in[3];
  const int*   esrc       = (const int*)d_in[4];
  const int*   edst       = (const int*)d_in[5];
  const float* pre_lin_w  = (const float*)d_in[7];
  const float* tp2_w1     = (const float*)d_in[8];
  const float* tp2_b1     = (const float*)d_in[9];
  const float* tp2_w2     = (const float*)d_in[10];
  const float* tp2_b2     = (const float*)d_in[11];
  const float* a_w1  = (const float*)d_in[12];
  const float* a_b1  = (const float*)d_in[13];
  const float* a_g1  = (const float*)d_in[14];
  const float* a_be1 = (const float*)d_in[15];
  const float* a_w2  = (const float*)d_in[16];
  const float* a_b2  = (const float*)d_in[17];
  const float* a_g2  = (const float*)d_in[18];
  const float* a_be2 = (const float*)d_in[19];
  const float* a_w3  = (const float*)d_in[20];
  const float* a_b3  = (const float*)d_in[21];
  const float* lin_w      = (const float*)d_in[22];
  const float* lin_edge_w = (const float*)d_in[23];
  const float* s_w1  = (const float*)d_in[24];
  const float* s_b1  = (const float*)d_in[25];
  const float* s_g1  = (const float*)d_in[26];
  const float* s_be1 = (const float*)d_in[27];
  const float* s_w2  = (const float*)d_in[28];
  const float* s_b2  = (const float*)d_in[29];
  const float* s_g2  = (const float*)d_in[30];
  const float* s_be2 = (const float*)d_in[31];
  const float* s_w3  = (const float*)d_in[32];
  const float* s_b3  = (const float*)d_in[33];

  float* out_node = (float*)d_out;
  float* out_edge = out_node + (size_t)NN * 128;

  char* ws = (char*)d_ws;
  size_t off = 0;
  auto take = [&](size_t bytes) -> char* {
    char* p = ws + off;
    off = (off + bytes + 255) & ~(size_t)255;
    return p;
  };
  u16*   msgb   = (u16*)take((size_t)EE * 128 * 2);
  u16*   y0b    = (u16*)take((size_t)EE * 64 * 2);
  u16*   nfb    = (u16*)take((size_t)NN * 512 * 2);
  float* alpha  = (float*)take((size_t)EE * 4 * 4);
  float* scal   = (float*)take((size_t)EE * 4 * 4);
  float* cbuf   = (float*)take((size_t)EE * 4 * 4);
  int*   counts = (int*)take((size_t)NN * 4);
  int*   offs   = (int*)take((size_t)(NN + 1) * 4);
  int*   cursor = (int*)take((size_t)NN * 4);
  int*   eids   = (int*)take((size_t)EE * 4);
  u16*   Bt1    = (u16*)take((size_t)128 * 320 * 2);
  u16*   Bt2    = (u16*)take((size_t)256 * 128 * 2);
  u16*   Bt3    = (u16*)take((size_t)128 * 512 * 2);
  u16*   Wmlp   = (u16*)take((size_t)WSTRIDE * 2 * 2);

  k_prep<<<544, 256, 0, stream>>>(pre_lin_w, lin_edge_w, lin_w, Bt1, Bt2, Bt3);
  k_prep2<<<(WSTRIDE + 255)/256, 256, 0, stream>>>(a_w1, a_w2, a_w3, tp2_w1, tp2_w2,
                                                   s_w1, s_w2, s_w3, Wmlp);
  k_zero<<<(NN + 255)/256, 256, 0, stream>>>(counts);
  k_count<<<EE/256, 256, 0, stream>>>(edst, counts);
  k_scan<<<1, 1024, 0, stream>>>(counts, offs, cursor);
  k_fill<<<EE/256, 256, 0, stream>>>(edst, cursor, eids);
  k_sort<<<(NN + 255)/256, 256, 0, stream>>>(offs, eids);
  k_alpha_m<<<EE/128, 256, 0, stream>>>(elen, Wmlp, a_b1, a_g1, a_be1,
                                        a_b2, a_g2, a_be2, a_b3, alpha);
  k_radial_m<<<EE/128, 256, 0, stream>>>(elen, edge_sh, Wmlp, tp2_b1, tp2_b2,
                                         alpha, scal, cbuf);
  g1_msg<<<EE/128, 256, 0, stream>>>(node_in, elen, esrc, edst, Bt1, msgb);
  g2_y0<<<EE/64, 256, 0, stream>>>(msgb, Bt2, cbuf, y0b);
  k_smlp2<<<EE/128, 256, 0, stream>>>(y0b, Wmlp, s_b1, s_g1, s_be1,
                                      s_b2, s_g2, s_be2, s_b3, out_edge);
  k_node<<<NN/4, 256, 0, stream>>>(offs, eids, alpha, scal, msgb, nfb);
  g10_out<<<(NN + 127)/128, 256, 0, stream>>>(nfb, Bt3, out_node);
}

// Round 6
// 594.796 us; speedup vs baseline: 1.0954x; 1.0083x over previous
//
#include <hip/hip_runtime.h>

#define NN 20000
#define EE 320000
#define WSTRIDE 27648

typedef unsigned short u16;
typedef unsigned int u32;
typedef __attribute__((ext_vector_type(8))) short bf16x8;
typedef __attribute__((ext_vector_type(4))) float f32x4;

__device__ __forceinline__ float bf2f(u16 u){
  union { u32 i; float f; } v; v.i = ((u32)u) << 16; return v.f;
}
__device__ __forceinline__ u16 f2bf(float f){
  union { float f; u32 i; } v; v.f = f;
  u32 i = v.i;
  return (u16)((i + 0x7FFFu + ((i >> 16) & 1u)) >> 16);
}
__device__ __forceinline__ u32 pack2(float a, float b){
  return ((u32)f2bf(b) << 16) | (u32)f2bf(a);
}
// cheap split: hi = truncated top-16, lo = rne(residual). total rel err ~2^-17
__device__ __forceinline__ void split2(float a, float b, u32& hi, u32& lo){
  union { float f; u32 u; } ua, ub; ua.f = a; ub.f = b;
  u32 ha = ua.u & 0xFFFF0000u, hb = ub.u & 0xFFFF0000u;
  union { u32 u; float f; } fa, fb; fa.u = ha; fb.u = hb;
  u16 la = f2bf(a - fa.f), lb = f2bf(b - fb.f);
  hi = hb | (ha >> 16);
  lo = ((u32)lb << 16) | la;
}

// ---------------- weight pre-transpose (to bf16, [n][k] layout) -------------
__global__ __launch_bounds__(256) void k_prep(
    const float* __restrict__ plw, const float* __restrict__ lew,
    const float* __restrict__ lw,
    u16* __restrict__ Bt1, u16* __restrict__ Bt2, u16* __restrict__ Bt3)
{
  int i = blockIdx.x * 256 + threadIdx.x;
  if (i < 128*320) {                       // Bt1[n][k] = pre_lin_w[k][n]
    int n = i / 320, k = i % 320;
    Bt1[i] = f2bf(plw[k*128 + n]);
  }
  int j = i - 128*320;
  if (j >= 0 && j < 256*128) {             // Bt2[h*64+c][k] = lin_edge_w[h*128+k][c]
    int n = j / 128, k = j % 128;
    int h = n >> 6, c = n & 63;
    Bt2[j] = f2bf(lew[(h*128 + k)*64 + c]);
  }
  int l = i - 128*320 - 256*128;
  if (l >= 0 && l < 128*512) {             // Bt3[n][k] = lin_w[k][n]
    int n = l / 512, k = l % 512;
    Bt3[l] = f2bf(lw[k*128 + n]);
  }
}

// MLP weights, transposed to [out][in], stored as hi (at i) + lo (at i+WSTRIDE).
__global__ __launch_bounds__(256) void k_prep2(
    const float* __restrict__ aw1, const float* __restrict__ aw2, const float* __restrict__ aw3,
    const float* __restrict__ rw1, const float* __restrict__ rw2,
    const float* __restrict__ sw1, const float* __restrict__ sw2, const float* __restrict__ sw3,
    u16* __restrict__ W)
{
  int i = blockIdx.x * 256 + threadIdx.x;
  if (i >= WSTRIDE) return;
  float v = 0.f;
  int j = i;
  if (j < 4096)      { int n = j >> 6, k = j & 63; v = aw1[k*64 + n]; }
  else if ((j -= 4096) < 4096) { int n = j >> 6, k = j & 63; v = aw2[k*64 + n]; }
  else if ((j -= 4096) < 1024) { int n = j >> 6, k = j & 63; v = (n < 4) ? aw3[k*4 + n] : 0.f; }
  else if ((j -= 1024) < 4096) { int n = j >> 6, k = j & 63; v = rw1[k*64 + n]; }
  else if ((j -= 4096) < 4096) { int n = j >> 6, k = j & 63; v = rw2[k*64 + n]; }
  else if ((j -= 4096) < 4096) { int n = j >> 6, k = j & 63; v = sw1[k*64 + n]; }
  else if ((j -= 4096) < 4096) { int n = j >> 6, k = j & 63; v = sw2[k*64 + n]; }
  else               { j -= 4096; int n = j >> 6, k = j & 63; v = sw3[k*32 + n]; }
  u16 hi = f2bf(v);
  W[i] = hi;
  W[i + WSTRIDE] = f2bf(v - bf2f(hi));
}

// elen fp32 -> bf16 hi/lo planes (written into msgb space, dead until g1)
__global__ __launch_bounds__(256) void k_prep3(
    const float* __restrict__ elen, u16* __restrict__ eh, u16* __restrict__ el)
{
  size_t i = (size_t)blockIdx.x * 256 + threadIdx.x;   // one thread = 8 elems
  const float* p = elen + i*8;
  float4 a = ((const float4*)p)[0];
  float4 b = ((const float4*)p)[1];
  u32 h[4], l[4];
  split2(a.x, a.y, h[0], l[0]); split2(a.z, a.w, h[1], l[1]);
  split2(b.x, b.y, h[2], l[2]); split2(b.z, b.w, h[3], l[3]);
  uint4 vh; vh.x=h[0]; vh.y=h[1]; vh.z=h[2]; vh.w=h[3];
  uint4 vl; vl.x=l[0]; vl.y=l[1]; vl.z=l[2]; vl.w=l[3];
  *(uint4*)(eh + i*8) = vh;
  *(uint4*)(el + i*8) = vl;
}

// ---------------- CSR build -------------------------------------------------
__global__ __launch_bounds__(256) void k_zero(int* __restrict__ counts){
  int i = blockIdx.x * 256 + threadIdx.x;
  if (i < NN) counts[i] = 0;
}
__global__ __launch_bounds__(256) void k_count(const int* __restrict__ edst, int* __restrict__ counts){
  int e = blockIdx.x * 256 + threadIdx.x;
  if (e < EE) atomicAdd(&counts[edst[e]], 1);
}
__global__ __launch_bounds__(1024) void k_scan(const int* __restrict__ counts,
                                               int* __restrict__ offs, int* __restrict__ cursor){
  __shared__ int part[1024];
  int t = threadIdx.x;
  int c0 = t * 20, c1 = c0 + 20; if (c1 > NN) c1 = NN; if (c0 > NN) c0 = NN;
  int s = 0;
  for (int i = c0; i < c1; ++i) s += counts[i];
  part[t] = s;
  __syncthreads();
  if (t == 0) {
    int run = 0;
    for (int i = 0; i < 1024; ++i) { int v = part[i]; part[i] = run; run += v; }
    offs[NN] = run;
  }
  __syncthreads();
  int run = part[t];
  for (int i = c0; i < c1; ++i) { offs[i] = run; cursor[i] = run; run += counts[i]; }
}
__global__ __launch_bounds__(256) void k_fill(const int* __restrict__ edst,
                                              int* __restrict__ cursor, int* __restrict__ eids){
  int e = blockIdx.x * 256 + threadIdx.x;
  if (e < EE) { int p = atomicAdd(&cursor[edst[e]], 1); eids[p] = e; }
}
__global__ __launch_bounds__(256) void k_sort(const int* __restrict__ offs, int* __restrict__ eids){
  int n = blockIdx.x * 256 + threadIdx.x;
  if (n >= NN) return;
  int b = offs[n], e = offs[n+1];
  for (int i = b + 1; i < e; ++i) {
    int v = eids[i]; int j = i - 1;
    while (j >= b && eids[j] > v) { eids[j+1] = eids[j]; --j; }
    eids[j+1] = v;
  }
}

// ---------------- MFMA MLP building blocks (128-row tile, 32 rows/wave) -----
// Wave w owns rows [w*32, w*32+32): all LDS traffic wave-private -> no barriers.
// Split accumulators: accA = Xh*Bh ; accB = Xh*Bl (+ Xl*Bh) -> 16 indep chains.
template<int NI, bool LOA>
__device__ __forceinline__ void gemm_lds(const u16 (*Xh)[72], const u16 (*Xl)[72],
                                         int wrow, int lane,
                                         const u16* __restrict__ Bh, const u16* __restrict__ Bl,
                                         f32x4 accA[2][4], f32x4 accB[2][4])
{
  const int fr = lane & 15, fc = lane >> 4;
  #pragma unroll
  for (int mi = 0; mi < 2; ++mi)
    #pragma unroll
    for (int ni = 0; ni < NI; ++ni) {
      accA[mi][ni] = (f32x4){0.f, 0.f, 0.f, 0.f};
      accB[mi][ni] = (f32x4){0.f, 0.f, 0.f, 0.f};
    }
  #pragma unroll
  for (int kk = 0; kk < 2; ++kk) {
    bf16x8 ah0 = *(const bf16x8*)&Xh[wrow + fr][kk*32 + fc*8];
    bf16x8 ah1 = *(const bf16x8*)&Xh[wrow + 16 + fr][kk*32 + fc*8];
    bf16x8 al0 = {}, al1 = {};
    if constexpr (LOA) {
      al0 = *(const bf16x8*)&Xl[wrow + fr][kk*32 + fc*8];
      al1 = *(const bf16x8*)&Xl[wrow + 16 + fr][kk*32 + fc*8];
    }
    #pragma unroll
    for (int ni = 0; ni < NI; ++ni) {
      bf16x8 bh = *(const bf16x8*)(Bh + (size_t)(ni*16 + fr)*64 + kk*32 + fc*8);
      bf16x8 bl = *(const bf16x8*)(Bl + (size_t)(ni*16 + fr)*64 + kk*32 + fc*8);
      accA[0][ni] = __builtin_amdgcn_mfma_f32_16x16x32_bf16(ah0, bh, accA[0][ni], 0, 0, 0);
      accB[0][ni] = __builtin_amdgcn_mfma_f32_16x16x32_bf16(ah0, bl, accB[0][ni], 0, 0, 0);
      if constexpr (LOA)
        accB[0][ni] = __builtin_amdgcn_mfma_f32_16x16x32_bf16(al0, bh, accB[0][ni], 0, 0, 0);
      accA[1][ni] = __builtin_amdgcn_mfma_f32_16x16x32_bf16(ah1, bh, accA[1][ni], 0, 0, 0);
      accB[1][ni] = __builtin_amdgcn_mfma_f32_16x16x32_bf16(ah1, bl, accB[1][ni], 0, 0, 0);
      if constexpr (LOA)
        accB[1][ni] = __builtin_amdgcn_mfma_f32_16x16x32_bf16(al1, bh, accB[1][ni], 0, 0, 0);
    }
  }
}

// A-fragments straight from global bf16 hi/lo planes (row stride 64)
template<int NI>
__device__ __forceinline__ void gemm_glb(const u16* __restrict__ Xh, const u16* __restrict__ Xl,
                                         int row0, int lane,
                                         const u16* __restrict__ Bh, const u16* __restrict__ Bl,
                                         f32x4 accA[2][4], f32x4 accB[2][4])
{
  const int fr = lane & 15, fc = lane >> 4;
  #pragma unroll
  for (int mi = 0; mi < 2; ++mi)
    #pragma unroll
    for (int ni = 0; ni < NI; ++ni) {
      accA[mi][ni] = (f32x4){0.f, 0.f, 0.f, 0.f};
      accB[mi][ni] = (f32x4){0.f, 0.f, 0.f, 0.f};
    }
  #pragma unroll
  for (int kk = 0; kk < 2; ++kk) {
    const size_t o0 = (size_t)(row0 + fr)*64 + kk*32 + fc*8;
    const size_t o1 = (size_t)(row0 + 16 + fr)*64 + kk*32 + fc*8;
    bf16x8 ah0 = *(const bf16x8*)(Xh + o0);
    bf16x8 ah1 = *(const bf16x8*)(Xh + o1);
    bf16x8 al0 = *(const bf16x8*)(Xl + o0);
    bf16x8 al1 = *(const bf16x8*)(Xl + o1);
    #pragma unroll
    for (int ni = 0; ni < NI; ++ni) {
      bf16x8 bh = *(const bf16x8*)(Bh + (size_t)(ni*16 + fr)*64 + kk*32 + fc*8);
      bf16x8 bl = *(const bf16x8*)(Bl + (size_t)(ni*16 + fr)*64 + kk*32 + fc*8);
      accA[0][ni] = __builtin_amdgcn_mfma_f32_16x16x32_bf16(ah0, bh, accA[0][ni], 0, 0, 0);
      accB[0][ni] = __builtin_amdgcn_mfma_f32_16x16x32_bf16(ah0, bl, accB[0][ni], 0, 0, 0);
      accB[0][ni] = __builtin_amdgcn_mfma_f32_16x16x32_bf16(al0, bh, accB[0][ni], 0, 0, 0);
      accA[1][ni] = __builtin_amdgcn_mfma_f32_16x16x32_bf16(ah1, bh, accA[1][ni], 0, 0, 0);
      accB[1][ni] = __builtin_amdgcn_mfma_f32_16x16x32_bf16(ah1, bl, accB[1][ni], 0, 0, 0);
      accB[1][ni] = __builtin_amdgcn_mfma_f32_16x16x32_bf16(al1, bh, accB[1][ni], 0, 0, 0);
    }
  }
}

// bias (+ optional LN) + SiLU on C fragments, store bf16 hi/lo to H (may == X)
template<bool LN>
__device__ __forceinline__ void act_store2(f32x4 accA[2][4], f32x4 accB[2][4],
    const float* __restrict__ b, const float* __restrict__ g, const float* __restrict__ be,
    u16 (*Hh)[72], u16 (*Hl)[72], int wrow, int lane)
{
  const int fr = lane & 15, fc = lane >> 4;
  float bv[4], gv[4], bev[4];
  #pragma unroll
  for (int ni = 0; ni < 4; ++ni) {
    bv[ni] = b[ni*16 + fr];
    if (LN) { gv[ni] = g[ni*16 + fr]; bev[ni] = be[ni*16 + fr]; }
  }
  #pragma unroll
  for (int mi = 0; mi < 2; ++mi)
    #pragma unroll
    for (int j = 0; j < 4; ++j) {
      int r = wrow + mi*16 + fc*4 + j;
      float x[4];
      #pragma unroll
      for (int ni = 0; ni < 4; ++ni) x[ni] = accA[mi][ni][j] + accB[mi][ni][j] + bv[ni];
      if (LN) {
        float s  = x[0] + x[1] + x[2] + x[3];
        float s2 = x[0]*x[0] + x[1]*x[1] + x[2]*x[2] + x[3]*x[3];
        #pragma unroll
        for (int off = 1; off < 16; off <<= 1) {
          s  += __shfl_xor(s,  off);
          s2 += __shfl_xor(s2, off);
        }
        float mu  = s * (1.f/64.f);
        float var = s2 * (1.f/64.f) - mu*mu;
        float rs  = rsqrtf(var + 1e-6f);
        #pragma unroll
        for (int ni = 0; ni < 4; ++ni) x[ni] = (x[ni] - mu)*rs*gv[ni] + bev[ni];
      }
      #pragma unroll
      for (int ni = 0; ni < 4; ++ni) {
        float y = x[ni];
        y = y / (1.f + __expf(-y));
        union { float f; u32 u; } c; c.f = y;
        union { u32 u; float f; } hf; hf.u = c.u & 0xFFFF0000u;
        Hh[r][ni*16 + fr] = (u16)(c.u >> 16);
        Hl[r][ni*16 + fr] = f2bf(y - hf.f);
      }
    }
}

// ---------------- fused alpha + radial MLPs ---------------------------------
__global__ __launch_bounds__(256, 4) void k_ar_mlp(
  const u16* __restrict__ eh, const u16* __restrict__ el,
  const float* __restrict__ esh, const u16* __restrict__ Wm,
  const float* __restrict__ ab1, const float* __restrict__ ag1, const float* __restrict__ abe1,
  const float* __restrict__ ab2, const float* __restrict__ ag2, const float* __restrict__ abe2,
  const float* __restrict__ ab3,
  const float* __restrict__ tb1, const float* __restrict__ tb2,
  float* __restrict__ alpha_g, float* __restrict__ scal_g, float* __restrict__ cbuf_g)
{
  __shared__ u16 Hh[128][72], Hl[128][72];
  __shared__ float aS[128][4];
  const u16* Wa1 = Wm;
  const u16* Wa2 = Wm + 4096;
  const u16* Wa3 = Wm + 8192;
  const u16* Wr1 = Wm + 9216;
  const u16* Wr2 = Wm + 13312;
  const int tid = threadIdx.x;
  const int wave = tid >> 6, lane = tid & 63;
  const int fr = lane & 15, fc = lane >> 4;
  const int wrow = wave * 32;
  const int e0 = blockIdx.x * 128;
  f32x4 accA[2][4], accB[2][4];
  // alpha L1 (A from global)
  gemm_glb<4>(eh, el, e0 + wrow, lane, Wa1, Wa1 + WSTRIDE, accA, accB);
  act_store2<true>(accA, accB, ab1, ag1, abe1, Hh, Hl, wrow, lane);
  // alpha L2 (in-place)
  gemm_lds<4, true>(Hh, Hl, wrow, lane, Wa2, Wa2 + WSTRIDE, accA, accB);
  act_store2<true>(accA, accB, ab2, ag2, abe2, Hh, Hl, wrow, lane);
  // alpha L3: N=4 (padded to 16)
  gemm_lds<1, true>(Hh, Hl, wrow, lane, Wa3, Wa3 + WSTRIDE, accA, accB);
  {
    float bv = (fr < 4) ? ab3[fr] : 0.f;
    #pragma unroll
    for (int mi = 0; mi < 2; ++mi)
      #pragma unroll
      for (int j = 0; j < 4; ++j) {
        int r = wrow + mi*16 + fc*4 + j;
        float v = accA[mi][0][j] + accB[mi][0][j] + bv;
        if (fr < 4) {
          alpha_g[(size_t)(e0 + r)*4 + fr] = v;
          aS[r][fr] = v;
        }
      }
  }
  // radial L1 (A from global again; L2-warm)
  gemm_glb<4>(eh, el, e0 + wrow, lane, Wr1, Wr1 + WSTRIDE, accA, accB);
  act_store2<false>(accA, accB, tb1, nullptr, nullptr, Hh, Hl, wrow, lane);
  // radial L2 + sh contraction
  gemm_lds<4, true>(Hh, Hl, wrow, lane, Wr2, Wr2 + WSTRIDE, accA, accB);
  {
    float bv[4];
    #pragma unroll
    for (int ni = 0; ni < 4; ++ni) bv[ni] = tb2[ni*16 + fr];
    #pragma unroll
    for (int mi = 0; mi < 2; ++mi)
      #pragma unroll
      for (int j = 0; j < 4; ++j) {
        int r = wrow + mi*16 + fc*4 + j;
        float shv = esh[(size_t)(e0 + r)*16 + fr];
        float sc[4];
        #pragma unroll
        for (int ni = 0; ni < 4; ++ni) {
          float t = (accA[mi][ni][j] + accB[mi][ni][j] + bv[ni]) * shv;
          #pragma unroll
          for (int off = 1; off < 16; off <<= 1) t += __shfl_xor(t, off);
          sc[ni] = t;
        }
        if (fr == 0) {
          float4 sv; sv.x = sc[0]; sv.y = sc[1]; sv.z = sc[2]; sv.w = sc[3];
          *(float4*)(scal_g + (size_t)(e0 + r)*4) = sv;
          float4 cv;
          cv.x = sc[0]*aS[r][0]; cv.y = sc[1]*aS[r][1];
          cv.z = sc[2]*aS[r][2]; cv.w = sc[3]*aS[r][3];
          *(float4*)(cbuf_g + (size_t)(e0 + r)*4) = cv;
        }
      }
  }
}

// ---------------- MFMA s-MLP (y0 -> edge_scalar[E,32]) ----------------------
__global__ __launch_bounds__(256, 4) void k_smlp2(
  const u16* __restrict__ y0b, const u16* __restrict__ Wm,
  const float* __restrict__ b1, const float* __restrict__ g1, const float* __restrict__ be1,
  const float* __restrict__ b2, const float* __restrict__ g2, const float* __restrict__ be2,
  const float* __restrict__ b3,
  float* __restrict__ oute)
{
  __shared__ u16 Xh[128][72], Xl[128][72];
  const u16* Ws1 = Wm + 17408;
  const u16* Ws2 = Wm + 21504;
  const u16* Ws3 = Wm + 25600;
  const int tid = threadIdx.x;
  const int wave = tid >> 6, lane = tid & 63;
  const int fr = lane & 15, fc = lane >> 4;
  const int wrow = wave * 32;
  const int e0 = blockIdx.x * 128;
  {
    int r = tid >> 1, cb = (tid & 1) * 32;
    const uint4* p = (const uint4*)(y0b + (size_t)(e0 + r)*64 + cb);
    uint4* dh = (uint4*)&Xh[r][cb];
    dh[0] = p[0]; dh[1] = p[1]; dh[2] = p[2]; dh[3] = p[3];
  }
  f32x4 accA[2][4], accB[2][4];
  // L1: input lo == 0 -> 2-chain gemm
  gemm_lds<4, false>(Xh, Xl, wrow, lane, Ws1, Ws1 + WSTRIDE, accA, accB);
  act_store2<true>(accA, accB, b1, g1, be1, Xh, Xl, wrow, lane);
  gemm_lds<4, true>(Xh, Xl, wrow, lane, Ws2, Ws2 + WSTRIDE, accA, accB);
  act_store2<true>(accA, accB, b2, g2, be2, Xh, Xl, wrow, lane);
  gemm_lds<2, true>(Xh, Xl, wrow, lane, Ws3, Ws3 + WSTRIDE, accA, accB);
  {
    float bv[2];
    bv[0] = b3[fr]; bv[1] = b3[16 + fr];
    #pragma unroll
    for (int mi = 0; mi < 2; ++mi)
      #pragma unroll
      for (int j = 0; j < 4; ++j) {
        int r = wrow + mi*16 + fc*4 + j;
        #pragma unroll
        for (int ni = 0; ni < 2; ++ni)
          oute[(size_t)(e0 + r)*32 + ni*16 + fr] = accA[mi][ni][j] + accB[mi][ni][j] + bv[ni];
      }
  }
}

// ---------------- G1: msg = [x_src|x_dst|elen] @ pre_lin_w  (bf16 out) ------
__global__ __launch_bounds__(256) void g1_msg(
    const float* __restrict__ node_in, const float* __restrict__ elen,
    const int* __restrict__ esrc, const int* __restrict__ edst,
    const u16* __restrict__ Bt1, u16* __restrict__ msgb)
{
  __shared__ u16 As[128][40];
  __shared__ u16 Bs[128][40];
  const int tid = threadIdx.x;
  const int e0 = blockIdx.x * 128;
  const int wave = tid >> 6, lane = tid & 63;
  const int wr = (wave >> 1) * 64, wc = (wave & 1) * 64;
  const int fr = lane & 15, fc = lane >> 4;
  f32x4 acc[4][4] = {};
  const int r = tid >> 1, half = tid & 1;
  const int e = e0 + r;
  const int s_idx = esrc[e], d_idx = edst[e];
  for (int k0 = 0; k0 < 320; k0 += 32) {
    const int kk = k0 + half * 16;
    const float* ap;
    if (kk < 128)      ap = node_in + (size_t)s_idx*128 + kk;
    else if (kk < 256) ap = node_in + (size_t)d_idx*128 + (kk - 128);
    else               ap = elen + (size_t)e*64 + (kk - 256);
    u32* asp = (u32*)&As[r][half*16];
    #pragma unroll
    for (int q = 0; q < 4; ++q) {
      float4 v = *(const float4*)(ap + q*4);
      asp[q*2]   = pack2(v.x, v.y);
      asp[q*2+1] = pack2(v.z, v.w);
    }
    const uint4* bp = (const uint4*)(Bt1 + (size_t)r*320 + kk);
    *(uint4*)&Bs[r][half*16]     = bp[0];
    *(uint4*)&Bs[r][half*16 + 8] = bp[1];
    __syncthreads();
    bf16x8 a[4], b[4];
    #pragma unroll
    for (int mi = 0; mi < 4; ++mi) a[mi] = *(const bf16x8*)&As[wr + mi*16 + fr][fc*8];
    #pragma unroll
    for (int ni = 0; ni < 4; ++ni) b[ni] = *(const bf16x8*)&Bs[wc + ni*16 + fr][fc*8];
    #pragma unroll
    for (int mi = 0; mi < 4; ++mi)
      #pragma unroll
      for (int ni = 0; ni < 4; ++ni)
        acc[mi][ni] = __builtin_amdgcn_mfma_f32_16x16x32_bf16(a[mi], b[ni], acc[mi][ni], 0, 0, 0);
    __syncthreads();
  }
  #pragma unroll
  for (int mi = 0; mi < 4; ++mi)
    #pragma unroll
    for (int j = 0; j < 4; ++j) {
      int row = wr + mi*16 + fc*4 + j;
      size_t base = (size_t)(e0 + row)*128 + wc + fr;
      #pragma unroll
      for (int ni = 0; ni < 4; ++ni)
        msgb[base + ni*16] = f2bf(acc[mi][ni][j]);
    }
}

// ---------------- G2: t = msg @ Wcat ; y0 = sum_h c[h]*t[:,h*64+j] ----------
union G2Smem {
  struct { u16 As[64][40]; u16 Bs[256][40]; } s;
  float R[2][64][66];
};
__global__ __launch_bounds__(256) void g2_y0(
    const u16* __restrict__ msgb, const u16* __restrict__ Bt2,
    const float* __restrict__ cbuf, u16* __restrict__ y0b)
{
  __shared__ G2Smem u;
  __shared__ float cS[64][4];
  const int tid = threadIdx.x, wave = tid >> 6, lane = tid & 63;
  const int e0 = blockIdx.x * 64;
  const int fr = lane & 15, fc = lane >> 4;
  cS[tid >> 2][tid & 3] = cbuf[(size_t)e0*4 + tid];
  f32x4 acc[4][4] = {};
  for (int k0 = 0; k0 < 128; k0 += 32) {
    { // stage A (64 x 32)
      int r = tid >> 2, q = tid & 3;
      *(uint4*)&u.s.As[r][q*8] = *(const uint4*)(msgb + (size_t)(e0 + r)*128 + k0 + q*8);
    }
    { // stage B (256 x 32)
      const uint4* bp = (const uint4*)(Bt2 + (size_t)tid*128 + k0);
      *(uint4*)&u.s.Bs[tid][0]  = bp[0];
      *(uint4*)&u.s.Bs[tid][8]  = bp[1];
      *(uint4*)&u.s.Bs[tid][16] = bp[2];
      *(uint4*)&u.s.Bs[tid][24] = bp[3];
    }
    __syncthreads();
    bf16x8 a[4], b[4];
    #pragma unroll
    for (int mi = 0; mi < 4; ++mi) a[mi] = *(const bf16x8*)&u.s.As[mi*16 + fr][fc*8];
    #pragma unroll
    for (int ni = 0; ni < 4; ++ni) b[ni] = *(const bf16x8*)&u.s.Bs[wave*64 + ni*16 + fr][fc*8];
    #pragma unroll
    for (int mi = 0; mi < 4; ++mi)
      #pragma unroll
      for (int ni = 0; ni < 4; ++ni)
        acc[mi][ni] = __builtin_amdgcn_mfma_f32_16x16x32_bf16(a[mi], b[ni], acc[mi][ni], 0, 0, 0);
    __syncthreads();
  }
  const int h = wave;
  if ((wave & 1) == 0) {
    float (*Rb)[66] = u.R[wave >> 1];
    #pragma unroll
    for (int mi = 0; mi < 4; ++mi)
      #pragma unroll
      for (int j = 0; j < 4; ++j) {
        int row = mi*16 + fc*4 + j;
        float cv = cS[row][h];
        #pragma unroll
        for (int ni = 0; ni < 4; ++ni)
          Rb[row][ni*16 + fr] = acc[mi][ni][j] * cv;
      }
  }
  __syncthreads();
  if (wave & 1) {
    float (*Rb)[66] = u.R[wave >> 1];
    #pragma unroll
    for (int mi = 0; mi < 4; ++mi)
      #pragma unroll
      for (int j = 0; j < 4; ++j) {
        int row = mi*16 + fc*4 + j;
        float cv = cS[row][h];
        #pragma unroll
        for (int ni = 0; ni < 4; ++ni)
          Rb[row][ni*16 + fr] += acc[mi][ni][j] * cv;
      }
  }
  __syncthreads();
  {
    int rr = tid >> 2, j0 = (tid & 3) * 16;
    u16 tmp[16];
    #pragma unroll
    for (int i = 0; i < 16; ++i)
      tmp[i] = f2bf(u.R[0][rr][j0 + i] + u.R[1][rr][j0 + i]);
    uint4* dst = (uint4*)(y0b + (size_t)(e0 + rr)*64 + j0);
    dst[0] = *(const uint4*)&tmp[0];
    dst[1] = *(const uint4*)&tmp[8];
  }
}

// ---------------- K9: per-node softmax + aggregation ------------------------
__global__ __launch_bounds__(256) void k_node(
  const int* __restrict__ offs, const int* __restrict__ eids,
  const float* __restrict__ alpha, const float* __restrict__ scal,
  const u16* __restrict__ msgb, u16* __restrict__ nfb)
{
  const int w = threadIdx.x >> 6, lane = threadIdx.x & 63;
  const int n = blockIdx.x * 4 + w;
  const int beg = offs[n], end = offs[n+1];
  float m0=-3e38f, m1=-3e38f, m2=-3e38f, m3=-3e38f;
  for (int i = beg + lane; i < end; i += 64) {
    int eid = eids[i];
    float4 a = *(const float4*)(alpha + (size_t)eid*4);
    m0 = fmaxf(m0, a.x); m1 = fmaxf(m1, a.y);
    m2 = fmaxf(m2, a.z); m3 = fmaxf(m3, a.w);
  }
  #pragma unroll
  for (int off = 1; off < 64; off <<= 1) {
    m0 = fmaxf(m0, __shfl_xor(m0, off));
    m1 = fmaxf(m1, __shfl_xor(m1, off));
    m2 = fmaxf(m2, __shfl_xor(m2, off));
    m3 = fmaxf(m3, __shfl_xor(m3, off));
  }
  float se0=0.f, se1=0.f, se2=0.f, se3=0.f;
  float f00=0.f, f01=0.f, f10=0.f, f11=0.f, f20=0.f, f21=0.f, f30=0.f, f31=0.f;
  for (int i = beg; i < end; ++i) {
    int eid = eids[i];
    float4 a = *(const float4*)(alpha + (size_t)eid*4);
    float4 s = *(const float4*)(scal + (size_t)eid*4);
    float e0 = __expf(a.x - m0), e1 = __expf(a.y - m1);
    float e2 = __expf(a.z - m2), e3 = __expf(a.w - m3);
    se0 += e0; se1 += e1; se2 += e2; se3 += e3;
    float w0 = e0*s.x, w1 = e1*s.y, w2 = e2*s.z, w3 = e3*s.w;
    float v0 = bf2f(msgb[(size_t)eid*128 + lane]);
    float v1 = bf2f(msgb[(size_t)eid*128 + 64 + lane]);
    f00 = fmaf(w0, v0, f00); f01 = fmaf(w0, v1, f01);
    f10 = fmaf(w1, v0, f10); f11 = fmaf(w1, v1, f11);
    f20 = fmaf(w2, v0, f20); f21 = fmaf(w2, v1, f21);
    f30 = fmaf(w3, v0, f30); f31 = fmaf(w3, v1, f31);
  }
  float i0 = 1.f/(se0 + 1e-16f), i1 = 1.f/(se1 + 1e-16f);
  float i2 = 1.f/(se2 + 1e-16f), i3 = 1.f/(se3 + 1e-16f);
  size_t b = (size_t)n * 512;
  nfb[b + 0*128 + lane]      = f2bf(f00*i0);
  nfb[b + 0*128 + 64 + lane] = f2bf(f01*i0);
  nfb[b + 1*128 + lane]      = f2bf(f10*i1);
  nfb[b + 1*128 + 64 + lane] = f2bf(f11*i1);
  nfb[b + 2*128 + lane]      = f2bf(f20*i2);
  nfb[b + 2*128 + 64 + lane] = f2bf(f21*i2);
  nfb[b + 3*128 + lane]      = f2bf(f30*i3);
  nfb[b + 3*128 + 64 + lane] = f2bf(f31*i3);
}

// ---------------- G10: node_out = node_fea @ lin_w --------------------------
__global__ __launch_bounds__(256) void g10_out(
    const u16* __restrict__ nfb, const u16* __restrict__ Bt3,
    float* __restrict__ out)
{
  __shared__ u16 As[128][40];
  __shared__ u16 Bs[128][40];
  const int tid = threadIdx.x;
  const int n0 = blockIdx.x * 128;
  const int wave = tid >> 6, lane = tid & 63;
  const int wr = (wave >> 1) * 64, wc = (wave & 1) * 64;
  const int fr = lane & 15, fc = lane >> 4;
  f32x4 acc[4][4] = {};
  const int r = tid >> 1, half = tid & 1;
  const int n = n0 + r;
  for (int k0 = 0; k0 < 512; k0 += 32) {
    uint4 z; z.x=0; z.y=0; z.z=0; z.w=0;
    uint4 v0 = z, v1 = z;
    if (n < NN) {
      const uint4* apv = (const uint4*)(nfb + (size_t)n*512 + k0 + half*16);
      v0 = apv[0]; v1 = apv[1];
    }
    *(uint4*)&As[r][half*16]     = v0;
    *(uint4*)&As[r][half*16 + 8] = v1;
    const uint4* bp = (const uint4*)(Bt3 + (size_t)r*512 + k0 + half*16);
    *(uint4*)&Bs[r][half*16]     = bp[0];
    *(uint4*)&Bs[r][half*16 + 8] = bp[1];
    __syncthreads();
    bf16x8 a[4], b[4];
    #pragma unroll
    for (int mi = 0; mi < 4; ++mi) a[mi] = *(const bf16x8*)&As[wr + mi*16 + fr][fc*8];
    #pragma unroll
    for (int ni = 0; ni < 4; ++ni) b[ni] = *(const bf16x8*)&Bs[wc + ni*16 + fr][fc*8];
    #pragma unroll
    for (int mi = 0; mi < 4; ++mi)
      #pragma unroll
      for (int ni = 0; ni < 4; ++ni)
        acc[mi][ni] = __builtin_amdgcn_mfma_f32_16x16x32_bf16(a[mi], b[ni], acc[mi][ni], 0, 0, 0);
    __syncthreads();
  }
  #pragma unroll
  for (int mi = 0; mi < 4; ++mi)
    #pragma unroll
    for (int j = 0; j < 4; ++j) {
      int rowg = n0 + wr + mi*16 + fc*4 + j;
      if (rowg < NN) {
        size_t base = (size_t)rowg*128 + wc + fr;
        #pragma unroll
        for (int ni = 0; ni < 4; ++ni)
          out[base + ni*16] = acc[mi][ni][j];
      }
    }
}

// ---------------- launch ----------------------------------------------------
extern "C" void kernel_launch(void* const* d_in, const int* in_sizes, int n_in,
                              void* d_out, int out_size, void* d_ws, size_t ws_size,
                              hipStream_t stream)
{
  const float* node_in    = (const float*)d_in[0];
  const float* edge_sh    = (const float*)d_in[2];
  const float* elen       = (const float*)d_in[3];
  const int*   esrc       = (const int*)d_in[4];
  const int*   edst       = (const int*)d_in[5];
  const float* pre_lin_w  = (const float*)d_in[7];
  const float* tp2_w1     = (const float*)d_in[8];
  const float* tp2_b1     = (const float*)d_in[9];
  const float* tp2_w2     = (const float*)d_in[10];
  const float* tp2_b2     = (const float*)d_in[11];
  const float* a_w1  = (const float*)d_in[12];
  const float* a_b1  = (const float*)d_in[13];
  const float* a_g1  = (const float*)d_in[14];
  const float* a_be1 = (const float*)d_in[15];
  const float* a_w2  = (const float*)d_in[16];
  const float* a_b2  = (const float*)d_in[17];
  const float* a_g2  = (const float*)d_in[18];
  const float* a_be2 = (const float*)d_in[19];
  const float* a_w3  = (const float*)d_in[20];
  const float* a_b3  = (const float*)d_in[21];
  const float* lin_w      = (const float*)d_in[22];
  const float* lin_edge_w = (const float*)d_in[23];
  const float* s_w1  = (const float*)d_in[24];
  const float* s_b1  = (const float*)d_in[25];
  const float* s_g1  = (const float*)d_in[26];
  const float* s_be1 = (const float*)d_in[27];
  const float* s_w2  = (const float*)d_in[28];
  const float* s_b2  = (const float*)d_in[29];
  const float* s_g2  = (const float*)d_in[30];
  const float* s_be2 = (const float*)d_in[31];
  const float* s_w3  = (const float*)d_in[32];
  const float* s_b3  = (const float*)d_in[33];

  float* out_node = (float*)d_out;
  float* out_edge = out_node + (size_t)NN * 128;

  char* ws = (char*)d_ws;
  size_t off = 0;
  auto take = [&](size_t bytes) -> char* {
    char* p = ws + off;
    off = (off + bytes + 255) & ~(size_t)255;
    return p;
  };
  u16*   msgb   = (u16*)take((size_t)EE * 128 * 2);
  u16*   y0b    = (u16*)take((size_t)EE * 64 * 2);
  u16*   nfb    = (u16*)take((size_t)NN * 512 * 2);
  float* alpha  = (float*)take((size_t)EE * 4 * 4);
  float* scal   = (float*)take((size_t)EE * 4 * 4);
  float* cbuf   = (float*)take((size_t)EE * 4 * 4);
  int*   counts = (int*)take((size_t)NN * 4);
  int*   offs   = (int*)take((size_t)(NN + 1) * 4);
  int*   cursor = (int*)take((size_t)NN * 4);
  int*   eids   = (int*)take((size_t)EE * 4);
  u16*   Bt1    = (u16*)take((size_t)128 * 320 * 2);
  u16*   Bt2    = (u16*)take((size_t)256 * 128 * 2);
  u16*   Bt3    = (u16*)take((size_t)128 * 512 * 2);
  u16*   Wmlp   = (u16*)take((size_t)WSTRIDE * 2 * 2);

  // elen bf16 hi/lo planes alias msgb (dead until g1_msg runs)
  u16* elen_h = msgb;
  u16* elen_l = msgb + (size_t)EE * 64;

  k_prep<<<544, 256, 0, stream>>>(pre_lin_w, lin_edge_w, lin_w, Bt1, Bt2, Bt3);
  k_prep2<<<(WSTRIDE + 255)/256, 256, 0, stream>>>(a_w1, a_w2, a_w3, tp2_w1, tp2_w2,
                                                   s_w1, s_w2, s_w3, Wmlp);
  k_prep3<<<EE*64/8/256, 256, 0, stream>>>(elen, elen_h, elen_l);
  k_zero<<<(NN + 255)/256, 256, 0, stream>>>(counts);
  k_count<<<EE/256, 256, 0, stream>>>(edst, counts);
  k_scan<<<1, 1024, 0, stream>>>(counts, offs, cursor);
  k_fill<<<EE/256, 256, 0, stream>>>(edst, cursor, eids);
  k_sort<<<(NN + 255)/256, 256, 0, stream>>>(offs, eids);
  k_ar_mlp<<<EE/128, 256, 0, stream>>>(elen_h, elen_l, edge_sh, Wmlp,
                                       a_b1, a_g1, a_be1, a_b2, a_g2, a_be2, a_b3,
                                       tp2_b1, tp2_b2, alpha, scal, cbuf);
  g1_msg<<<EE/128, 256, 0, stream>>>(node_in, elen, esrc, edst, Bt1, msgb);
  g2_y0<<<EE/64, 256, 0, stream>>>(msgb, Bt2, cbuf, y0b);
  k_smlp2<<<EE/128, 256, 0, stream>>>(y0b, Wmlp, s_b1, s_g1, s_be1,
                                      s_b2, s_g2, s_be2, s_b3, out_edge);
  k_node<<<NN/4, 256, 0, stream>>>(offs, eids, alpha, scal, msgb, nfb);
  g10_out<<<(NN + 127)/128, 256, 0, stream>>>(nfb, Bt3, out_node);
}

// Round 7
// 518.065 us; speedup vs baseline: 1.2577x; 1.1481x over previous
//
#include <hip/hip_runtime.h>

#define NN 20000
#define EE 320000
#define WTOT 27648

typedef unsigned short u16;
typedef unsigned int u32;
typedef __attribute__((ext_vector_type(8))) short bf16x8;
typedef __attribute__((ext_vector_type(8))) _Float16 f16x8;
typedef __attribute__((ext_vector_type(4))) float f32x4;

__device__ __forceinline__ float bf2f(u16 u){
  union { u32 i; float f; } v; v.i = ((u32)u) << 16; return v.f;
}
__device__ __forceinline__ u16 f2bf(float f){
  union { float f; u32 i; } v; v.f = f;
  u32 i = v.i;
  return (u16)((i + 0x7FFFu + ((i >> 16) & 1u)) >> 16);
}
__device__ __forceinline__ u32 pack2(float a, float b){
  return ((u32)f2bf(b) << 16) | (u32)f2bf(a);
}
__device__ __forceinline__ u16 f2h(float f){
  union { _Float16 h[2]; u32 u; } v; v.h[0] = (_Float16)f;
  return (u16)(v.u & 0xFFFF);
}
__device__ __forceinline__ u32 packh2(float a, float b){
  return ((u32)f2h(b) << 16) | (u32)f2h(a);
}

// ---------------- weight pre-transpose (to bf16, [n][k] layout) -------------
__global__ __launch_bounds__(256) void k_prep(
    const float* __restrict__ plw, const float* __restrict__ lew,
    const float* __restrict__ lw,
    u16* __restrict__ Bt1, u16* __restrict__ Bt2, u16* __restrict__ Bt3)
{
  int i = blockIdx.x * 256 + threadIdx.x;
  if (i < 128*320) {                       // Bt1[n][k] = pre_lin_w[k][n]
    int n = i / 320, k = i % 320;
    Bt1[i] = f2bf(plw[k*128 + n]);
  }
  int j = i - 128*320;
  if (j >= 0 && j < 256*128) {             // Bt2[h*64+c][k] = lin_edge_w[h*128+k][c]
    int n = j / 128, k = j % 128;
    int h = n >> 6, c = n & 63;
    Bt2[j] = f2bf(lew[(h*128 + k)*64 + c]);
  }
  int l = i - 128*320 - 256*128;
  if (l >= 0 && l < 128*512) {             // Bt3[n][k] = lin_w[k][n]
    int n = l / 512, k = l % 512;
    Bt3[l] = f2bf(lw[k*128 + n]);
  }
}

// MLP weights, transposed to [out][in], fp16.
// Layout: Wa1[4096] Wa2[4096] Wa3[1024(pad16x64)] Wr1[4096] Wr2[4096]
//         Ws1[4096] Ws2[4096] Ws3[2048]
__global__ __launch_bounds__(256) void k_prep2(
    const float* __restrict__ aw1, const float* __restrict__ aw2, const float* __restrict__ aw3,
    const float* __restrict__ rw1, const float* __restrict__ rw2,
    const float* __restrict__ sw1, const float* __restrict__ sw2, const float* __restrict__ sw3,
    u16* __restrict__ W)
{
  int i = blockIdx.x * 256 + threadIdx.x;
  if (i >= WTOT) return;
  float v = 0.f;
  int j = i;
  if (j < 4096)      { int n = j >> 6, k = j & 63; v = aw1[k*64 + n]; }
  else if ((j -= 4096) < 4096) { int n = j >> 6, k = j & 63; v = aw2[k*64 + n]; }
  else if ((j -= 4096) < 1024) { int n = j >> 6, k = j & 63; v = (n < 4) ? aw3[k*4 + n] : 0.f; }
  else if ((j -= 1024) < 4096) { int n = j >> 6, k = j & 63; v = rw1[k*64 + n]; }
  else if ((j -= 4096) < 4096) { int n = j >> 6, k = j & 63; v = rw2[k*64 + n]; }
  else if ((j -= 4096) < 4096) { int n = j >> 6, k = j & 63; v = sw1[k*64 + n]; }
  else if ((j -= 4096) < 4096) { int n = j >> 6, k = j & 63; v = sw2[k*64 + n]; }
  else               { j -= 4096; int n = j >> 6, k = j & 63; v = sw3[k*32 + n]; }
  W[i] = f2h(v);
}

// elen fp32 -> fp16 plane (written into msgb space, dead until g1)
__global__ __launch_bounds__(256) void k_prep3(
    const float* __restrict__ elen, u16* __restrict__ eh)
{
  size_t i = (size_t)blockIdx.x * 256 + threadIdx.x;   // one thread = 8 elems
  const float* p = elen + i*8;
  float4 a = ((const float4*)p)[0];
  float4 b = ((const float4*)p)[1];
  uint4 vh;
  vh.x = packh2(a.x, a.y); vh.y = packh2(a.z, a.w);
  vh.z = packh2(b.x, b.y); vh.w = packh2(b.z, b.w);
  *(uint4*)(eh + i*8) = vh;
}

// ---------------- CSR build -------------------------------------------------
__global__ __launch_bounds__(256) void k_zero(int* __restrict__ counts){
  int i = blockIdx.x * 256 + threadIdx.x;
  if (i < NN) counts[i] = 0;
}
__global__ __launch_bounds__(256) void k_count(const int* __restrict__ edst, int* __restrict__ counts){
  int e = blockIdx.x * 256 + threadIdx.x;
  if (e < EE) atomicAdd(&counts[edst[e]], 1);
}
__global__ __launch_bounds__(1024) void k_scan(const int* __restrict__ counts,
                                               int* __restrict__ offs, int* __restrict__ cursor){
  __shared__ int part[1024];
  int t = threadIdx.x;
  int c0 = t * 20, c1 = c0 + 20; if (c1 > NN) c1 = NN; if (c0 > NN) c0 = NN;
  int s = 0;
  for (int i = c0; i < c1; ++i) s += counts[i];
  part[t] = s;
  __syncthreads();
  if (t == 0) {
    int run = 0;
    for (int i = 0; i < 1024; ++i) { int v = part[i]; part[i] = run; run += v; }
    offs[NN] = run;
  }
  __syncthreads();
  int run = part[t];
  for (int i = c0; i < c1; ++i) { offs[i] = run; cursor[i] = run; run += counts[i]; }
}
__global__ __launch_bounds__(256) void k_fill(const int* __restrict__ edst,
                                              int* __restrict__ cursor, int* __restrict__ eids){
  int e = blockIdx.x * 256 + threadIdx.x;
  if (e < EE) { int p = atomicAdd(&cursor[edst[e]], 1); eids[p] = e; }
}
__global__ __launch_bounds__(256) void k_sort(const int* __restrict__ offs, int* __restrict__ eids){
  int n = blockIdx.x * 256 + threadIdx.x;
  if (n >= NN) return;
  int b = offs[n], e = offs[n+1];
  for (int i = b + 1; i < e; ++i) {
    int v = eids[i]; int j = i - 1;
    while (j >= b && eids[j] > v) { eids[j+1] = eids[j]; --j; }
    eids[j+1] = v;
  }
}

// ---------------- FP16 MFMA MLP building blocks (128-row tile, 32/wave) -----
// Wave w owns rows [w*32, w*32+32): all LDS traffic wave-private -> no barriers.
// acc[2][4] = 8 independent MFMA chains.
template<int NI>
__device__ __forceinline__ void gemm16_lds(const u16 (*X)[72], int wrow, int lane,
                                           const u16* __restrict__ B, f32x4 acc[2][4])
{
  const int fr = lane & 15, fc = lane >> 4;
  #pragma unroll
  for (int mi = 0; mi < 2; ++mi)
    #pragma unroll
    for (int ni = 0; ni < NI; ++ni)
      acc[mi][ni] = (f32x4){0.f, 0.f, 0.f, 0.f};
  #pragma unroll
  for (int kk = 0; kk < 2; ++kk) {
    f16x8 a0 = *(const f16x8*)&X[wrow + fr][kk*32 + fc*8];
    f16x8 a1 = *(const f16x8*)&X[wrow + 16 + fr][kk*32 + fc*8];
    #pragma unroll
    for (int ni = 0; ni < NI; ++ni) {
      f16x8 b = *(const f16x8*)(B + (size_t)(ni*16 + fr)*64 + kk*32 + fc*8);
      acc[0][ni] = __builtin_amdgcn_mfma_f32_16x16x32_f16(a0, b, acc[0][ni], 0, 0, 0);
      acc[1][ni] = __builtin_amdgcn_mfma_f32_16x16x32_f16(a1, b, acc[1][ni], 0, 0, 0);
    }
  }
}

// A-fragments straight from the global fp16 plane (row stride 64)
template<int NI>
__device__ __forceinline__ void gemm16_glb(const u16* __restrict__ X, int row0, int lane,
                                           const u16* __restrict__ B, f32x4 acc[2][4])
{
  const int fr = lane & 15, fc = lane >> 4;
  #pragma unroll
  for (int mi = 0; mi < 2; ++mi)
    #pragma unroll
    for (int ni = 0; ni < NI; ++ni)
      acc[mi][ni] = (f32x4){0.f, 0.f, 0.f, 0.f};
  #pragma unroll
  for (int kk = 0; kk < 2; ++kk) {
    const size_t o0 = (size_t)(row0 + fr)*64 + kk*32 + fc*8;
    const size_t o1 = (size_t)(row0 + 16 + fr)*64 + kk*32 + fc*8;
    f16x8 a0 = *(const f16x8*)(X + o0);
    f16x8 a1 = *(const f16x8*)(X + o1);
    #pragma unroll
    for (int ni = 0; ni < NI; ++ni) {
      f16x8 b = *(const f16x8*)(B + (size_t)(ni*16 + fr)*64 + kk*32 + fc*8);
      acc[0][ni] = __builtin_amdgcn_mfma_f32_16x16x32_f16(a0, b, acc[0][ni], 0, 0, 0);
      acc[1][ni] = __builtin_amdgcn_mfma_f32_16x16x32_f16(a1, b, acc[1][ni], 0, 0, 0);
    }
  }
}

// bias (+ optional LN) + SiLU on C fragments, store fp16 to H (may == X)
template<bool LN>
__device__ __forceinline__ void act_store16(f32x4 acc[2][4],
    const float* __restrict__ b, const float* __restrict__ g, const float* __restrict__ be,
    u16 (*H)[72], int wrow, int lane)
{
  const int fr = lane & 15, fc = lane >> 4;
  float bv[4], gv[4], bev[4];
  #pragma unroll
  for (int ni = 0; ni < 4; ++ni) {
    bv[ni] = b[ni*16 + fr];
    if (LN) { gv[ni] = g[ni*16 + fr]; bev[ni] = be[ni*16 + fr]; }
  }
  #pragma unroll
  for (int mi = 0; mi < 2; ++mi)
    #pragma unroll
    for (int j = 0; j < 4; ++j) {
      int r = wrow + mi*16 + fc*4 + j;
      float x[4];
      #pragma unroll
      for (int ni = 0; ni < 4; ++ni) x[ni] = acc[mi][ni][j] + bv[ni];
      if (LN) {
        float s  = x[0] + x[1] + x[2] + x[3];
        float s2 = x[0]*x[0] + x[1]*x[1] + x[2]*x[2] + x[3]*x[3];
        #pragma unroll
        for (int off = 1; off < 16; off <<= 1) {
          s  += __shfl_xor(s,  off);
          s2 += __shfl_xor(s2, off);
        }
        float mu  = s * (1.f/64.f);
        float var = s2 * (1.f/64.f) - mu*mu;
        float rs  = rsqrtf(var + 1e-6f);
        #pragma unroll
        for (int ni = 0; ni < 4; ++ni) x[ni] = (x[ni] - mu)*rs*gv[ni] + bev[ni];
      }
      #pragma unroll
      for (int ni = 0; ni < 4; ++ni) {
        float y = x[ni];
        y = y / (1.f + __expf(-y));
        H[r][ni*16 + fr] = f2h(y);
      }
    }
}

// ---------------- fused alpha + radial MLPs ---------------------------------
__global__ __launch_bounds__(256, 6) void k_ar_mlp(
  const u16* __restrict__ eh,
  const float* __restrict__ esh, const u16* __restrict__ Wm,
  const float* __restrict__ ab1, const float* __restrict__ ag1, const float* __restrict__ abe1,
  const float* __restrict__ ab2, const float* __restrict__ ag2, const float* __restrict__ abe2,
  const float* __restrict__ ab3,
  const float* __restrict__ tb1, const float* __restrict__ tb2,
  float* __restrict__ alpha_g, float* __restrict__ scal_g, float* __restrict__ cbuf_g)
{
  __shared__ u16 H[128][72];
  __shared__ float aS[128][4];
  const u16* Wa1 = Wm;
  const u16* Wa2 = Wm + 4096;
  const u16* Wa3 = Wm + 8192;
  const u16* Wr1 = Wm + 9216;
  const u16* Wr2 = Wm + 13312;
  const int tid = threadIdx.x;
  const int wave = tid >> 6, lane = tid & 63;
  const int fr = lane & 15, fc = lane >> 4;
  const int wrow = wave * 32;
  const int e0 = blockIdx.x * 128;
  f32x4 acc[2][4];
  // alpha L1 (A from global)
  gemm16_glb<4>(eh, e0 + wrow, lane, Wa1, acc);
  act_store16<true>(acc, ab1, ag1, abe1, H, wrow, lane);
  // alpha L2 (in-place)
  gemm16_lds<4>(H, wrow, lane, Wa2, acc);
  act_store16<true>(acc, ab2, ag2, abe2, H, wrow, lane);
  // alpha L3: N=4 (padded to 16)
  gemm16_lds<1>(H, wrow, lane, Wa3, acc);
  {
    float bv = (fr < 4) ? ab3[fr] : 0.f;
    #pragma unroll
    for (int mi = 0; mi < 2; ++mi)
      #pragma unroll
      for (int j = 0; j < 4; ++j) {
        int r = wrow + mi*16 + fc*4 + j;
        float v = acc[mi][0][j] + bv;
        if (fr < 4) {
          alpha_g[(size_t)(e0 + r)*4 + fr] = v;
          aS[r][fr] = v;
        }
      }
  }
  // radial L1 (A from global again; L2-warm)
  gemm16_glb<4>(eh, e0 + wrow, lane, Wr1, acc);
  act_store16<false>(acc, tb1, nullptr, nullptr, H, wrow, lane);
  // radial L2 + sh contraction
  gemm16_lds<4>(H, wrow, lane, Wr2, acc);
  {
    float bv[4];
    #pragma unroll
    for (int ni = 0; ni < 4; ++ni) bv[ni] = tb2[ni*16 + fr];
    #pragma unroll
    for (int mi = 0; mi < 2; ++mi)
      #pragma unroll
      for (int j = 0; j < 4; ++j) {
        int r = wrow + mi*16 + fc*4 + j;
        float shv = esh[(size_t)(e0 + r)*16 + fr];
        float sc[4];
        #pragma unroll
        for (int ni = 0; ni < 4; ++ni) {
          float t = (acc[mi][ni][j] + bv[ni]) * shv;
          #pragma unroll
          for (int off = 1; off < 16; off <<= 1) t += __shfl_xor(t, off);
          sc[ni] = t;
        }
        if (fr == 0) {
          float4 sv; sv.x = sc[0]; sv.y = sc[1]; sv.z = sc[2]; sv.w = sc[3];
          *(float4*)(scal_g + (size_t)(e0 + r)*4) = sv;
          float4 cv;
          cv.x = sc[0]*aS[r][0]; cv.y = sc[1]*aS[r][1];
          cv.z = sc[2]*aS[r][2]; cv.w = sc[3]*aS[r][3];
          *(float4*)(cbuf_g + (size_t)(e0 + r)*4) = cv;
        }
      }
  }
}

// ---------------- FP16 s-MLP (y0 fp16 -> edge_scalar[E,32]) -----------------
__global__ __launch_bounds__(256, 6) void k_smlp2(
  const u16* __restrict__ y0h, const u16* __restrict__ Wm,
  const float* __restrict__ b1, const float* __restrict__ g1, const float* __restrict__ be1,
  const float* __restrict__ b2, const float* __restrict__ g2, const float* __restrict__ be2,
  const float* __restrict__ b3,
  float* __restrict__ oute)
{
  __shared__ u16 X[128][72];
  const u16* Ws1 = Wm + 17408;
  const u16* Ws2 = Wm + 21504;
  const u16* Ws3 = Wm + 25600;
  const int tid = threadIdx.x;
  const int wave = tid >> 6, lane = tid & 63;
  const int fr = lane & 15, fc = lane >> 4;
  const int wrow = wave * 32;
  const int e0 = blockIdx.x * 128;
  {
    int r = tid >> 1, cb = (tid & 1) * 32;
    const uint4* p = (const uint4*)(y0h + (size_t)(e0 + r)*64 + cb);
    uint4* dh = (uint4*)&X[r][cb];
    dh[0] = p[0]; dh[1] = p[1]; dh[2] = p[2]; dh[3] = p[3];
  }
  f32x4 acc[2][4];
  gemm16_lds<4>(X, wrow, lane, Ws1, acc);
  act_store16<true>(acc, b1, g1, be1, X, wrow, lane);
  gemm16_lds<4>(X, wrow, lane, Ws2, acc);
  act_store16<true>(acc, b2, g2, be2, X, wrow, lane);
  gemm16_lds<2>(X, wrow, lane, Ws3, acc);
  {
    float bv[2];
    bv[0] = b3[fr]; bv[1] = b3[16 + fr];
    #pragma unroll
    for (int mi = 0; mi < 2; ++mi)
      #pragma unroll
      for (int j = 0; j < 4; ++j) {
        int r = wrow + mi*16 + fc*4 + j;
        #pragma unroll
        for (int ni = 0; ni < 2; ++ni)
          oute[(size_t)(e0 + r)*32 + ni*16 + fr] = acc[mi][ni][j] + bv[ni];
      }
  }
}

// ---------------- G1: msg = [x_src|x_dst|elen] @ pre_lin_w  (bf16 out) ------
__global__ __launch_bounds__(256) void g1_msg(
    const float* __restrict__ node_in, const float* __restrict__ elen,
    const int* __restrict__ esrc, const int* __restrict__ edst,
    const u16* __restrict__ Bt1, u16* __restrict__ msgb)
{
  __shared__ u16 As[128][40];
  __shared__ u16 Bs[128][40];
  const int tid = threadIdx.x;
  const int e0 = blockIdx.x * 128;
  const int wave = tid >> 6, lane = tid & 63;
  const int wr = (wave >> 1) * 64, wc = (wave & 1) * 64;
  const int fr = lane & 15, fc = lane >> 4;
  f32x4 acc[4][4] = {};
  const int r = tid >> 1, half = tid & 1;
  const int e = e0 + r;
  const int s_idx = esrc[e], d_idx = edst[e];
  for (int k0 = 0; k0 < 320; k0 += 32) {
    const int kk = k0 + half * 16;
    const float* ap;
    if (kk < 128)      ap = node_in + (size_t)s_idx*128 + kk;
    else if (kk < 256) ap = node_in + (size_t)d_idx*128 + (kk - 128);
    else               ap = elen + (size_t)e*64 + (kk - 256);
    u32* asp = (u32*)&As[r][half*16];
    #pragma unroll
    for (int q = 0; q < 4; ++q) {
      float4 v = *(const float4*)(ap + q*4);
      asp[q*2]   = pack2(v.x, v.y);
      asp[q*2+1] = pack2(v.z, v.w);
    }
    const uint4* bp = (const uint4*)(Bt1 + (size_t)r*320 + kk);
    *(uint4*)&Bs[r][half*16]     = bp[0];
    *(uint4*)&Bs[r][half*16 + 8] = bp[1];
    __syncthreads();
    bf16x8 a[4], b[4];
    #pragma unroll
    for (int mi = 0; mi < 4; ++mi) a[mi] = *(const bf16x8*)&As[wr + mi*16 + fr][fc*8];
    #pragma unroll
    for (int ni = 0; ni < 4; ++ni) b[ni] = *(const bf16x8*)&Bs[wc + ni*16 + fr][fc*8];
    #pragma unroll
    for (int mi = 0; mi < 4; ++mi)
      #pragma unroll
      for (int ni = 0; ni < 4; ++ni)
        acc[mi][ni] = __builtin_amdgcn_mfma_f32_16x16x32_bf16(a[mi], b[ni], acc[mi][ni], 0, 0, 0);
    __syncthreads();
  }
  #pragma unroll
  for (int mi = 0; mi < 4; ++mi)
    #pragma unroll
    for (int j = 0; j < 4; ++j) {
      int row = wr + mi*16 + fc*4 + j;
      size_t base = (size_t)(e0 + row)*128 + wc + fr;
      #pragma unroll
      for (int ni = 0; ni < 4; ++ni)
        msgb[base + ni*16] = f2bf(acc[mi][ni][j]);
    }
}

// ---------------- G2: t = msg @ Wcat ; y0 = sum_h c[h]*t[:,h*64+j] ----------
union G2Smem {
  struct { u16 As[64][40]; u16 Bs[256][40]; } s;
  float R[2][64][66];
};
__global__ __launch_bounds__(256) void g2_y0(
    const u16* __restrict__ msgb, const u16* __restrict__ Bt2,
    const float* __restrict__ cbuf, u16* __restrict__ y0h)
{
  __shared__ G2Smem u;
  __shared__ float cS[64][4];
  const int tid = threadIdx.x, wave = tid >> 6, lane = tid & 63;
  const int e0 = blockIdx.x * 64;
  const int fr = lane & 15, fc = lane >> 4;
  cS[tid >> 2][tid & 3] = cbuf[(size_t)e0*4 + tid];
  f32x4 acc[4][4] = {};
  for (int k0 = 0; k0 < 128; k0 += 32) {
    { // stage A (64 x 32)
      int r = tid >> 2, q = tid & 3;
      *(uint4*)&u.s.As[r][q*8] = *(const uint4*)(msgb + (size_t)(e0 + r)*128 + k0 + q*8);
    }
    { // stage B (256 x 32)
      const uint4* bp = (const uint4*)(Bt2 + (size_t)tid*128 + k0);
      *(uint4*)&u.s.Bs[tid][0]  = bp[0];
      *(uint4*)&u.s.Bs[tid][8]  = bp[1];
      *(uint4*)&u.s.Bs[tid][16] = bp[2];
      *(uint4*)&u.s.Bs[tid][24] = bp[3];
    }
    __syncthreads();
    bf16x8 a[4], b[4];
    #pragma unroll
    for (int mi = 0; mi < 4; ++mi) a[mi] = *(const bf16x8*)&u.s.As[mi*16 + fr][fc*8];
    #pragma unroll
    for (int ni = 0; ni < 4; ++ni) b[ni] = *(const bf16x8*)&u.s.Bs[wave*64 + ni*16 + fr][fc*8];
    #pragma unroll
    for (int mi = 0; mi < 4; ++mi)
      #pragma unroll
      for (int ni = 0; ni < 4; ++ni)
        acc[mi][ni] = __builtin_amdgcn_mfma_f32_16x16x32_bf16(a[mi], b[ni], acc[mi][ni], 0, 0, 0);
    __syncthreads();
  }
  const int h = wave;
  if ((wave & 1) == 0) {
    float (*Rb)[66] = u.R[wave >> 1];
    #pragma unroll
    for (int mi = 0; mi < 4; ++mi)
      #pragma unroll
      for (int j = 0; j < 4; ++j) {
        int row = mi*16 + fc*4 + j;
        float cv = cS[row][h];
        #pragma unroll
        for (int ni = 0; ni < 4; ++ni)
          Rb[row][ni*16 + fr] = acc[mi][ni][j] * cv;
      }
  }
  __syncthreads();
  if (wave & 1) {
    float (*Rb)[66] = u.R[wave >> 1];
    #pragma unroll
    for (int mi = 0; mi < 4; ++mi)
      #pragma unroll
      for (int j = 0; j < 4; ++j) {
        int row = mi*16 + fc*4 + j;
        float cv = cS[row][h];
        #pragma unroll
        for (int ni = 0; ni < 4; ++ni)
          Rb[row][ni*16 + fr] += acc[mi][ni][j] * cv;
      }
  }
  __syncthreads();
  {
    int rr = tid >> 2, j0 = (tid & 3) * 16;
    u16 tmp[16];
    #pragma unroll
    for (int i = 0; i < 16; ++i)
      tmp[i] = f2h(u.R[0][rr][j0 + i] + u.R[1][rr][j0 + i]);
    uint4* dst = (uint4*)(y0h + (size_t)(e0 + rr)*64 + j0);
    dst[0] = *(const uint4*)&tmp[0];
    dst[1] = *(const uint4*)&tmp[8];
  }
}

// ---------------- K9: per-node softmax + aggregation ------------------------
__global__ __launch_bounds__(256) void k_node(
  const int* __restrict__ offs, const int* __restrict__ eids,
  const float* __restrict__ alpha, const float* __restrict__ scal,
  const u16* __restrict__ msgb, u16* __restrict__ nfb)
{
  const int w = threadIdx.x >> 6, lane = threadIdx.x & 63;
  const int n = blockIdx.x * 4 + w;
  const int beg = offs[n], end = offs[n+1];
  float m0=-3e38f, m1=-3e38f, m2=-3e38f, m3=-3e38f;
  for (int i = beg + lane; i < end; i += 64) {
    int eid = eids[i];
    float4 a = *(const float4*)(alpha + (size_t)eid*4);
    m0 = fmaxf(m0, a.x); m1 = fmaxf(m1, a.y);
    m2 = fmaxf(m2, a.z); m3 = fmaxf(m3, a.w);
  }
  #pragma unroll
  for (int off = 1; off < 64; off <<= 1) {
    m0 = fmaxf(m0, __shfl_xor(m0, off));
    m1 = fmaxf(m1, __shfl_xor(m1, off));
    m2 = fmaxf(m2, __shfl_xor(m2, off));
    m3 = fmaxf(m3, __shfl_xor(m3, off));
  }
  float se0=0.f, se1=0.f, se2=0.f, se3=0.f;
  float f00=0.f, f01=0.f, f10=0.f, f11=0.f, f20=0.f, f21=0.f, f30=0.f, f31=0.f;
  for (int i = beg; i < end; ++i) {
    int eid = eids[i];
    float4 a = *(const float4*)(alpha + (size_t)eid*4);
    float4 s = *(const float4*)(scal + (size_t)eid*4);
    float e0 = __expf(a.x - m0), e1 = __expf(a.y - m1);
    float e2 = __expf(a.z - m2), e3 = __expf(a.w - m3);
    se0 += e0; se1 += e1; se2 += e2; se3 += e3;
    float w0 = e0*s.x, w1 = e1*s.y, w2 = e2*s.z, w3 = e3*s.w;
    float v0 = bf2f(msgb[(size_t)eid*128 + lane]);
    float v1 = bf2f(msgb[(size_t)eid*128 + 64 + lane]);
    f00 = fmaf(w0, v0, f00); f01 = fmaf(w0, v1, f01);
    f10 = fmaf(w1, v0, f10); f11 = fmaf(w1, v1, f11);
    f20 = fmaf(w2, v0, f20); f21 = fmaf(w2, v1, f21);
    f30 = fmaf(w3, v0, f30); f31 = fmaf(w3, v1, f31);
  }
  float i0 = 1.f/(se0 + 1e-16f), i1 = 1.f/(se1 + 1e-16f);
  float i2 = 1.f/(se2 + 1e-16f), i3 = 1.f/(se3 + 1e-16f);
  size_t b = (size_t)n * 512;
  nfb[b + 0*128 + lane]      = f2bf(f00*i0);
  nfb[b + 0*128 + 64 + lane] = f2bf(f01*i0);
  nfb[b + 1*128 + lane]      = f2bf(f10*i1);
  nfb[b + 1*128 + 64 + lane] = f2bf(f11*i1);
  nfb[b + 2*128 + lane]      = f2bf(f20*i2);
  nfb[b + 2*128 + 64 + lane] = f2bf(f21*i2);
  nfb[b + 3*128 + lane]      = f2bf(f30*i3);
  nfb[b + 3*128 + 64 + lane] = f2bf(f31*i3);
}

// ---------------- G10: node_out = node_fea @ lin_w --------------------------
__global__ __launch_bounds__(256) void g10_out(
    const u16* __restrict__ nfb, const u16* __restrict__ Bt3,
    float* __restrict__ out)
{
  __shared__ u16 As[128][40];
  __shared__ u16 Bs[128][40];
  const int tid = threadIdx.x;
  const int n0 = blockIdx.x * 128;
  const int wave = tid >> 6, lane = tid & 63;
  const int wr = (wave >> 1) * 64, wc = (wave & 1) * 64;
  const int fr = lane & 15, fc = lane >> 4;
  f32x4 acc[4][4] = {};
  const int r = tid >> 1, half = tid & 1;
  const int n = n0 + r;
  for (int k0 = 0; k0 < 512; k0 += 32) {
    uint4 z; z.x=0; z.y=0; z.z=0; z.w=0;
    uint4 v0 = z, v1 = z;
    if (n < NN) {
      const uint4* apv = (const uint4*)(nfb + (size_t)n*512 + k0 + half*16);
      v0 = apv[0]; v1 = apv[1];
    }
    *(uint4*)&As[r][half*16]     = v0;
    *(uint4*)&As[r][half*16 + 8] = v1;
    const uint4* bp = (const uint4*)(Bt3 + (size_t)r*512 + k0 + half*16);
    *(uint4*)&Bs[r][half*16]     = bp[0];
    *(uint4*)&Bs[r][half*16 + 8] = bp[1];
    __syncthreads();
    bf16x8 a[4], b[4];
    #pragma unroll
    for (int mi = 0; mi < 4; ++mi) a[mi] = *(const bf16x8*)&As[wr + mi*16 + fr][fc*8];
    #pragma unroll
    for (int ni = 0; ni < 4; ++ni) b[ni] = *(const bf16x8*)&Bs[wc + ni*16 + fr][fc*8];
    #pragma unroll
    for (int mi = 0; mi < 4; ++mi)
      #pragma unroll
      for (int ni = 0; ni < 4; ++ni)
        acc[mi][ni] = __builtin_amdgcn_mfma_f32_16x16x32_bf16(a[mi], b[ni], acc[mi][ni], 0, 0, 0);
    __syncthreads();
  }
  #pragma unroll
  for (int mi = 0; mi < 4; ++mi)
    #pragma unroll
    for (int j = 0; j < 4; ++j) {
      int rowg = n0 + wr + mi*16 + fc*4 + j;
      if (rowg < NN) {
        size_t base = (size_t)rowg*128 + wc + fr;
        #pragma unroll
        for (int ni = 0; ni < 4; ++ni)
          out[base + ni*16] = acc[mi][ni][j];
      }
    }
}

// ---------------- launch ----------------------------------------------------
extern "C" void kernel_launch(void* const* d_in, const int* in_sizes, int n_in,
                              void* d_out, int out_size, void* d_ws, size_t ws_size,
                              hipStream_t stream)
{
  const float* node_in    = (const float*)d_in[0];
  const float* edge_sh    = (const float*)d_in[2];
  const float* elen       = (const float*)d_in[3];
  const int*   esrc       = (const int*)d_in[4];
  const int*   edst       = (const int*)d_in[5];
  const float* pre_lin_w  = (const float*)d_in[7];
  const float* tp2_w1     = (const float*)d_in[8];
  const float* tp2_b1     = (const float*)d_in[9];
  const float* tp2_w2     = (const float*)d_in[10];
  const float* tp2_b2     = (const float*)d_in[11];
  const float* a_w1  = (const float*)d_in[12];
  const float* a_b1  = (const float*)d_in[13];
  const float* a_g1  = (const float*)d_in[14];
  const float* a_be1 = (const float*)d_in[15];
  const float* a_w2  = (const float*)d_in[16];
  const float* a_b2  = (const float*)d_in[17];
  const float* a_g2  = (const float*)d_in[18];
  const float* a_be2 = (const float*)d_in[19];
  const float* a_w3  = (const float*)d_in[20];
  const float* a_b3  = (const float*)d_in[21];
  const float* lin_w      = (const float*)d_in[22];
  const float* lin_edge_w = (const float*)d_in[23];
  const float* s_w1  = (const float*)d_in[24];
  const float* s_b1  = (const float*)d_in[25];
  const float* s_g1  = (const float*)d_in[26];
  const float* s_be1 = (const float*)d_in[27];
  const float* s_w2  = (const float*)d_in[28];
  const float* s_b2  = (const float*)d_in[29];
  const float* s_g2  = (const float*)d_in[30];
  const float* s_be2 = (const float*)d_in[31];
  const float* s_w3  = (const float*)d_in[32];
  const float* s_b3  = (const float*)d_in[33];

  float* out_node = (float*)d_out;
  float* out_edge = out_node + (size_t)NN * 128;

  char* ws = (char*)d_ws;
  size_t off = 0;
  auto take = [&](size_t bytes) -> char* {
    char* p = ws + off;
    off = (off + bytes + 255) & ~(size_t)255;
    return p;
  };
  u16*   msgb   = (u16*)take((size_t)EE * 128 * 2);
  u16*   y0h    = (u16*)take((size_t)EE * 64 * 2);
  u16*   nfb    = (u16*)take((size_t)NN * 512 * 2);
  float* alpha  = (float*)take((size_t)EE * 4 * 4);
  float* scal   = (float*)take((size_t)EE * 4 * 4);
  float* cbuf   = (float*)take((size_t)EE * 4 * 4);
  int*   counts = (int*)take((size_t)NN * 4);
  int*   offs   = (int*)take((size_t)(NN + 1) * 4);
  int*   cursor = (int*)take((size_t)NN * 4);
  int*   eids   = (int*)take((size_t)EE * 4);
  u16*   Bt1    = (u16*)take((size_t)128 * 320 * 2);
  u16*   Bt2    = (u16*)take((size_t)256 * 128 * 2);
  u16*   Bt3    = (u16*)take((size_t)128 * 512 * 2);
  u16*   Wmlp   = (u16*)take((size_t)WTOT * 2);

  // elen fp16 plane aliases msgb (dead until g1_msg runs)
  u16* elen_h = msgb;

  k_prep<<<544, 256, 0, stream>>>(pre_lin_w, lin_edge_w, lin_w, Bt1, Bt2, Bt3);
  k_prep2<<<(WTOT + 255)/256, 256, 0, stream>>>(a_w1, a_w2, a_w3, tp2_w1, tp2_w2,
                                                s_w1, s_w2, s_w3, Wmlp);
  k_prep3<<<EE*64/8/256, 256, 0, stream>>>(elen, elen_h);
  k_zero<<<(NN + 255)/256, 256, 0, stream>>>(counts);
  k_count<<<EE/256, 256, 0, stream>>>(edst, counts);
  k_scan<<<1, 1024, 0, stream>>>(counts, offs, cursor);
  k_fill<<<EE/256, 256, 0, stream>>>(edst, cursor, eids);
  k_sort<<<(NN + 255)/256, 256, 0, stream>>>(offs, eids);
  k_ar_mlp<<<EE/128, 256, 0, stream>>>(elen_h, edge_sh, Wmlp,
                                       a_b1, a_g1, a_be1, a_b2, a_g2, a_be2, a_b3,
                                       tp2_b1, tp2_b2, alpha, scal, cbuf);
  g1_msg<<<EE/128, 256, 0, stream>>>(node_in, elen, esrc, edst, Bt1, msgb);
  g2_y0<<<EE/64, 256, 0, stream>>>(msgb, Bt2, cbuf, y0h);
  k_smlp2<<<EE/128, 256, 0, stream>>>(y0h, Wmlp, s_b1, s_g1, s_be1,
                                      s_b2, s_g2, s_be2, s_b3, out_edge);
  k_node<<<NN/4, 256, 0, stream>>>(offs, eids, alpha, scal, msgb, nfb);
  g10_out<<<(NN + 127)/128, 256, 0, stream>>>(nfb, Bt3, out_node);
}

// Round 8
// 484.889 us; speedup vs baseline: 1.3437x; 1.0684x over previous
//
#include <hip/hip_runtime.h>

#define NN 20000
#define EE 320000
#define WTOT 27648

typedef unsigned short u16;
typedef unsigned int u32;
typedef __attribute__((ext_vector_type(8))) short bf16x8;
typedef __attribute__((ext_vector_type(8))) _Float16 f16x8;
typedef __attribute__((ext_vector_type(4))) float f32x4;

__device__ __forceinline__ float bf2f(u16 u){
  union { u32 i; float f; } v; v.i = ((u32)u) << 16; return v.f;
}
__device__ __forceinline__ u16 f2bf(float f){
  union { float f; u32 i; } v; v.f = f;
  u32 i = v.i;
  return (u16)((i + 0x7FFFu + ((i >> 16) & 1u)) >> 16);
}
__device__ __forceinline__ u32 pack2(float a, float b){
  return ((u32)f2bf(b) << 16) | (u32)f2bf(a);
}
__device__ __forceinline__ u16 f2h(float f){
  union { _Float16 h[2]; u32 u; } v; v.h[0] = (_Float16)f;
  return (u16)(v.u & 0xFFFF);
}

// ---------------- weight pre-transpose (to bf16, [n][k] layout) -------------
__global__ __launch_bounds__(256) void k_prep(
    const float* __restrict__ plw, const float* __restrict__ lew,
    const float* __restrict__ lw,
    u16* __restrict__ Bt1, u16* __restrict__ Bt2, u16* __restrict__ Bt3)
{
  int i = blockIdx.x * 256 + threadIdx.x;
  if (i < 128*320) {                       // Bt1[n][k] = pre_lin_w[k][n]
    int n = i / 320, k = i % 320;
    Bt1[i] = f2bf(plw[k*128 + n]);
  }
  int j = i - 128*320;
  if (j >= 0 && j < 256*128) {             // Bt2[h*64+c][k] = lin_edge_w[h*128+k][c]
    int n = j / 128, k = j % 128;
    int h = n >> 6, c = n & 63;
    Bt2[j] = f2bf(lew[(h*128 + k)*64 + c]);
  }
  int l = i - 128*320 - 256*128;
  if (l >= 0 && l < 128*512) {             // Bt3[n][k] = lin_w[k][n]
    int n = l / 512, k = l % 512;
    Bt3[l] = f2bf(lw[k*128 + n]);
  }
}

// MLP weights, transposed to [out][in], fp16.
// Layout: Wc1[8192]=[Wa1|Wr1] Wa2[4096] Wa3[1024(pad16x64)] Wr2[4096]
//         Ws1[4096] Ws2[4096] Ws3[2048]
__global__ __launch_bounds__(256) void k_prep2(
    const float* __restrict__ aw1, const float* __restrict__ aw2, const float* __restrict__ aw3,
    const float* __restrict__ rw1, const float* __restrict__ rw2,
    const float* __restrict__ sw1, const float* __restrict__ sw2, const float* __restrict__ sw3,
    u16* __restrict__ W)
{
  int i = blockIdx.x * 256 + threadIdx.x;
  if (i >= WTOT) return;
  float v = 0.f;
  int j = i;
  if (j < 8192)      { int n = j >> 6, k = j & 63;
                       v = (n < 64) ? aw1[k*64 + n] : rw1[k*64 + (n - 64)]; }
  else if ((j -= 8192) < 4096) { int n = j >> 6, k = j & 63; v = aw2[k*64 + n]; }
  else if ((j -= 4096) < 1024) { int n = j >> 6, k = j & 63; v = (n < 4) ? aw3[k*4 + n] : 0.f; }
  else if ((j -= 1024) < 4096) { int n = j >> 6, k = j & 63; v = rw2[k*64 + n]; }
  else if ((j -= 4096) < 4096) { int n = j >> 6, k = j & 63; v = sw1[k*64 + n]; }
  else if ((j -= 4096) < 4096) { int n = j >> 6, k = j & 63; v = sw2[k*64 + n]; }
  else               { j -= 4096; int n = j >> 6, k = j & 63; v = sw3[k*32 + n]; }
  W[i] = f2h(v);
}

// ---------------- CSR build -------------------------------------------------
__global__ __launch_bounds__(256) void k_zero(int* __restrict__ counts){
  int i = blockIdx.x * 256 + threadIdx.x;
  if (i < NN) counts[i] = 0;
}
__global__ __launch_bounds__(256) void k_count(const int* __restrict__ edst, int* __restrict__ counts){
  int e = blockIdx.x * 256 + threadIdx.x;
  if (e < EE) atomicAdd(&counts[edst[e]], 1);
}
__global__ __launch_bounds__(1024) void k_scan(const int* __restrict__ counts,
                                               int* __restrict__ offs, int* __restrict__ cursor){
  __shared__ int part[1024];
  int t = threadIdx.x;
  int c0 = t * 20, c1 = c0 + 20; if (c1 > NN) c1 = NN; if (c0 > NN) c0 = NN;
  int s = 0;
  for (int i = c0; i < c1; ++i) s += counts[i];
  part[t] = s;
  __syncthreads();
  if (t == 0) {
    int run = 0;
    for (int i = 0; i < 1024; ++i) { int v = part[i]; part[i] = run; run += v; }
    offs[NN] = run;
  }
  __syncthreads();
  int run = part[t];
  for (int i = c0; i < c1; ++i) { offs[i] = run; cursor[i] = run; run += counts[i]; }
}
__global__ __launch_bounds__(256) void k_fill(const int* __restrict__ edst,
                                              int* __restrict__ cursor, int* __restrict__ eids){
  int e = blockIdx.x * 256 + threadIdx.x;
  if (e < EE) { int p = atomicAdd(&cursor[edst[e]], 1); eids[p] = e; }
}
__global__ __launch_bounds__(256) void k_sort(const int* __restrict__ offs, int* __restrict__ eids){
  int n = blockIdx.x * 256 + threadIdx.x;
  if (n >= NN) return;
  int b = offs[n], e = offs[n+1];
  for (int i = b + 1; i < e; ++i) {
    int v = eids[i]; int j = i - 1;
    while (j >= b && eids[j] > v) { eids[j+1] = eids[j]; --j; }
    eids[j+1] = v;
  }
}

// ---------------- FP16 MFMA MLP building blocks -----------------------------
// 2-row-block (32 rows/wave) LDS gemm: acc[2][NI] independent chains.
template<int NI>
__device__ __forceinline__ void gemm16_lds(const u16 (*X)[72], int wrow, int lane,
                                           const u16* __restrict__ B, f32x4 acc[2][4])
{
  const int fr = lane & 15, fc = lane >> 4;
  #pragma unroll
  for (int mi = 0; mi < 2; ++mi)
    #pragma unroll
    for (int ni = 0; ni < NI; ++ni)
      acc[mi][ni] = (f32x4){0.f, 0.f, 0.f, 0.f};
  #pragma unroll
  for (int kk = 0; kk < 2; ++kk) {
    f16x8 a0 = *(const f16x8*)&X[wrow + fr][kk*32 + fc*8];
    f16x8 a1 = *(const f16x8*)&X[wrow + 16 + fr][kk*32 + fc*8];
    #pragma unroll
    for (int ni = 0; ni < NI; ++ni) {
      f16x8 b = *(const f16x8*)(B + (size_t)(ni*16 + fr)*64 + kk*32 + fc*8);
      acc[0][ni] = __builtin_amdgcn_mfma_f32_16x16x32_f16(a0, b, acc[0][ni], 0, 0, 0);
      acc[1][ni] = __builtin_amdgcn_mfma_f32_16x16x32_f16(a1, b, acc[1][ni], 0, 0, 0);
    }
  }
}

// 1-row-block (16 rows/wave) LDS gemm for the fused s-MLP tail.
template<int NI>
__device__ __forceinline__ void gemm16_lds1(const u16 (*X)[72], int wrow, int lane,
                                            const u16* __restrict__ B, f32x4 acc[4])
{
  const int fr = lane & 15, fc = lane >> 4;
  #pragma unroll
  for (int ni = 0; ni < NI; ++ni) acc[ni] = (f32x4){0.f, 0.f, 0.f, 0.f};
  #pragma unroll
  for (int kk = 0; kk < 2; ++kk) {
    f16x8 a = *(const f16x8*)&X[wrow + fr][kk*32 + fc*8];
    #pragma unroll
    for (int ni = 0; ni < NI; ++ni) {
      f16x8 b = *(const f16x8*)(B + (size_t)(ni*16 + fr)*64 + kk*32 + fc*8);
      acc[ni] = __builtin_amdgcn_mfma_f32_16x16x32_f16(a, b, acc[ni], 0, 0, 0);
    }
  }
}

// NI=8 gemm with A loaded as fp32 from global (elen) and converted in-register.
__device__ __forceinline__ void gemm32_glb8(const float* __restrict__ X, int row0, int lane,
                                            const u16* __restrict__ B, f32x4 acc[2][8])
{
  const int fr = lane & 15, fc = lane >> 4;
  #pragma unroll
  for (int mi = 0; mi < 2; ++mi)
    #pragma unroll
    for (int ni = 0; ni < 8; ++ni)
      acc[mi][ni] = (f32x4){0.f, 0.f, 0.f, 0.f};
  #pragma unroll
  for (int kk = 0; kk < 2; ++kk) {
    const float* p0 = X + (size_t)(row0 + fr)*64 + kk*32 + fc*8;
    const float* p1 = X + (size_t)(row0 + 16 + fr)*64 + kk*32 + fc*8;
    float4 v00 = ((const float4*)p0)[0], v01 = ((const float4*)p0)[1];
    float4 v10 = ((const float4*)p1)[0], v11 = ((const float4*)p1)[1];
    f16x8 a0, a1;
    a0[0]=(_Float16)v00.x; a0[1]=(_Float16)v00.y; a0[2]=(_Float16)v00.z; a0[3]=(_Float16)v00.w;
    a0[4]=(_Float16)v01.x; a0[5]=(_Float16)v01.y; a0[6]=(_Float16)v01.z; a0[7]=(_Float16)v01.w;
    a1[0]=(_Float16)v10.x; a1[1]=(_Float16)v10.y; a1[2]=(_Float16)v10.z; a1[3]=(_Float16)v10.w;
    a1[4]=(_Float16)v11.x; a1[5]=(_Float16)v11.y; a1[6]=(_Float16)v11.z; a1[7]=(_Float16)v11.w;
    #pragma unroll
    for (int ni = 0; ni < 8; ++ni) {
      f16x8 b = *(const f16x8*)(B + (size_t)(ni*16 + fr)*64 + kk*32 + fc*8);
      acc[0][ni] = __builtin_amdgcn_mfma_f32_16x16x32_f16(a0, b, acc[0][ni], 0, 0, 0);
      acc[1][ni] = __builtin_amdgcn_mfma_f32_16x16x32_f16(a1, b, acc[1][ni], 0, 0, 0);
    }
  }
}

// bias (+ optional LN) + SiLU on 2-row-block C fragments, store fp16
template<bool LN>
__device__ __forceinline__ void act_store16(f32x4 acc[2][4],
    const float* __restrict__ b, const float* __restrict__ g, const float* __restrict__ be,
    u16 (*H)[72], int wrow, int lane)
{
  const int fr = lane & 15, fc = lane >> 4;
  float bv[4], gv[4], bev[4];
  #pragma unroll
  for (int ni = 0; ni < 4; ++ni) {
    bv[ni] = b[ni*16 + fr];
    if (LN) { gv[ni] = g[ni*16 + fr]; bev[ni] = be[ni*16 + fr]; }
  }
  #pragma unroll
  for (int mi = 0; mi < 2; ++mi)
    #pragma unroll
    for (int j = 0; j < 4; ++j) {
      int r = wrow + mi*16 + fc*4 + j;
      float x[4];
      #pragma unroll
      for (int ni = 0; ni < 4; ++ni) x[ni] = acc[mi][ni][j] + bv[ni];
      if (LN) {
        float s  = x[0] + x[1] + x[2] + x[3];
        float s2 = x[0]*x[0] + x[1]*x[1] + x[2]*x[2] + x[3]*x[3];
        #pragma unroll
        for (int off = 1; off < 16; off <<= 1) {
          s  += __shfl_xor(s,  off);
          s2 += __shfl_xor(s2, off);
        }
        float mu  = s * (1.f/64.f);
        float var = s2 * (1.f/64.f) - mu*mu;
        float rs  = rsqrtf(var + 1e-6f);
        #pragma unroll
        for (int ni = 0; ni < 4; ++ni) x[ni] = (x[ni] - mu)*rs*gv[ni] + bev[ni];
      }
      #pragma unroll
      for (int ni = 0; ni < 4; ++ni) {
        float y = x[ni];
        y = y / (1.f + __expf(-y));
        H[r][ni*16 + fr] = f2h(y);
      }
    }
}

// 1-row-block version (fused s-MLP tail)
template<bool LN>
__device__ __forceinline__ void act_store16_1(f32x4 acc[4],
    const float* __restrict__ b, const float* __restrict__ g, const float* __restrict__ be,
    u16 (*H)[72], int wrow, int lane)
{
  const int fr = lane & 15, fc = lane >> 4;
  float bv[4], gv[4], bev[4];
  #pragma unroll
  for (int ni = 0; ni < 4; ++ni) {
    bv[ni] = b[ni*16 + fr];
    if (LN) { gv[ni] = g[ni*16 + fr]; bev[ni] = be[ni*16 + fr]; }
  }
  #pragma unroll
  for (int j = 0; j < 4; ++j) {
    int r = wrow + fc*4 + j;
    float x[4];
    #pragma unroll
    for (int ni = 0; ni < 4; ++ni) x[ni] = acc[ni][j] + bv[ni];
    if (LN) {
      float s  = x[0] + x[1] + x[2] + x[3];
      float s2 = x[0]*x[0] + x[1]*x[1] + x[2]*x[2] + x[3]*x[3];
      #pragma unroll
      for (int off = 1; off < 16; off <<= 1) {
        s  += __shfl_xor(s,  off);
        s2 += __shfl_xor(s2, off);
      }
      float mu  = s * (1.f/64.f);
      float var = s2 * (1.f/64.f) - mu*mu;
      float rs  = rsqrtf(var + 1e-6f);
      #pragma unroll
      for (int ni = 0; ni < 4; ++ni) x[ni] = (x[ni] - mu)*rs*gv[ni] + bev[ni];
    }
    #pragma unroll
    for (int ni = 0; ni < 4; ++ni) {
      float y = x[ni];
      y = y / (1.f + __expf(-y));
      H[r][ni*16 + fr] = f2h(y);
    }
  }
}

// ---------------- fused alpha + radial MLPs (4 gemm phases) -----------------
__global__ __launch_bounds__(256, 4) void k_ar_mlp(
  const float* __restrict__ elen,
  const float* __restrict__ esh, const u16* __restrict__ Wm,
  const float* __restrict__ ab1, const float* __restrict__ ag1, const float* __restrict__ abe1,
  const float* __restrict__ ab2, const float* __restrict__ ag2, const float* __restrict__ abe2,
  const float* __restrict__ ab3,
  const float* __restrict__ tb1, const float* __restrict__ tb2,
  float* __restrict__ alpha_g, float* __restrict__ scal_g, float* __restrict__ cbuf_g)
{
  __shared__ u16 Ha[128][72], Hr[128][72];
  __shared__ float aS[128][4];
  const u16* Wc1 = Wm;            // [Wa1|Wr1], 128 outs
  const u16* Wa2 = Wm + 8192;
  const u16* Wa3 = Wm + 12288;
  const u16* Wr2 = Wm + 13312;
  const int tid = threadIdx.x;
  const int wave = tid >> 6, lane = tid & 63;
  const int fr = lane & 15, fc = lane >> 4;
  const int wrow = wave * 32;
  const int e0 = blockIdx.x * 128;
  // phase 1: combined L1 (alpha outs 0..63, radial outs 64..127)
  {
    f32x4 acc8[2][8];
    gemm32_glb8(elen, e0 + wrow, lane, Wc1, acc8);
    float bva[4], gva[4], beva[4], bvr[4];
    #pragma unroll
    for (int ni = 0; ni < 4; ++ni) {
      bva[ni] = ab1[ni*16 + fr]; gva[ni] = ag1[ni*16 + fr]; beva[ni] = abe1[ni*16 + fr];
      bvr[ni] = tb1[ni*16 + fr];
    }
    #pragma unroll
    for (int mi = 0; mi < 2; ++mi)
      #pragma unroll
      for (int j = 0; j < 4; ++j) {
        int r = wrow + mi*16 + fc*4 + j;
        float xa[4], xr[4];
        #pragma unroll
        for (int ni = 0; ni < 4; ++ni) {
          xa[ni] = acc8[mi][ni][j] + bva[ni];
          xr[ni] = acc8[mi][ni+4][j] + bvr[ni];
        }
        // alpha: LN + SiLU
        float s  = xa[0] + xa[1] + xa[2] + xa[3];
        float s2 = xa[0]*xa[0] + xa[1]*xa[1] + xa[2]*xa[2] + xa[3]*xa[3];
        #pragma unroll
        for (int off = 1; off < 16; off <<= 1) {
          s  += __shfl_xor(s,  off);
          s2 += __shfl_xor(s2, off);
        }
        float mu  = s * (1.f/64.f);
        float var = s2 * (1.f/64.f) - mu*mu;
        float rs  = rsqrtf(var + 1e-6f);
        #pragma unroll
        for (int ni = 0; ni < 4; ++ni) {
          float y = (xa[ni] - mu)*rs*gva[ni] + beva[ni];
          y = y / (1.f + __expf(-y));
          Ha[r][ni*16 + fr] = f2h(y);
          float z = xr[ni];
          z = z / (1.f + __expf(-z));
          Hr[r][ni*16 + fr] = f2h(z);
        }
      }
  }
  f32x4 acc[2][4];
  // alpha L2 (in-place on Ha)
  gemm16_lds<4>(Ha, wrow, lane, Wa2, acc);
  act_store16<true>(acc, ab2, ag2, abe2, Ha, wrow, lane);
  // alpha L3: N=4 (padded to 16)
  gemm16_lds<1>(Ha, wrow, lane, Wa3, acc);
  {
    float bv = (fr < 4) ? ab3[fr] : 0.f;
    #pragma unroll
    for (int mi = 0; mi < 2; ++mi)
      #pragma unroll
      for (int j = 0; j < 4; ++j) {
        int r = wrow + mi*16 + fc*4 + j;
        float v = acc[mi][0][j] + bv;
        if (fr < 4) {
          alpha_g[(size_t)(e0 + r)*4 + fr] = v;
          aS[r][fr] = v;
        }
      }
  }
  // radial L2 + sh contraction
  gemm16_lds<4>(Hr, wrow, lane, Wr2, acc);
  {
    float bv[4];
    #pragma unroll
    for (int ni = 0; ni < 4; ++ni) bv[ni] = tb2[ni*16 + fr];
    #pragma unroll
    for (int mi = 0; mi < 2; ++mi)
      #pragma unroll
      for (int j = 0; j < 4; ++j) {
        int r = wrow + mi*16 + fc*4 + j;
        float shv = esh[(size_t)(e0 + r)*16 + fr];
        float sc[4];
        #pragma unroll
        for (int ni = 0; ni < 4; ++ni) {
          float t = (acc[mi][ni][j] + bv[ni]) * shv;
          #pragma unroll
          for (int off = 1; off < 16; off <<= 1) t += __shfl_xor(t, off);
          sc[ni] = t;
        }
        if (fr == 0) {
          float4 sv; sv.x = sc[0]; sv.y = sc[1]; sv.z = sc[2]; sv.w = sc[3];
          *(float4*)(scal_g + (size_t)(e0 + r)*4) = sv;
          float4 cv;
          cv.x = sc[0]*aS[r][0]; cv.y = sc[1]*aS[r][1];
          cv.z = sc[2]*aS[r][2]; cv.w = sc[3]*aS[r][3];
          *(float4*)(cbuf_g + (size_t)(e0 + r)*4) = cv;
        }
      }
  }
}

// ---------------- G1: msg = [x_src|x_dst|elen] @ pre_lin_w  (bf16 out) ------
__global__ __launch_bounds__(256) void g1_msg(
    const float* __restrict__ node_in, const float* __restrict__ elen,
    const int* __restrict__ esrc, const int* __restrict__ edst,
    const u16* __restrict__ Bt1, u16* __restrict__ msgb)
{
  __shared__ u16 As[128][40];
  __shared__ u16 Bs[128][40];
  const int tid = threadIdx.x;
  const int e0 = blockIdx.x * 128;
  const int wave = tid >> 6, lane = tid & 63;
  const int wr = (wave >> 1) * 64, wc = (wave & 1) * 64;
  const int fr = lane & 15, fc = lane >> 4;
  f32x4 acc[4][4] = {};
  const int r = tid >> 1, half = tid & 1;
  const int e = e0 + r;
  const int s_idx = esrc[e], d_idx = edst[e];
  for (int k0 = 0; k0 < 320; k0 += 32) {
    const int kk = k0 + half * 16;
    const float* ap;
    if (kk < 128)      ap = node_in + (size_t)s_idx*128 + kk;
    else if (kk < 256) ap = node_in + (size_t)d_idx*128 + (kk - 128);
    else               ap = elen + (size_t)e*64 + (kk - 256);
    u32* asp = (u32*)&As[r][half*16];
    #pragma unroll
    for (int q = 0; q < 4; ++q) {
      float4 v = *(const float4*)(ap + q*4);
      asp[q*2]   = pack2(v.x, v.y);
      asp[q*2+1] = pack2(v.z, v.w);
    }
    const uint4* bp = (const uint4*)(Bt1 + (size_t)r*320 + kk);
    *(uint4*)&Bs[r][half*16]     = bp[0];
    *(uint4*)&Bs[r][half*16 + 8] = bp[1];
    __syncthreads();
    bf16x8 a[4], b[4];
    #pragma unroll
    for (int mi = 0; mi < 4; ++mi) a[mi] = *(const bf16x8*)&As[wr + mi*16 + fr][fc*8];
    #pragma unroll
    for (int ni = 0; ni < 4; ++ni) b[ni] = *(const bf16x8*)&Bs[wc + ni*16 + fr][fc*8];
    #pragma unroll
    for (int mi = 0; mi < 4; ++mi)
      #pragma unroll
      for (int ni = 0; ni < 4; ++ni)
        acc[mi][ni] = __builtin_amdgcn_mfma_f32_16x16x32_bf16(a[mi], b[ni], acc[mi][ni], 0, 0, 0);
    __syncthreads();
  }
  #pragma unroll
  for (int mi = 0; mi < 4; ++mi)
    #pragma unroll
    for (int j = 0; j < 4; ++j) {
      int row = wr + mi*16 + fc*4 + j;
      size_t base = (size_t)(e0 + row)*128 + wc + fr;
      #pragma unroll
      for (int ni = 0; ni < 4; ++ni)
        msgb[base + ni*16] = f2bf(acc[mi][ni][j]);
    }
}

// ---- G2S: t = msg @ Wcat ; y0 = sum_h c[h]*t ; edge_scalar = sMLP(y0) ------
union G2Smem {
  struct { u16 As[64][40]; u16 Bs[256][40]; } s;
  float R[2][64][66];
};
__global__ __launch_bounds__(256) void g2s(
    const u16* __restrict__ msgb, const u16* __restrict__ Bt2,
    const float* __restrict__ cbuf, const u16* __restrict__ Wm,
    const float* __restrict__ b1, const float* __restrict__ g1, const float* __restrict__ be1,
    const float* __restrict__ b2, const float* __restrict__ g2, const float* __restrict__ be2,
    const float* __restrict__ b3,
    float* __restrict__ oute)
{
  __shared__ G2Smem u;
  __shared__ float cS[64][4];
  __shared__ u16 X[64][72];
  const u16* Ws1 = Wm + 17408;
  const u16* Ws2 = Wm + 21504;
  const u16* Ws3 = Wm + 25600;
  const int tid = threadIdx.x, wave = tid >> 6, lane = tid & 63;
  const int e0 = blockIdx.x * 64;
  const int fr = lane & 15, fc = lane >> 4;
  cS[tid >> 2][tid & 3] = cbuf[(size_t)e0*4 + tid];
  f32x4 acc[4][4] = {};
  for (int k0 = 0; k0 < 128; k0 += 32) {
    { // stage A (64 x 32)
      int r = tid >> 2, q = tid & 3;
      *(uint4*)&u.s.As[r][q*8] = *(const uint4*)(msgb + (size_t)(e0 + r)*128 + k0 + q*8);
    }
    { // stage B (256 x 32)
      const uint4* bp = (const uint4*)(Bt2 + (size_t)tid*128 + k0);
      *(uint4*)&u.s.Bs[tid][0]  = bp[0];
      *(uint4*)&u.s.Bs[tid][8]  = bp[1];
      *(uint4*)&u.s.Bs[tid][16] = bp[2];
      *(uint4*)&u.s.Bs[tid][24] = bp[3];
    }
    __syncthreads();
    bf16x8 a[4], b[4];
    #pragma unroll
    for (int mi = 0; mi < 4; ++mi) a[mi] = *(const bf16x8*)&u.s.As[mi*16 + fr][fc*8];
    #pragma unroll
    for (int ni = 0; ni < 4; ++ni) b[ni] = *(const bf16x8*)&u.s.Bs[wave*64 + ni*16 + fr][fc*8];
    #pragma unroll
    for (int mi = 0; mi < 4; ++mi)
      #pragma unroll
      for (int ni = 0; ni < 4; ++ni)
        acc[mi][ni] = __builtin_amdgcn_mfma_f32_16x16x32_bf16(a[mi], b[ni], acc[mi][ni], 0, 0, 0);
    __syncthreads();
  }
  const int h = wave;
  if ((wave & 1) == 0) {
    float (*Rb)[66] = u.R[wave >> 1];
    #pragma unroll
    for (int mi = 0; mi < 4; ++mi)
      #pragma unroll
      for (int j = 0; j < 4; ++j) {
        int row = mi*16 + fc*4 + j;
        float cv = cS[row][h];
        #pragma unroll
        for (int ni = 0; ni < 4; ++ni)
          Rb[row][ni*16 + fr] = acc[mi][ni][j] * cv;
      }
  }
  __syncthreads();
  if (wave & 1) {
    float (*Rb)[66] = u.R[wave >> 1];
    #pragma unroll
    for (int mi = 0; mi < 4; ++mi)
      #pragma unroll
      for (int j = 0; j < 4; ++j) {
        int row = mi*16 + fc*4 + j;
        float cv = cS[row][h];
        #pragma unroll
        for (int ni = 0; ni < 4; ++ni)
          Rb[row][ni*16 + fr] += acc[mi][ni][j] * cv;
      }
  }
  __syncthreads();
  { // y0 -> X fp16 (thread tid writes row tid>>2: wave-private rows)
    int rr = tid >> 2, j0 = (tid & 3) * 16;
    #pragma unroll
    for (int i = 0; i < 16; ++i)
      X[rr][j0 + i] = f2h(u.R[0][rr][j0 + i] + u.R[1][rr][j0 + i]);
  }
  // s-MLP tail: wave w owns rows [w*16, w*16+16) — barrier-free
  const int wrow = wave * 16;
  f32x4 sa[4];
  gemm16_lds1<4>(X, wrow, lane, Ws1, sa);
  act_store16_1<true>(sa, b1, g1, be1, X, wrow, lane);
  gemm16_lds1<4>(X, wrow, lane, Ws2, sa);
  act_store16_1<true>(sa, b2, g2, be2, X, wrow, lane);
  gemm16_lds1<2>(X, wrow, lane, Ws3, sa);
  {
    float bv[2];
    bv[0] = b3[fr]; bv[1] = b3[16 + fr];
    #pragma unroll
    for (int j = 0; j < 4; ++j) {
      int r = wrow + fc*4 + j;
      #pragma unroll
      for (int ni = 0; ni < 2; ++ni)
        oute[(size_t)(e0 + r)*32 + ni*16 + fr] = sa[ni][j] + bv[ni];
    }
  }
}

// ---------------- K9: per-node softmax + aggregation ------------------------
__global__ __launch_bounds__(256) void k_node(
  const int* __restrict__ offs, const int* __restrict__ eids,
  const float* __restrict__ alpha, const float* __restrict__ scal,
  const u16* __restrict__ msgb, u16* __restrict__ nfb)
{
  const int w = threadIdx.x >> 6, lane = threadIdx.x & 63;
  const int n = blockIdx.x * 4 + w;
  const int beg = offs[n], end = offs[n+1];
  float m0=-3e38f, m1=-3e38f, m2=-3e38f, m3=-3e38f;
  for (int i = beg + lane; i < end; i += 64) {
    int eid = eids[i];
    float4 a = *(const float4*)(alpha + (size_t)eid*4);
    m0 = fmaxf(m0, a.x); m1 = fmaxf(m1, a.y);
    m2 = fmaxf(m2, a.z); m3 = fmaxf(m3, a.w);
  }
  #pragma unroll
  for (int off = 1; off < 64; off <<= 1) {
    m0 = fmaxf(m0, __shfl_xor(m0, off));
    m1 = fmaxf(m1, __shfl_xor(m1, off));
    m2 = fmaxf(m2, __shfl_xor(m2, off));
    m3 = fmaxf(m3, __shfl_xor(m3, off));
  }
  float se0=0.f, se1=0.f, se2=0.f, se3=0.f;
  float f00=0.f, f01=0.f, f10=0.f, f11=0.f, f20=0.f, f21=0.f, f30=0.f, f31=0.f;
  for (int i = beg; i < end; ++i) {
    int eid = eids[i];
    float4 a = *(const float4*)(alpha + (size_t)eid*4);
    float4 s = *(const float4*)(scal + (size_t)eid*4);
    float e0 = __expf(a.x - m0), e1 = __expf(a.y - m1);
    float e2 = __expf(a.z - m2), e3 = __expf(a.w - m3);
    se0 += e0; se1 += e1; se2 += e2; se3 += e3;
    float w0 = e0*s.x, w1 = e1*s.y, w2 = e2*s.z, w3 = e3*s.w;
    float v0 = bf2f(msgb[(size_t)eid*128 + lane]);
    float v1 = bf2f(msgb[(size_t)eid*128 + 64 + lane]);
    f00 = fmaf(w0, v0, f00); f01 = fmaf(w0, v1, f01);
    f10 = fmaf(w1, v0, f10); f11 = fmaf(w1, v1, f11);
    f20 = fmaf(w2, v0, f20); f21 = fmaf(w2, v1, f21);
    f30 = fmaf(w3, v0, f30); f31 = fmaf(w3, v1, f31);
  }
  float i0 = 1.f/(se0 + 1e-16f), i1 = 1.f/(se1 + 1e-16f);
  float i2 = 1.f/(se2 + 1e-16f), i3 = 1.f/(se3 + 1e-16f);
  size_t b = (size_t)n * 512;
  nfb[b + 0*128 + lane]      = f2bf(f00*i0);
  nfb[b + 0*128 + 64 + lane] = f2bf(f01*i0);
  nfb[b + 1*128 + lane]      = f2bf(f10*i1);
  nfb[b + 1*128 + 64 + lane] = f2bf(f11*i1);
  nfb[b + 2*128 + lane]      = f2bf(f20*i2);
  nfb[b + 2*128 + 64 + lane] = f2bf(f21*i2);
  nfb[b + 3*128 + lane]      = f2bf(f30*i3);
  nfb[b + 3*128 + 64 + lane] = f2bf(f31*i3);
}

// ---------------- G10: node_out = node_fea @ lin_w --------------------------
__global__ __launch_bounds__(256) void g10_out(
    const u16* __restrict__ nfb, const u16* __restrict__ Bt3,
    float* __restrict__ out)
{
  __shared__ u16 As[128][40];
  __shared__ u16 Bs[128][40];
  const int tid = threadIdx.x;
  const int n0 = blockIdx.x * 128;
  const int wave = tid >> 6, lane = tid & 63;
  const int wr = (wave >> 1) * 64, wc = (wave & 1) * 64;
  const int fr = lane & 15, fc = lane >> 4;
  f32x4 acc[4][4] = {};
  const int r = tid >> 1, half = tid & 1;
  const int n = n0 + r;
  for (int k0 = 0; k0 < 512; k0 += 32) {
    uint4 z; z.x=0; z.y=0; z.z=0; z.w=0;
    uint4 v0 = z, v1 = z;
    if (n < NN) {
      const uint4* apv = (const uint4*)(nfb + (size_t)n*512 + k0 + half*16);
      v0 = apv[0]; v1 = apv[1];
    }
    *(uint4*)&As[r][half*16]     = v0;
    *(uint4*)&As[r][half*16 + 8] = v1;
    const uint4* bp = (const uint4*)(Bt3 + (size_t)r*512 + k0 + half*16);
    *(uint4*)&Bs[r][half*16]     = bp[0];
    *(uint4*)&Bs[r][half*16 + 8] = bp[1];
    __syncthreads();
    bf16x8 a[4], b[4];
    #pragma unroll
    for (int mi = 0; mi < 4; ++mi) a[mi] = *(const bf16x8*)&As[wr + mi*16 + fr][fc*8];
    #pragma unroll
    for (int ni = 0; ni < 4; ++ni) b[ni] = *(const bf16x8*)&Bs[wc + ni*16 + fr][fc*8];
    #pragma unroll
    for (int mi = 0; mi < 4; ++mi)
      #pragma unroll
      for (int ni = 0; ni < 4; ++ni)
        acc[mi][ni] = __builtin_amdgcn_mfma_f32_16x16x32_bf16(a[mi], b[ni], acc[mi][ni], 0, 0, 0);
    __syncthreads();
  }
  #pragma unroll
  for (int mi = 0; mi < 4; ++mi)
    #pragma unroll
    for (int j = 0; j < 4; ++j) {
      int rowg = n0 + wr + mi*16 + fc*4 + j;
      if (rowg < NN) {
        size_t base = (size_t)rowg*128 + wc + fr;
        #pragma unroll
        for (int ni = 0; ni < 4; ++ni)
          out[base + ni*16] = acc[mi][ni][j];
      }
    }
}

// ---------------- launch ----------------------------------------------------
extern "C" void kernel_launch(void* const* d_in, const int* in_sizes, int n_in,
                              void* d_out, int out_size, void* d_ws, size_t ws_size,
                              hipStream_t stream)
{
  const float* node_in    = (const float*)d_in[0];
  const float* edge_sh    = (const float*)d_in[2];
  const float* elen       = (const float*)d_in[3];
  const int*   esrc       = (const int*)d_in[4];
  const int*   edst       = (const int*)d_in[5];
  const float* pre_lin_w  = (const float*)d_in[7];
  const float* tp2_w1     = (const float*)d_in[8];
  const float* tp2_b1     = (const float*)d_in[9];
  const float* tp2_w2     = (const float*)d_in[10];
  const float* tp2_b2     = (const float*)d_in[11];
  const float* a_w1  = (const float*)d_in[12];
  const float* a_b1  = (const float*)d_in[13];
  const float* a_g1  = (const float*)d_in[14];
  const float* a_be1 = (const float*)d_in[15];
  const float* a_w2  = (const float*)d_in[16];
  const float* a_b2  = (const float*)d_in[17];
  const float* a_g2  = (const float*)d_in[18];
  const float* a_be2 = (const float*)d_in[19];
  const float* a_w3  = (const float*)d_in[20];
  const float* a_b3  = (const float*)d_in[21];
  const float* lin_w      = (const float*)d_in[22];
  const float* lin_edge_w = (const float*)d_in[23];
  const float* s_w1  = (const float*)d_in[24];
  const float* s_b1  = (const float*)d_in[25];
  const float* s_g1  = (const float*)d_in[26];
  const float* s_be1 = (const float*)d_in[27];
  const float* s_w2  = (const float*)d_in[28];
  const float* s_b2  = (const float*)d_in[29];
  const float* s_g2  = (const float*)d_in[30];
  const float* s_be2 = (const float*)d_in[31];
  const float* s_w3  = (const float*)d_in[32];
  const float* s_b3  = (const float*)d_in[33];

  float* out_node = (float*)d_out;
  float* out_edge = out_node + (size_t)NN * 128;

  char* ws = (char*)d_ws;
  size_t off = 0;
  auto take = [&](size_t bytes) -> char* {
    char* p = ws + off;
    off = (off + bytes + 255) & ~(size_t)255;
    return p;
  };
  u16*   msgb   = (u16*)take((size_t)EE * 128 * 2);
  u16*   nfb    = (u16*)take((size_t)NN * 512 * 2);
  float* alpha  = (float*)take((size_t)EE * 4 * 4);
  float* scal   = (float*)take((size_t)EE * 4 * 4);
  float* cbuf   = (float*)take((size_t)EE * 4 * 4);
  int*   counts = (int*)take((size_t)NN * 4);
  int*   offs   = (int*)take((size_t)(NN + 1) * 4);
  int*   cursor = (int*)take((size_t)NN * 4);
  int*   eids   = (int*)take((size_t)EE * 4);
  u16*   Bt1    = (u16*)take((size_t)128 * 320 * 2);
  u16*   Bt2    = (u16*)take((size_t)256 * 128 * 2);
  u16*   Bt3    = (u16*)take((size_t)128 * 512 * 2);
  u16*   Wmlp   = (u16*)take((size_t)WTOT * 2);

  k_prep<<<544, 256, 0, stream>>>(pre_lin_w, lin_edge_w, lin_w, Bt1, Bt2, Bt3);
  k_prep2<<<(WTOT + 255)/256, 256, 0, stream>>>(a_w1, a_w2, a_w3, tp2_w1, tp2_w2,
                                                s_w1, s_w2, s_w3, Wmlp);
  k_zero<<<(NN + 255)/256, 256, 0, stream>>>(counts);
  k_count<<<EE/256, 256, 0, stream>>>(edst, counts);
  k_scan<<<1, 1024, 0, stream>>>(counts, offs, cursor);
  k_fill<<<EE/256, 256, 0, stream>>>(edst, cursor, eids);
  k_sort<<<(NN + 255)/256, 256, 0, stream>>>(offs, eids);
  k_ar_mlp<<<EE/128, 256, 0, stream>>>(elen, edge_sh, Wmlp,
                                       a_b1, a_g1, a_be1, a_b2, a_g2, a_be2, a_b3,
                                       tp2_b1, tp2_b2, alpha, scal, cbuf);
  g1_msg<<<EE/128, 256, 0, stream>>>(node_in, elen, esrc, edst, Bt1, msgb);
  g2s<<<EE/64, 256, 0, stream>>>(msgb, Bt2, cbuf, Wmlp,
                                 s_b1, s_g1, s_be1, s_b2, s_g2, s_be2, s_b3, out_edge);
  k_node<<<NN/4, 256, 0, stream>>>(offs, eids, alpha, scal, msgb, nfb);
  g10_out<<<(NN + 127)/128, 256, 0, stream>>>(nfb, Bt3, out_node);
}

// Round 9
// 467.166 us; speedup vs baseline: 1.3947x; 1.0379x over previous
//
#include <hip/hip_runtime.h>

#define NN 20000
#define EE 320000
#define WTOT 27648

typedef unsigned short u16;
typedef unsigned int u32;
typedef __attribute__((ext_vector_type(8))) short bf16x8;
typedef __attribute__((ext_vector_type(8))) _Float16 f16x8;
typedef __attribute__((ext_vector_type(4))) float f32x4;

__device__ __forceinline__ float bf2f(u16 u){
  union { u32 i; float f; } v; v.i = ((u32)u) << 16; return v.f;
}
__device__ __forceinline__ u16 f2bf(float f){
  union { float f; u32 i; } v; v.f = f;
  u32 i = v.i;
  return (u16)((i + 0x7FFFu + ((i >> 16) & 1u)) >> 16);
}
__device__ __forceinline__ u32 pack2(float a, float b){
  return ((u32)f2bf(b) << 16) | (u32)f2bf(a);
}
__device__ __forceinline__ u16 f2h(float f){
  union { _Float16 h[2]; u32 u; } v; v.h[0] = (_Float16)f;
  return (u16)(v.u & 0xFFFF);
}

// ---------------- weight pre-transpose (to bf16, [n][k] layout) -------------
__global__ __launch_bounds__(256) void k_prep(
    const float* __restrict__ plw, const float* __restrict__ lew,
    const float* __restrict__ lw,
    u16* __restrict__ Bt1, u16* __restrict__ Bt2, u16* __restrict__ Bt3)
{
  int i = blockIdx.x * 256 + threadIdx.x;
  if (i < 128*320) {                       // Bt1[n][k] = pre_lin_w[k][n]
    int n = i / 320, k = i % 320;
    Bt1[i] = f2bf(plw[k*128 + n]);
  }
  int j = i - 128*320;
  if (j >= 0 && j < 256*128) {             // Bt2[h*64+c][k] = lin_edge_w[h*128+k][c]
    int n = j / 128, k = j % 128;
    int h = n >> 6, c = n & 63;
    Bt2[j] = f2bf(lew[(h*128 + k)*64 + c]);
  }
  int l = i - 128*320 - 256*128;
  if (l >= 0 && l < 128*512) {             // Bt3[n][k] = lin_w[k][n]
    int n = l / 512, k = l % 512;
    Bt3[l] = f2bf(lw[k*128 + n]);
  }
}

// MLP weights, transposed to [out][in], fp16.
// Layout: Wc1[8192]=[Wa1|Wr1] Wa2[4096] Wa3[1024(pad16x64)] Wr2[4096]
//         Ws1[4096] Ws2[4096] Ws3[2048]
__global__ __launch_bounds__(256) void k_prep2(
    const float* __restrict__ aw1, const float* __restrict__ aw2, const float* __restrict__ aw3,
    const float* __restrict__ rw1, const float* __restrict__ rw2,
    const float* __restrict__ sw1, const float* __restrict__ sw2, const float* __restrict__ sw3,
    u16* __restrict__ W)
{
  int i = blockIdx.x * 256 + threadIdx.x;
  if (i >= WTOT) return;
  float v = 0.f;
  int j = i;
  if (j < 8192)      { int n = j >> 6, k = j & 63;
                       v = (n < 64) ? aw1[k*64 + n] : rw1[k*64 + (n - 64)]; }
  else if ((j -= 8192) < 4096) { int n = j >> 6, k = j & 63; v = aw2[k*64 + n]; }
  else if ((j -= 4096) < 1024) { int n = j >> 6, k = j & 63; v = (n < 4) ? aw3[k*4 + n] : 0.f; }
  else if ((j -= 1024) < 4096) { int n = j >> 6, k = j & 63; v = rw2[k*64 + n]; }
  else if ((j -= 4096) < 4096) { int n = j >> 6, k = j & 63; v = sw1[k*64 + n]; }
  else if ((j -= 4096) < 4096) { int n = j >> 6, k = j & 63; v = sw2[k*64 + n]; }
  else               { j -= 4096; int n = j >> 6, k = j & 63; v = sw3[k*32 + n]; }
  W[i] = f2h(v);
}

// ---------------- CSR build -------------------------------------------------
__global__ __launch_bounds__(256) void k_zero(int* __restrict__ counts){
  int i = blockIdx.x * 256 + threadIdx.x;
  if (i < NN) counts[i] = 0;
}
__global__ __launch_bounds__(256) void k_count(const int* __restrict__ edst, int* __restrict__ counts){
  int e = blockIdx.x * 256 + threadIdx.x;
  if (e < EE) atomicAdd(&counts[edst[e]], 1);
}
__global__ __launch_bounds__(1024) void k_scan(const int* __restrict__ counts,
                                               int* __restrict__ offs, int* __restrict__ cursor){
  __shared__ int part[1024];
  int t = threadIdx.x;
  int c0 = t * 20, c1 = c0 + 20; if (c1 > NN) c1 = NN; if (c0 > NN) c0 = NN;
  int s = 0;
  for (int i = c0; i < c1; ++i) s += counts[i];
  part[t] = s;
  __syncthreads();
  if (t == 0) {
    int run = 0;
    for (int i = 0; i < 1024; ++i) { int v = part[i]; part[i] = run; run += v; }
    offs[NN] = run;
  }
  __syncthreads();
  int run = part[t];
  for (int i = c0; i < c1; ++i) { offs[i] = run; cursor[i] = run; run += counts[i]; }
}
__global__ __launch_bounds__(256) void k_fill(const int* __restrict__ edst,
                                              int* __restrict__ cursor, int* __restrict__ eids){
  int e = blockIdx.x * 256 + threadIdx.x;
  if (e < EE) { int p = atomicAdd(&cursor[edst[e]], 1); eids[p] = e; }
}
__global__ __launch_bounds__(256) void k_sort(const int* __restrict__ offs, int* __restrict__ eids){
  int n = blockIdx.x * 256 + threadIdx.x;
  if (n >= NN) return;
  int b = offs[n], e = offs[n+1];
  for (int i = b + 1; i < e; ++i) {
    int v = eids[i]; int j = i - 1;
    while (j >= b && eids[j] > v) { eids[j+1] = eids[j]; --j; }
    eids[j+1] = v;
  }
}

// ---------------- FP16 MFMA MLP building blocks -----------------------------
// 2-row-block (32 rows/wave) LDS gemm: acc[2][NI] independent chains.
template<int NI>
__device__ __forceinline__ void gemm16_lds(const u16 (*X)[72], int wrow, int lane,
                                           const u16* __restrict__ B, f32x4 acc[2][4])
{
  const int fr = lane & 15, fc = lane >> 4;
  #pragma unroll
  for (int mi = 0; mi < 2; ++mi)
    #pragma unroll
    for (int ni = 0; ni < NI; ++ni)
      acc[mi][ni] = (f32x4){0.f, 0.f, 0.f, 0.f};
  #pragma unroll
  for (int kk = 0; kk < 2; ++kk) {
    f16x8 a0 = *(const f16x8*)&X[wrow + fr][kk*32 + fc*8];
    f16x8 a1 = *(const f16x8*)&X[wrow + 16 + fr][kk*32 + fc*8];
    #pragma unroll
    for (int ni = 0; ni < NI; ++ni) {
      f16x8 b = *(const f16x8*)(B + (size_t)(ni*16 + fr)*64 + kk*32 + fc*8);
      acc[0][ni] = __builtin_amdgcn_mfma_f32_16x16x32_f16(a0, b, acc[0][ni], 0, 0, 0);
      acc[1][ni] = __builtin_amdgcn_mfma_f32_16x16x32_f16(a1, b, acc[1][ni], 0, 0, 0);
    }
  }
}

// 1-row-block (16 rows/wave) LDS gemm for the fused s-MLP tail.
template<int NI>
__device__ __forceinline__ void gemm16_lds1(const u16 (*X)[72], int wrow, int lane,
                                            const u16* __restrict__ B, f32x4 acc[4])
{
  const int fr = lane & 15, fc = lane >> 4;
  #pragma unroll
  for (int ni = 0; ni < NI; ++ni) acc[ni] = (f32x4){0.f, 0.f, 0.f, 0.f};
  #pragma unroll
  for (int kk = 0; kk < 2; ++kk) {
    f16x8 a = *(const f16x8*)&X[wrow + fr][kk*32 + fc*8];
    #pragma unroll
    for (int ni = 0; ni < NI; ++ni) {
      f16x8 b = *(const f16x8*)(B + (size_t)(ni*16 + fr)*64 + kk*32 + fc*8);
      acc[ni] = __builtin_amdgcn_mfma_f32_16x16x32_f16(a, b, acc[ni], 0, 0, 0);
    }
  }
}

// NI=8 gemm with A loaded as fp32 from global (elen) and converted in-register.
__device__ __forceinline__ void gemm32_glb8(const float* __restrict__ X, int row0, int lane,
                                            const u16* __restrict__ B, f32x4 acc[2][8])
{
  const int fr = lane & 15, fc = lane >> 4;
  #pragma unroll
  for (int mi = 0; mi < 2; ++mi)
    #pragma unroll
    for (int ni = 0; ni < 8; ++ni)
      acc[mi][ni] = (f32x4){0.f, 0.f, 0.f, 0.f};
  #pragma unroll
  for (int kk = 0; kk < 2; ++kk) {
    const float* p0 = X + (size_t)(row0 + fr)*64 + kk*32 + fc*8;
    const float* p1 = X + (size_t)(row0 + 16 + fr)*64 + kk*32 + fc*8;
    float4 v00 = ((const float4*)p0)[0], v01 = ((const float4*)p0)[1];
    float4 v10 = ((const float4*)p1)[0], v11 = ((const float4*)p1)[1];
    f16x8 a0, a1;
    a0[0]=(_Float16)v00.x; a0[1]=(_Float16)v00.y; a0[2]=(_Float16)v00.z; a0[3]=(_Float16)v00.w;
    a0[4]=(_Float16)v01.x; a0[5]=(_Float16)v01.y; a0[6]=(_Float16)v01.z; a0[7]=(_Float16)v01.w;
    a1[0]=(_Float16)v10.x; a1[1]=(_Float16)v10.y; a1[2]=(_Float16)v10.z; a1[3]=(_Float16)v10.w;
    a1[4]=(_Float16)v11.x; a1[5]=(_Float16)v11.y; a1[6]=(_Float16)v11.z; a1[7]=(_Float16)v11.w;
    #pragma unroll
    for (int ni = 0; ni < 8; ++ni) {
      f16x8 b = *(const f16x8*)(B + (size_t)(ni*16 + fr)*64 + kk*32 + fc*8);
      acc[0][ni] = __builtin_amdgcn_mfma_f32_16x16x32_f16(a0, b, acc[0][ni], 0, 0, 0);
      acc[1][ni] = __builtin_amdgcn_mfma_f32_16x16x32_f16(a1, b, acc[1][ni], 0, 0, 0);
    }
  }
}

// bias (+ optional LN) + SiLU on 2-row-block C fragments, store fp16
template<bool LN>
__device__ __forceinline__ void act_store16(f32x4 acc[2][4],
    const float* __restrict__ b, const float* __restrict__ g, const float* __restrict__ be,
    u16 (*H)[72], int wrow, int lane)
{
  const int fr = lane & 15, fc = lane >> 4;
  float bv[4], gv[4], bev[4];
  #pragma unroll
  for (int ni = 0; ni < 4; ++ni) {
    bv[ni] = b[ni*16 + fr];
    if (LN) { gv[ni] = g[ni*16 + fr]; bev[ni] = be[ni*16 + fr]; }
  }
  #pragma unroll
  for (int mi = 0; mi < 2; ++mi)
    #pragma unroll
    for (int j = 0; j < 4; ++j) {
      int r = wrow + mi*16 + fc*4 + j;
      float x[4];
      #pragma unroll
      for (int ni = 0; ni < 4; ++ni) x[ni] = acc[mi][ni][j] + bv[ni];
      if (LN) {
        float s  = x[0] + x[1] + x[2] + x[3];
        float s2 = x[0]*x[0] + x[1]*x[1] + x[2]*x[2] + x[3]*x[3];
        #pragma unroll
        for (int off = 1; off < 16; off <<= 1) {
          s  += __shfl_xor(s,  off);
          s2 += __shfl_xor(s2, off);
        }
        float mu  = s * (1.f/64.f);
        float var = s2 * (1.f/64.f) - mu*mu;
        float rs  = rsqrtf(var + 1e-6f);
        #pragma unroll
        for (int ni = 0; ni < 4; ++ni) x[ni] = (x[ni] - mu)*rs*gv[ni] + bev[ni];
      }
      #pragma unroll
      for (int ni = 0; ni < 4; ++ni) {
        float y = x[ni];
        y = y / (1.f + __expf(-y));
        H[r][ni*16 + fr] = f2h(y);
      }
    }
}

// 1-row-block version (fused s-MLP tail)
template<bool LN>
__device__ __forceinline__ void act_store16_1(f32x4 acc[4],
    const float* __restrict__ b, const float* __restrict__ g, const float* __restrict__ be,
    u16 (*H)[72], int wrow, int lane)
{
  const int fr = lane & 15, fc = lane >> 4;
  float bv[4], gv[4], bev[4];
  #pragma unroll
  for (int ni = 0; ni < 4; ++ni) {
    bv[ni] = b[ni*16 + fr];
    if (LN) { gv[ni] = g[ni*16 + fr]; bev[ni] = be[ni*16 + fr]; }
  }
  #pragma unroll
  for (int j = 0; j < 4; ++j) {
    int r = wrow + fc*4 + j;
    float x[4];
    #pragma unroll
    for (int ni = 0; ni < 4; ++ni) x[ni] = acc[ni][j] + bv[ni];
    if (LN) {
      float s  = x[0] + x[1] + x[2] + x[3];
      float s2 = x[0]*x[0] + x[1]*x[1] + x[2]*x[2] + x[3]*x[3];
      #pragma unroll
      for (int off = 1; off < 16; off <<= 1) {
        s  += __shfl_xor(s,  off);
        s2 += __shfl_xor(s2, off);
      }
      float mu  = s * (1.f/64.f);
      float var = s2 * (1.f/64.f) - mu*mu;
      float rs  = rsqrtf(var + 1e-6f);
      #pragma unroll
      for (int ni = 0; ni < 4; ++ni) x[ni] = (x[ni] - mu)*rs*gv[ni] + bev[ni];
    }
    #pragma unroll
    for (int ni = 0; ni < 4; ++ni) {
      float y = x[ni];
      y = y / (1.f + __expf(-y));
      H[r][ni*16 + fr] = f2h(y);
    }
  }
}

// ---------------- fused alpha + radial MLPs (4 gemm phases) -----------------
__global__ __launch_bounds__(256, 4) void k_ar_mlp(
  const float* __restrict__ elen,
  const float* __restrict__ esh, const u16* __restrict__ Wm,
  const float* __restrict__ ab1, const float* __restrict__ ag1, const float* __restrict__ abe1,
  const float* __restrict__ ab2, const float* __restrict__ ag2, const float* __restrict__ abe2,
  const float* __restrict__ ab3,
  const float* __restrict__ tb1, const float* __restrict__ tb2,
  float* __restrict__ alpha_g, float* __restrict__ scal_g, float* __restrict__ cbuf_g)
{
  __shared__ u16 Ha[128][72], Hr[128][72];
  __shared__ float aS[128][4];
  const u16* Wc1 = Wm;            // [Wa1|Wr1], 128 outs
  const u16* Wa2 = Wm + 8192;
  const u16* Wa3 = Wm + 12288;
  const u16* Wr2 = Wm + 13312;
  const int tid = threadIdx.x;
  const int wave = tid >> 6, lane = tid & 63;
  const int fr = lane & 15, fc = lane >> 4;
  const int wrow = wave * 32;
  const int e0 = blockIdx.x * 128;
  // phase 1: combined L1 (alpha outs 0..63, radial outs 64..127)
  {
    f32x4 acc8[2][8];
    gemm32_glb8(elen, e0 + wrow, lane, Wc1, acc8);
    float bva[4], gva[4], beva[4], bvr[4];
    #pragma unroll
    for (int ni = 0; ni < 4; ++ni) {
      bva[ni] = ab1[ni*16 + fr]; gva[ni] = ag1[ni*16 + fr]; beva[ni] = abe1[ni*16 + fr];
      bvr[ni] = tb1[ni*16 + fr];
    }
    #pragma unroll
    for (int mi = 0; mi < 2; ++mi)
      #pragma unroll
      for (int j = 0; j < 4; ++j) {
        int r = wrow + mi*16 + fc*4 + j;
        float xa[4], xr[4];
        #pragma unroll
        for (int ni = 0; ni < 4; ++ni) {
          xa[ni] = acc8[mi][ni][j] + bva[ni];
          xr[ni] = acc8[mi][ni+4][j] + bvr[ni];
        }
        // alpha: LN + SiLU
        float s  = xa[0] + xa[1] + xa[2] + xa[3];
        float s2 = xa[0]*xa[0] + xa[1]*xa[1] + xa[2]*xa[2] + xa[3]*xa[3];
        #pragma unroll
        for (int off = 1; off < 16; off <<= 1) {
          s  += __shfl_xor(s,  off);
          s2 += __shfl_xor(s2, off);
        }
        float mu  = s * (1.f/64.f);
        float var = s2 * (1.f/64.f) - mu*mu;
        float rs  = rsqrtf(var + 1e-6f);
        #pragma unroll
        for (int ni = 0; ni < 4; ++ni) {
          float y = (xa[ni] - mu)*rs*gva[ni] + beva[ni];
          y = y / (1.f + __expf(-y));
          Ha[r][ni*16 + fr] = f2h(y);
          float z = xr[ni];
          z = z / (1.f + __expf(-z));
          Hr[r][ni*16 + fr] = f2h(z);
        }
      }
  }
  f32x4 acc[2][4];
  // alpha L2 (in-place on Ha)
  gemm16_lds<4>(Ha, wrow, lane, Wa2, acc);
  act_store16<true>(acc, ab2, ag2, abe2, Ha, wrow, lane);
  // alpha L3: N=4 (padded to 16)
  gemm16_lds<1>(Ha, wrow, lane, Wa3, acc);
  {
    float bv = (fr < 4) ? ab3[fr] : 0.f;
    #pragma unroll
    for (int mi = 0; mi < 2; ++mi)
      #pragma unroll
      for (int j = 0; j < 4; ++j) {
        int r = wrow + mi*16 + fc*4 + j;
        float v = acc[mi][0][j] + bv;
        if (fr < 4) {
          alpha_g[(size_t)(e0 + r)*4 + fr] = v;
          aS[r][fr] = v;
        }
      }
  }
  // radial L2 + sh contraction
  gemm16_lds<4>(Hr, wrow, lane, Wr2, acc);
  {
    float bv[4];
    #pragma unroll
    for (int ni = 0; ni < 4; ++ni) bv[ni] = tb2[ni*16 + fr];
    #pragma unroll
    for (int mi = 0; mi < 2; ++mi)
      #pragma unroll
      for (int j = 0; j < 4; ++j) {
        int r = wrow + mi*16 + fc*4 + j;
        float shv = esh[(size_t)(e0 + r)*16 + fr];
        float sc[4];
        #pragma unroll
        for (int ni = 0; ni < 4; ++ni) {
          float t = (acc[mi][ni][j] + bv[ni]) * shv;
          #pragma unroll
          for (int off = 1; off < 16; off <<= 1) t += __shfl_xor(t, off);
          sc[ni] = t;
        }
        if (fr == 0) {
          float4 sv; sv.x = sc[0]; sv.y = sc[1]; sv.z = sc[2]; sv.w = sc[3];
          *(float4*)(scal_g + (size_t)(e0 + r)*4) = sv;
          float4 cv;
          cv.x = sc[0]*aS[r][0]; cv.y = sc[1]*aS[r][1];
          cv.z = sc[2]*aS[r][2]; cv.w = sc[3]*aS[r][3];
          *(float4*)(cbuf_g + (size_t)(e0 + r)*4) = cv;
        }
      }
  }
}

// ---------------- G1: msg = [x_src|x_dst|elen] @ pre_lin_w  (bf16 out) ------
__global__ __launch_bounds__(256) void g1_msg(
    const float* __restrict__ node_in, const float* __restrict__ elen,
    const int* __restrict__ esrc, const int* __restrict__ edst,
    const u16* __restrict__ Bt1, u16* __restrict__ msgb)
{
  __shared__ u16 As[128][40];
  __shared__ u16 Bs[128][40];
  const int tid = threadIdx.x;
  const int e0 = blockIdx.x * 128;
  const int wave = tid >> 6, lane = tid & 63;
  const int wr = (wave >> 1) * 64, wc = (wave & 1) * 64;
  const int fr = lane & 15, fc = lane >> 4;
  f32x4 acc[4][4] = {};
  const int r = tid >> 1, half = tid & 1;
  const int e = e0 + r;
  const int s_idx = esrc[e], d_idx = edst[e];
  for (int k0 = 0; k0 < 320; k0 += 32) {
    const int kk = k0 + half * 16;
    const float* ap;
    if (kk < 128)      ap = node_in + (size_t)s_idx*128 + kk;
    else if (kk < 256) ap = node_in + (size_t)d_idx*128 + (kk - 128);
    else               ap = elen + (size_t)e*64 + (kk - 256);
    u32* asp = (u32*)&As[r][half*16];
    #pragma unroll
    for (int q = 0; q < 4; ++q) {
      float4 v = *(const float4*)(ap + q*4);
      asp[q*2]   = pack2(v.x, v.y);
      asp[q*2+1] = pack2(v.z, v.w);
    }
    const uint4* bp = (const uint4*)(Bt1 + (size_t)r*320 + kk);
    *(uint4*)&Bs[r][half*16]     = bp[0];
    *(uint4*)&Bs[r][half*16 + 8] = bp[1];
    __syncthreads();
    bf16x8 a[4], b[4];
    #pragma unroll
    for (int mi = 0; mi < 4; ++mi) a[mi] = *(const bf16x8*)&As[wr + mi*16 + fr][fc*8];
    #pragma unroll
    for (int ni = 0; ni < 4; ++ni) b[ni] = *(const bf16x8*)&Bs[wc + ni*16 + fr][fc*8];
    #pragma unroll
    for (int mi = 0; mi < 4; ++mi)
      #pragma unroll
      for (int ni = 0; ni < 4; ++ni)
        acc[mi][ni] = __builtin_amdgcn_mfma_f32_16x16x32_bf16(a[mi], b[ni], acc[mi][ni], 0, 0, 0);
    __syncthreads();
  }
  #pragma unroll
  for (int mi = 0; mi < 4; ++mi)
    #pragma unroll
    for (int j = 0; j < 4; ++j) {
      int row = wr + mi*16 + fc*4 + j;
      size_t base = (size_t)(e0 + row)*128 + wc + fr;
      #pragma unroll
      for (int ni = 0; ni < 4; ++ni)
        msgb[base + ni*16] = f2bf(acc[mi][ni][j]);
    }
}

// ---- G2S: per-wave 16 rows x 256 cols; head-sum IN-REGISTER; fused s-MLP ---
union G2Smem {
  struct { u16 As[64][40]; u16 Bs[256][40]; } s;   // 25600 B, dead after K-loop
  u16 X[64][72];                                    // 9216 B, s-MLP tile
};
__global__ __launch_bounds__(256, 4) void g2s(
    const u16* __restrict__ msgb, const u16* __restrict__ Bt2,
    const float* __restrict__ cbuf, const u16* __restrict__ Wm,
    const float* __restrict__ b1, const float* __restrict__ g1, const float* __restrict__ be1,
    const float* __restrict__ b2, const float* __restrict__ g2, const float* __restrict__ be2,
    const float* __restrict__ b3,
    float* __restrict__ oute)
{
  __shared__ G2Smem u;
  __shared__ float cS[64][4];
  const u16* Ws1 = Wm + 17408;
  const u16* Ws2 = Wm + 21504;
  const u16* Ws3 = Wm + 25600;
  const int tid = threadIdx.x, wave = tid >> 6, lane = tid & 63;
  const int e0 = blockIdx.x * 64;
  const int fr = lane & 15, fc = lane >> 4;
  const int wrow = wave * 16;
  cS[tid >> 2][tid & 3] = cbuf[(size_t)e0*4 + tid];
  f32x4 acc[16];
  #pragma unroll
  for (int ni = 0; ni < 16; ++ni) acc[ni] = (f32x4){0.f, 0.f, 0.f, 0.f};
  for (int k0 = 0; k0 < 128; k0 += 32) {
    { // stage A (64 x 32)
      int r = tid >> 2, q = tid & 3;
      *(uint4*)&u.s.As[r][q*8] = *(const uint4*)(msgb + (size_t)(e0 + r)*128 + k0 + q*8);
    }
    { // stage B (256 x 32)
      const uint4* bp = (const uint4*)(Bt2 + (size_t)tid*128 + k0);
      *(uint4*)&u.s.Bs[tid][0]  = bp[0];
      *(uint4*)&u.s.Bs[tid][8]  = bp[1];
      *(uint4*)&u.s.Bs[tid][16] = bp[2];
      *(uint4*)&u.s.Bs[tid][24] = bp[3];
    }
    __syncthreads();
    bf16x8 a = *(const bf16x8*)&u.s.As[wrow + fr][fc*8];
    #pragma unroll
    for (int ni = 0; ni < 16; ++ni) {
      bf16x8 b = *(const bf16x8*)&u.s.Bs[ni*16 + fr][fc*8];
      acc[ni] = __builtin_amdgcn_mfma_f32_16x16x32_bf16(a, b, acc[ni], 0, 0, 0);
    }
    __syncthreads();
  }
  // head-sum in-register: y0[m] = sum_h cS[row][h] * acc[4h+m]; write X fp16
  #pragma unroll
  for (int j = 0; j < 4; ++j) {
    int r = wrow + fc*4 + j;
    float c0 = cS[r][0], c1 = cS[r][1], c2 = cS[r][2], c3 = cS[r][3];
    #pragma unroll
    for (int m = 0; m < 4; ++m) {
      float y = c0*acc[m][j] + c1*acc[4+m][j] + c2*acc[8+m][j] + c3*acc[12+m][j];
      u.X[r][m*16 + fr] = f2h(y);
    }
  }
  // s-MLP tail: wave w owns rows [w*16, w*16+16) of X — barrier-free
  f32x4 sa[4];
  gemm16_lds1<4>(u.X, wrow, lane, Ws1, sa);
  act_store16_1<true>(sa, b1, g1, be1, u.X, wrow, lane);
  gemm16_lds1<4>(u.X, wrow, lane, Ws2, sa);
  act_store16_1<true>(sa, b2, g2, be2, u.X, wrow, lane);
  gemm16_lds1<2>(u.X, wrow, lane, Ws3, sa);
  {
    float bv[2];
    bv[0] = b3[fr]; bv[1] = b3[16 + fr];
    #pragma unroll
    for (int j = 0; j < 4; ++j) {
      int r = wrow + fc*4 + j;
      #pragma unroll
      for (int ni = 0; ni < 2; ++ni)
        oute[(size_t)(e0 + r)*32 + ni*16 + fr] = sa[ni][j] + bv[ni];
    }
  }
}

// ---------------- K9: per-node softmax + aggregation ------------------------
__global__ __launch_bounds__(256) void k_node(
  const int* __restrict__ offs, const int* __restrict__ eids,
  const float* __restrict__ alpha, const float* __restrict__ scal,
  const u16* __restrict__ msgb, u16* __restrict__ nfb)
{
  const int w = threadIdx.x >> 6, lane = threadIdx.x & 63;
  const int n = blockIdx.x * 4 + w;
  const int beg = offs[n], end = offs[n+1];
  float m0=-3e38f, m1=-3e38f, m2=-3e38f, m3=-3e38f;
  for (int i = beg + lane; i < end; i += 64) {
    int eid = eids[i];
    float4 a = *(const float4*)(alpha + (size_t)eid*4);
    m0 = fmaxf(m0, a.x); m1 = fmaxf(m1, a.y);
    m2 = fmaxf(m2, a.z); m3 = fmaxf(m3, a.w);
  }
  #pragma unroll
  for (int off = 1; off < 64; off <<= 1) {
    m0 = fmaxf(m0, __shfl_xor(m0, off));
    m1 = fmaxf(m1, __shfl_xor(m1, off));
    m2 = fmaxf(m2, __shfl_xor(m2, off));
    m3 = fmaxf(m3, __shfl_xor(m3, off));
  }
  float se0=0.f, se1=0.f, se2=0.f, se3=0.f;
  float f00=0.f, f01=0.f, f10=0.f, f11=0.f, f20=0.f, f21=0.f, f30=0.f, f31=0.f;
  for (int i = beg; i < end; ++i) {
    int eid = eids[i];
    float4 a = *(const float4*)(alpha + (size_t)eid*4);
    float4 s = *(const float4*)(scal + (size_t)eid*4);
    float e0 = __expf(a.x - m0), e1 = __expf(a.y - m1);
    float e2 = __expf(a.z - m2), e3 = __expf(a.w - m3);
    se0 += e0; se1 += e1; se2 += e2; se3 += e3;
    float w0 = e0*s.x, w1 = e1*s.y, w2 = e2*s.z, w3 = e3*s.w;
    float v0 = bf2f(msgb[(size_t)eid*128 + lane]);
    float v1 = bf2f(msgb[(size_t)eid*128 + 64 + lane]);
    f00 = fmaf(w0, v0, f00); f01 = fmaf(w0, v1, f01);
    f10 = fmaf(w1, v0, f10); f11 = fmaf(w1, v1, f11);
    f20 = fmaf(w2, v0, f20); f21 = fmaf(w2, v1, f21);
    f30 = fmaf(w3, v0, f30); f31 = fmaf(w3, v1, f31);
  }
  float i0 = 1.f/(se0 + 1e-16f), i1 = 1.f/(se1 + 1e-16f);
  float i2 = 1.f/(se2 + 1e-16f), i3 = 1.f/(se3 + 1e-16f);
  size_t b = (size_t)n * 512;
  nfb[b + 0*128 + lane]      = f2bf(f00*i0);
  nfb[b + 0*128 + 64 + lane] = f2bf(f01*i0);
  nfb[b + 1*128 + lane]      = f2bf(f10*i1);
  nfb[b + 1*128 + 64 + lane] = f2bf(f11*i1);
  nfb[b + 2*128 + lane]      = f2bf(f20*i2);
  nfb[b + 2*128 + 64 + lane] = f2bf(f21*i2);
  nfb[b + 3*128 + lane]      = f2bf(f30*i3);
  nfb[b + 3*128 + 64 + lane] = f2bf(f31*i3);
}

// ---------------- G10: node_out = node_fea @ lin_w --------------------------
__global__ __launch_bounds__(256) void g10_out(
    const u16* __restrict__ nfb, const u16* __restrict__ Bt3,
    float* __restrict__ out)
{
  __shared__ u16 As[128][40];
  __shared__ u16 Bs[128][40];
  const int tid = threadIdx.x;
  const int n0 = blockIdx.x * 128;
  const int wave = tid >> 6, lane = tid & 63;
  const int wr = (wave >> 1) * 64, wc = (wave & 1) * 64;
  const int fr = lane & 15, fc = lane >> 4;
  f32x4 acc[4][4] = {};
  const int r = tid >> 1, half = tid & 1;
  const int n = n0 + r;
  for (int k0 = 0; k0 < 512; k0 += 32) {
    uint4 z; z.x=0; z.y=0; z.z=0; z.w=0;
    uint4 v0 = z, v1 = z;
    if (n < NN) {
      const uint4* apv = (const uint4*)(nfb + (size_t)n*512 + k0 + half*16);
      v0 = apv[0]; v1 = apv[1];
    }
    *(uint4*)&As[r][half*16]     = v0;
    *(uint4*)&As[r][half*16 + 8] = v1;
    const uint4* bp = (const uint4*)(Bt3 + (size_t)r*512 + k0 + half*16);
    *(uint4*)&Bs[r][half*16]     = bp[0];
    *(uint4*)&Bs[r][half*16 + 8] = bp[1];
    __syncthreads();
    bf16x8 a[4], b[4];
    #pragma unroll
    for (int mi = 0; mi < 4; ++mi) a[mi] = *(const bf16x8*)&As[wr + mi*16 + fr][fc*8];
    #pragma unroll
    for (int ni = 0; ni < 4; ++ni) b[ni] = *(const bf16x8*)&Bs[wc + ni*16 + fr][fc*8];
    #pragma unroll
    for (int mi = 0; mi < 4; ++mi)
      #pragma unroll
      for (int ni = 0; ni < 4; ++ni)
        acc[mi][ni] = __builtin_amdgcn_mfma_f32_16x16x32_bf16(a[mi], b[ni], acc[mi][ni], 0, 0, 0);
    __syncthreads();
  }
  #pragma unroll
  for (int mi = 0; mi < 4; ++mi)
    #pragma unroll
    for (int j = 0; j < 4; ++j) {
      int rowg = n0 + wr + mi*16 + fc*4 + j;
      if (rowg < NN) {
        size_t base = (size_t)rowg*128 + wc + fr;
        #pragma unroll
        for (int ni = 0; ni < 4; ++ni)
          out[base + ni*16] = acc[mi][ni][j];
      }
    }
}

// ---------------- launch ----------------------------------------------------
extern "C" void kernel_launch(void* const* d_in, const int* in_sizes, int n_in,
                              void* d_out, int out_size, void* d_ws, size_t ws_size,
                              hipStream_t stream)
{
  const float* node_in    = (const float*)d_in[0];
  const float* edge_sh    = (const float*)d_in[2];
  const float* elen       = (const float*)d_in[3];
  const int*   esrc       = (const int*)d_in[4];
  const int*   edst       = (const int*)d_in[5];
  const float* pre_lin_w  = (const float*)d_in[7];
  const float* tp2_w1     = (const float*)d_in[8];
  const float* tp2_b1     = (const float*)d_in[9];
  const float* tp2_w2     = (const float*)d_in[10];
  const float* tp2_b2     = (const float*)d_in[11];
  const float* a_w1  = (const float*)d_in[12];
  const float* a_b1  = (const float*)d_in[13];
  const float* a_g1  = (const float*)d_in[14];
  const float* a_be1 = (const float*)d_in[15];
  const float* a_w2  = (const float*)d_in[16];
  const float* a_b2  = (const float*)d_in[17];
  const float* a_g2  = (const float*)d_in[18];
  const float* a_be2 = (const float*)d_in[19];
  const float* a_w3  = (const float*)d_in[20];
  const float* a_b3  = (const float*)d_in[21];
  const float* lin_w      = (const float*)d_in[22];
  const float* lin_edge_w = (const float*)d_in[23];
  const float* s_w1  = (const float*)d_in[24];
  const float* s_b1  = (const float*)d_in[25];
  const float* s_g1  = (const float*)d_in[26];
  const float* s_be1 = (const float*)d_in[27];
  const float* s_w2  = (const float*)d_in[28];
  const float* s_b2  = (const float*)d_in[29];
  const float* s_g2  = (const float*)d_in[30];
  const float* s_be2 = (const float*)d_in[31];
  const float* s_w3  = (const float*)d_in[32];
  const float* s_b3  = (const float*)d_in[33];

  float* out_node = (float*)d_out;
  float* out_edge = out_node + (size_t)NN * 128;

  char* ws = (char*)d_ws;
  size_t off = 0;
  auto take = [&](size_t bytes) -> char* {
    char* p = ws + off;
    off = (off + bytes + 255) & ~(size_t)255;
    return p;
  };
  u16*   msgb   = (u16*)take((size_t)EE * 128 * 2);
  u16*   nfb    = (u16*)take((size_t)NN * 512 * 2);
  float* alpha  = (float*)take((size_t)EE * 4 * 4);
  float* scal   = (float*)take((size_t)EE * 4 * 4);
  float* cbuf   = (float*)take((size_t)EE * 4 * 4);
  int*   counts = (int*)take((size_t)NN * 4);
  int*   offs   = (int*)take((size_t)(NN + 1) * 4);
  int*   cursor = (int*)take((size_t)NN * 4);
  int*   eids   = (int*)take((size_t)EE * 4);
  u16*   Bt1    = (u16*)take((size_t)128 * 320 * 2);
  u16*   Bt2    = (u16*)take((size_t)256 * 128 * 2);
  u16*   Bt3    = (u16*)take((size_t)128 * 512 * 2);
  u16*   Wmlp   = (u16*)take((size_t)WTOT * 2);

  k_prep<<<544, 256, 0, stream>>>(pre_lin_w, lin_edge_w, lin_w, Bt1, Bt2, Bt3);
  k_prep2<<<(WTOT + 255)/256, 256, 0, stream>>>(a_w1, a_w2, a_w3, tp2_w1, tp2_w2,
                                                s_w1, s_w2, s_w3, Wmlp);
  k_zero<<<(NN + 255)/256, 256, 0, stream>>>(counts);
  k_count<<<EE/256, 256, 0, stream>>>(edst, counts);
  k_scan<<<1, 1024, 0, stream>>>(counts, offs, cursor);
  k_fill<<<EE/256, 256, 0, stream>>>(edst, cursor, eids);
  k_sort<<<(NN + 255)/256, 256, 0, stream>>>(offs, eids);
  k_ar_mlp<<<EE/128, 256, 0, stream>>>(elen, edge_sh, Wmlp,
                                       a_b1, a_g1, a_be1, a_b2, a_g2, a_be2, a_b3,
                                       tp2_b1, tp2_b2, alpha, scal, cbuf);
  g1_msg<<<EE/128, 256, 0, stream>>>(node_in, elen, esrc, edst, Bt1, msgb);
  g2s<<<EE/64, 256, 0, stream>>>(msgb, Bt2, cbuf, Wmlp,
                                 s_b1, s_g1, s_be1, s_b2, s_g2, s_be2, s_b3, out_edge);
  k_node<<<NN/4, 256, 0, stream>>>(offs, eids, alpha, scal, msgb, nfb);
  g10_out<<<(NN + 127)/128, 256, 0, stream>>>(nfb, Bt3, out_node);
}